// Round 1
// 257.190 us; speedup vs baseline: 1.1292x; 1.1292x over previous
//
#include <hip/hip_runtime.h>

typedef unsigned short u16;
typedef unsigned int   u32;

typedef __attribute__((ext_vector_type(4))) short short4v;
typedef __attribute__((ext_vector_type(8))) short bf16x8;  // 8 bf16 (4 VGPRs)
typedef __attribute__((ext_vector_type(4))) float f32x4;

// Problem: B=8, C=256, N=4096, heads=8, d=32, P=64. Inputs fp32 (auto-detect),
// output FP32. r13: x pre-transposed to xT[b][n][c]; q_sa+y_sc fused into ONE
// m97-style GEMM (128^2 tile, BK=64, global_load_lds dwordx4, K-contig both
// operands) writing Y[b][1024][4096] (rows: q 0:256, qc 256:512, kc 512:768,
// vc 768:1024).

__device__ __forceinline__ float bf2f(u16 u){
  union { u32 i; float f; } v; v.i = ((u32)u) << 16; return v.f;
}
__device__ __forceinline__ u16 f2bf(float f){
  u32 u = __float_as_uint(f);
  u32 r = u + 0x7FFFu + ((u >> 16) & 1u);   // RNE
  return (u16)(r >> 16);
}

__device__ __forceinline__ void gload_lds16(const u16* g, u16* l){
  __builtin_amdgcn_global_load_lds((const __attribute__((address_space(1))) void*)g,
                                   (__attribute__((address_space(3))) void*)l,
                                   16, 0, 0);
}

// ---------------------------------------------------------------------------
// K0a: dtype detector on x. flag=1 => fp32 input.
// ---------------------------------------------------------------------------
__global__ void k_detect(const u16* __restrict__ x, u32* __restrict__ flag){
  __shared__ int cnt[256];
  const int t = threadIdx.x;
  int c = 0;
  #pragma unroll
  for(int i = 0; i < 4; i++){
    u16 v = x[t * 4 + i];
    int e = (v >> 7) & 0xFF;
    if(e >= 112 && e <= 134) c++;
  }
  cnt[t] = c;
  __syncthreads();
  for(int s = 128; s > 0; s >>= 1){
    if(t < s) cnt[t] += cnt[t + s];
    __syncthreads();
  }
  if(t == 0) *flag = (cnt[0] < 800) ? 1u : 0u;
}

// ---------------------------------------------------------------------------
// K0b: canonicalize to bf16 (8 elems/thread).
// ---------------------------------------------------------------------------
__global__ __launch_bounds__(256) void k_conv_bf(const void* __restrict__ src,
                                                 u16* __restrict__ dst, int n,
                                                 const u32* __restrict__ flag){
  const int i0 = (blockIdx.x * 256 + threadIdx.x) * 8;
  if(i0 >= n) return;
  const bool isf32 = (*flag != 0);
  if(isf32){
    const float4 a = *(const float4*)((const float*)src + i0);
    const float4 b = *(const float4*)((const float*)src + i0 + 4);
    uint4 o;
    o.x = (u32)f2bf(a.x) | ((u32)f2bf(a.y) << 16);
    o.y = (u32)f2bf(a.z) | ((u32)f2bf(a.w) << 16);
    o.z = (u32)f2bf(b.x) | ((u32)f2bf(b.y) << 16);
    o.w = (u32)f2bf(b.z) | ((u32)f2bf(b.w) << 16);
    *(uint4*)(dst + i0) = o;
  } else {
    *(uint4*)(dst + i0) = *(const uint4*)((const u16*)src + i0);
  }
}

// ---------------------------------------------------------------------------
// K0c: canonicalize to fp32 (4 elems/thread).
// ---------------------------------------------------------------------------
__global__ __launch_bounds__(256) void k_conv_f32(const void* __restrict__ src,
                                                  float* __restrict__ dst, int n,
                                                  const u32* __restrict__ flag){
  const int i0 = (blockIdx.x * 256 + threadIdx.x) * 4;
  if(i0 >= n) return;
  const bool isf32 = (*flag != 0);
  if(isf32){
    *(float4*)(dst + i0) = *(const float4*)((const float*)src + i0);
  } else {
    const uint2 a = *(const uint2*)((const u16*)src + i0);
    float4 o;
    o.x = bf2f((u16)(a.x & 0xFFFF)); o.y = bf2f((u16)(a.x >> 16));
    o.z = bf2f((u16)(a.y & 0xFFFF)); o.w = bf2f((u16)(a.y >> 16));
    *(float4*)(dst + i0) = o;
  }
}

// ---------------------------------------------------------------------------
// K0d: canonicalize to fp32 (all n) + bf16 (first nb elems) — for W_sa.
// ---------------------------------------------------------------------------
__global__ __launch_bounds__(256) void k_conv_both(const void* __restrict__ src,
                                                   float* __restrict__ dstf,
                                                   u16* __restrict__ dstb, int n,
                                                   int nb,
                                                   const u32* __restrict__ flag){
  const int i0 = (blockIdx.x * 256 + threadIdx.x) * 4;
  if(i0 >= n) return;
  const bool isf32 = (*flag != 0);
  float4 o;
  if(isf32){
    o = *(const float4*)((const float*)src + i0);
  } else {
    const uint2 a = *(const uint2*)((const u16*)src + i0);
    o.x = bf2f((u16)(a.x & 0xFFFF)); o.y = bf2f((u16)(a.x >> 16));
    o.z = bf2f((u16)(a.y & 0xFFFF)); o.w = bf2f((u16)(a.y >> 16));
  }
  *(float4*)(dstf + i0) = o;
  if(i0 < nb){
    uint2 pk;
    pk.x = (u32)f2bf(o.x) | ((u32)f2bf(o.y) << 16);
    pk.y = (u32)f2bf(o.z) | ((u32)f2bf(o.w) << 16);
    *(uint2*)(dstb + i0) = pk;
  }
}

// ---------------------------------------------------------------------------
// K0e (new): x -> xb[b][c][n] bf16 AND xT[b][n][c] bf16 (LDS 64x64 transpose).
// ---------------------------------------------------------------------------
__global__ __launch_bounds__(256) void k_convT(const void* __restrict__ src,
                                               u16* __restrict__ xb,
                                               u16* __restrict__ xT,
                                               const u32* __restrict__ flag){
  __shared__ u16 T[64][72];
  const int t = threadIdx.x;
  const int n0 = blockIdx.x * 64, c0 = blockIdx.y * 64, b = blockIdx.z;
  const int cl = t >> 2, ns = (t & 3) * 16;
  const bool isf32 = (*flag != 0);
  const size_t srcoff = ((size_t)(b * 256 + c0 + cl)) * 4096 + n0 + ns;
  u16 e[16];
  if(isf32){
    const float* sp = (const float*)src + srcoff;
    #pragma unroll
    for(int i = 0; i < 4; i++){
      const float4 v = *(const float4*)(sp + i * 4);
      e[i*4+0] = f2bf(v.x); e[i*4+1] = f2bf(v.y);
      e[i*4+2] = f2bf(v.z); e[i*4+3] = f2bf(v.w);
    }
  } else {
    const u16* sp = (const u16*)src + srcoff;
    *(uint4*)&e[0] = *(const uint4*)sp;
    *(uint4*)&e[8] = *(const uint4*)(sp + 8);
  }
  // pass-through copy (row-major, coalesced)
  u16* xbp = xb + srcoff;
  *(uint4*)xbp       = *(uint4*)&e[0];
  *(uint4*)(xbp + 8) = *(uint4*)&e[8];
  // transpose via LDS
  #pragma unroll
  for(int i = 0; i < 16; i++) T[ns + i][cl] = e[i];
  __syncthreads();
  const int nl = t >> 2, cs = (t & 3) * 16;
  u16* xtp = xT + ((size_t)b * 4096 + n0 + nl) * 256 + c0 + cs;
  *(uint4*)xtp       = *(const uint4*)&T[nl][cs];
  *(uint4*)(xtp + 8) = *(const uint4*)&T[nl][cs + 8];
}

// ---------------------------------------------------------------------------
// K1 (new): fused QKV GEMM, m97 structure. Y[b][m][n] = sum_k Wc[m][k]*xT[b][n][k].
// 128x128 tile, BK=64, 4 waves (2m x 2n), global_load_lds width 16 staging,
// bf16 LDS-transposed coalesced epilogue. Grid (32 ntile, 8 mtile, 8 b).
// ---------------------------------------------------------------------------
__global__ __launch_bounds__(256) void k_qkv(const u16* __restrict__ Wc,
                                             const u16* __restrict__ xT,
                                             u16* __restrict__ Y){
  __shared__ union {
    struct { u16 Ws[128][64]; u16 Xs[128][64]; } s;
    u16 Cs[128][136];
  } L;
  const int t = threadIdx.x;
  const int n0 = blockIdx.x * 128, m0 = blockIdx.y * 128, b = blockIdx.z;
  const int w = t >> 6, lane = t & 63;
  const int fm = lane & 15, fq = lane >> 4;
  const int wm = w >> 1, wn = w & 1;
  const int lr = lane >> 3, lc = (lane & 7) * 8;
  const u16* gw = Wc + (size_t)m0 * 256;
  const u16* gx = xT + ((size_t)b * 4096 + n0) * 256;
  f32x4 acc[4][4] = {};
  for(int kc = 0; kc < 256; kc += 64){
    #pragma unroll
    for(int i = 0; i < 4; i++){
      const int row = w * 32 + i * 8;          // wave-uniform LDS base row
      gload_lds16(gw + (size_t)(row + lr) * 256 + kc + lc, &L.s.Ws[row][0]);
      gload_lds16(gx + (size_t)(row + lr) * 256 + kc + lc, &L.s.Xs[row][0]);
    }
    __syncthreads();                            // drains vmcnt -> tiles ready
    #pragma unroll
    for(int kh = 0; kh < 2; kh++){
      bf16x8 af[4], bx[4];
      #pragma unroll
      for(int mt = 0; mt < 4; mt++)
        af[mt] = *(const bf16x8*)&L.s.Ws[wm * 64 + mt * 16 + fm][kh * 32 + fq * 8];
      #pragma unroll
      for(int nt = 0; nt < 4; nt++)
        bx[nt] = *(const bf16x8*)&L.s.Xs[wn * 64 + nt * 16 + fm][kh * 32 + fq * 8];
      #pragma unroll
      for(int mt = 0; mt < 4; mt++)
        #pragma unroll
        for(int nt = 0; nt < 4; nt++)
          acc[mt][nt] = __builtin_amdgcn_mfma_f32_16x16x32_bf16(af[mt], bx[nt],
                                                                acc[mt][nt], 0, 0, 0);
    }
    __syncthreads();
  }
  // epilogue: acc -> bf16 via LDS transpose (Cs overlays the staging tiles)
  #pragma unroll
  for(int mt = 0; mt < 4; mt++)
    #pragma unroll
    for(int nt = 0; nt < 4; nt++)
      #pragma unroll
      for(int r = 0; r < 4; r++)
        L.Cs[wm * 64 + mt * 16 + fq * 4 + r][wn * 64 + nt * 16 + fm] =
          f2bf(acc[mt][nt][r]);
  __syncthreads();
  #pragma unroll
  for(int i = 0; i < 8; i++){
    const int row = i * 16 + (t >> 4), ce = (t & 15) * 8;
    *(uint4*)(Y + ((size_t)b * 1024 + m0 + row) * 4096 + n0 + ce) =
      *(const uint4*)&L.Cs[row][ce];
  }
}

// ---------------------------------------------------------------------------
// K2: split-K LDS-tiled xef partials (unchanged).
// ---------------------------------------------------------------------------
__global__ __launch_bounds__(256) void k_xef8(const u16* __restrict__ xb,
                                              const float* __restrict__ EFf,
                                              float* __restrict__ xefp){
  __shared__ float At[32][68];
  __shared__ float Bt[64][72];
  const int t = threadIdx.x;
  const int c0 = blockIdx.x * 32, s = blockIdx.y, b = blockIdx.z;
  const int cc = t >> 3, p0 = (t & 7) * 8;
  float acc[8] = {};
  for(int n0 = s * 512; n0 < s * 512 + 512; n0 += 64){
    {
      const int r = t >> 3, k0 = (t & 7) * 8;
      const u16* sx = xb + (size_t)(b * 256 + c0 + r) * 4096 + n0 + k0;
      uint4 xv = *(const uint4*)sx;
      u16 e[8]; *(uint4*)e = xv;
      #pragma unroll
      for(int i = 0; i < 8; i++) At[r][k0 + i] = bf2f(e[i]);
      const int rk = t >> 2, pp = (t & 3) * 16;
      const float* se = EFf + (size_t)(n0 + rk) * 64 + pp;
      #pragma unroll
      for(int i = 0; i < 4; i++)
        *(float4*)&Bt[rk][pp + i * 4] = *(const float4*)(se + i * 4);
    }
    __syncthreads();
    #pragma unroll 8
    for(int kk = 0; kk < 64; kk++){
      const float a = At[cc][kk];
      const float4 b0 = *(const float4*)&Bt[kk][p0];
      const float4 b1 = *(const float4*)&Bt[kk][p0 + 4];
      acc[0] += a*b0.x; acc[1] += a*b0.y; acc[2] += a*b0.z; acc[3] += a*b0.w;
      acc[4] += a*b1.x; acc[5] += a*b1.y; acc[6] += a*b1.z; acc[7] += a*b1.w;
    }
    __syncthreads();
  }
  float* dst = xefp + ((size_t)s * 131072 + (size_t)(b * 256 + c0 + cc) * 64 + p0);
  #pragma unroll
  for(int i = 0; i < 8; i++) dst[i] = acc[i];
}

// ---------------------------------------------------------------------------
// K2b: reduce partials: xef[i] = sum_s xefp[s][i].
// ---------------------------------------------------------------------------
__global__ __launch_bounds__(256) void k_xred(const float* __restrict__ xefp,
                                              float* __restrict__ xef){
  const int i0 = (blockIdx.x * 256 + threadIdx.x) * 4;
  float4 a = *(const float4*)(xefp + i0);
  #pragma unroll
  for(int s = 1; s < 8; s++){
    const float4 v = *(const float4*)(xefp + (size_t)s * 131072 + i0);
    a.x += v.x; a.y += v.y; a.z += v.z; a.w += v.w;
  }
  *(float4*)(xef + i0) = a;
}

// ---------------------------------------------------------------------------
// K3: kvp -> bf16 kpT/vpb for MFMA k_sa (unchanged).
// ---------------------------------------------------------------------------
__global__ __launch_bounds__(256) void k_kv4b(const float* __restrict__ Wsaf,
                                              const float* __restrict__ xef,
                                              const float* __restrict__ invsa,
                                              u16* __restrict__ kpT,
                                              u16* __restrict__ vpb){
  const int t = threadIdx.x;
  const int ri = t >> 6, p = t & 63;
  const int r = blockIdx.x * 4 + ri, b = blockIdx.y;
  const int row_w = (r < 256) ? (256 + r) : (512 + r);
  const float* wr = Wsaf + (size_t)row_w * 256;
  const float* xr = xef + (size_t)(b * 256) * 64 + p;
  float acc = 0.f;
  for(int c = 0; c < 256; c++)
    acc += wr[c] * xr[(size_t)c * 64];
  if(r < 256){
    const float sc = invsa[b * 256 + r];
    kpT[((size_t)(b * 8 + (r >> 5)) * 64 + p) * 32 + (r & 31)] = f2bf(acc * sc);
  } else {
    const int rv = r - 256;
    vpb[((size_t)(b * 8 + (rv >> 5)) * 32 + (rv & 31)) * 64 + p] = f2bf(acc);
  }
}

// ---------------------------------------------------------------------------
// K4: dst[b*256+r] = 1 / max(||row||_2, 1e-12), LDS tree reduction.
// ---------------------------------------------------------------------------
__global__ __launch_bounds__(256) void k_norm(const u16* __restrict__ src,
                                              float* __restrict__ dst,
                                              int stride_b, int row_off){
  __shared__ float red[256];
  const int r = blockIdx.x, b = blockIdx.y, t = threadIdx.x;
  const u16* row = src + (size_t)(b * stride_b + row_off + r) * 4096;
  float s = 0.f;
  #pragma unroll
  for(int i = 0; i < 16; i++){ float v = bf2f(row[t + 256 * i]); s += v * v; }
  red[t] = s;
  __syncthreads();
  for(int s2 = 128; s2 > 0; s2 >>= 1){
    if(t < s2) red[t] += red[t + s2];
    __syncthreads();
  }
  if(t == 0) dst[b * 256 + r] = 1.0f / fmaxf(sqrtf(red[0]), 1e-12f);
}

// ---------------------------------------------------------------------------
// K5: MFMA Gram partials (Y rows: qc at 256+, kc at 512+).
// ---------------------------------------------------------------------------
__device__ __forceinline__ bf16x8 ld_frag8(const u16* p){
  short4v lo = *(const short4v*)p;
  short4v hi = *(const short4v*)(p + 4);
  bf16x8 r;
  r[0]=lo[0]; r[1]=lo[1]; r[2]=lo[2]; r[3]=lo[3];
  r[4]=hi[0]; r[5]=hi[1]; r[6]=hi[2]; r[7]=hi[3];
  return r;
}

__global__ __launch_bounds__(256) void k_gram_mfma(const u16* __restrict__ Y,
                                                   float* __restrict__ Gp){
  const int t = threadIdx.x;
  const int s = blockIdx.x, h = blockIdx.y, b = blockIdx.z;
  const int w = t >> 6, lane = t & 63;
  const int fm = lane & 15, fq = lane >> 4;
  const int j0 = (w >> 1) * 16, e0 = (w & 1) * 16;
  const u16* qrow = Y + (size_t)(b * 1024 + 256 + h * 32 + j0 + fm) * 4096;
  const u16* krow = Y + (size_t)(b * 1024 + 512 + h * 32 + e0 + fm) * 4096;
  f32x4 acc = {};
  const int nb0 = s * 512 + fq * 8;
  #pragma unroll 4
  for(int it = 0; it < 16; it++){
    const int nb = nb0 + it * 32;
    bf16x8 a  = ld_frag8(qrow + nb);
    bf16x8 bb = ld_frag8(krow + nb);
    acc = __builtin_amdgcn_mfma_f32_16x16x32_bf16(a, bb, acc, 0, 0, 0);
  }
  float* dst = Gp + ((size_t)((s * 8 + b) * 8 + h) * 1024);
  #pragma unroll
  for(int r = 0; r < 4; r++)
    dst[(j0 + fq * 4 + r) * 32 + e0 + fm] = acc[r];
}

// ---------------------------------------------------------------------------
// K5b: channel softmax (unchanged).
// ---------------------------------------------------------------------------
__global__ void k_softmax_ca(const float* __restrict__ Gp,
                             const float* __restrict__ invq,
                             const float* __restrict__ invk,
                             const float* __restrict__ temp,
                             float* __restrict__ attn){
  const int j = threadIdx.x, h = blockIdx.x, b = blockIdx.y;
  const float tm = temp[h];
  const float iq = invq[b * 256 + h * 32 + j];
  float v[32];
  float m = -1e30f;
  #pragma unroll
  for(int e = 0; e < 32; e++){
    float g = 0.f;
    #pragma unroll
    for(int s = 0; s < 8; s++)
      g += Gp[(size_t)s * 65536 + (size_t)(b * 8 + h) * 1024 + j * 32 + e];
    float val = g * iq * invk[b * 256 + h * 32 + e] * tm;
    v[e] = val; m = fmaxf(m, val);
  }
  float sum = 0.f;
  #pragma unroll
  for(int e = 0; e < 32; e++){ v[e] = __expf(v[e] - m); sum += v[e]; }
  const float inv = 1.0f / sum;
  #pragma unroll
  for(int e = 0; e < 32; e++) attn[(size_t)(b * 8 + h) * 1024 + j * 32 + e] = v[e] * inv;
}

// ---------------------------------------------------------------------------
// K6: full-MFMA spatial attention (q rows now at Y base, stride_b 1024).
// ---------------------------------------------------------------------------
__global__ __launch_bounds__(256) void k_sa_mfma(const u16* __restrict__ Y,
                                                 const u16* __restrict__ kpT,
                                                 const u16* __restrict__ vpb,
                                                 const float* __restrict__ temp2,
                                                 u16* __restrict__ xsa){
  __shared__ u16 As[64][36];    // [n][j]  q^T tile
  __shared__ u16 Ks[64][36];    // [p][j]  scaled k_proj^T
  __shared__ u16 Vs[32][68];    // [jv][p] v_proj
  __shared__ u16 Ps[64][68];    // [n][p]  unnormalized probs (wave-private rows)
  __shared__ u16 Cs[32][68];    // [jv][n] output transpose
  const int t = threadIdx.x;
  const int ntile = blockIdx.x, h = blockIdx.y, b = blockIdx.z;
  const int n0 = ntile * 64;
  const int w = t >> 6, lane = t & 63;
  const int fm = lane & 15, fq = lane >> 4;
  {
    const int j = t >> 3, ns = (t & 7) * 8;
    const u16* src = Y + (size_t)(b * 1024 + h * 32 + j) * 4096 + n0 + ns;
    uint4 v = *(const uint4*)src;
    u16 e[8]; *(uint4*)e = v;
    #pragma unroll
    for(int i = 0; i < 8; i++) As[ns + i][j] = e[i];
  }
  {
    const int p = t >> 2, jb = (t & 3) * 8;
    *(uint4*)&Ks[p][jb] =
      *(const uint4*)(kpT + ((size_t)(b * 8 + h) * 64 + p) * 32 + jb);
  }
  {
    const int jv = t >> 3, ps = (t & 7) * 8;
    *(uint4*)&Vs[jv][ps] =
      *(const uint4*)(vpb + ((size_t)(b * 8 + h) * 32 + jv) * 64 + ps);
  }
  __syncthreads();
  bf16x8 a = ld_frag8(&As[w * 16 + fm][fq * 8]);
  f32x4 lg[4];
  #pragma unroll
  for(int pt = 0; pt < 4; pt++){
    bf16x8 bk = ld_frag8(&Ks[pt * 16 + fm][fq * 8]);
    f32x4 z = {};
    lg[pt] = __builtin_amdgcn_mfma_f32_16x16x32_bf16(a, bk, z, 0, 0, 0);
  }
  const float tm = temp2[h];
  float sinv[4];
  #pragma unroll
  for(int r = 0; r < 4; r++){
    float v0 = lg[0][r]*tm, v1 = lg[1][r]*tm, v2 = lg[2][r]*tm, v3 = lg[3][r]*tm;
    float mx = fmaxf(fmaxf(v0, v1), fmaxf(v2, v3));
    #pragma unroll
    for(int m = 1; m < 16; m <<= 1) mx = fmaxf(mx, __shfl_xor(mx, m, 16));
    v0 = __expf(v0 - mx); v1 = __expf(v1 - mx);
    v2 = __expf(v2 - mx); v3 = __expf(v3 - mx);
    float s = v0 + v1 + v2 + v3;
    #pragma unroll
    for(int m = 1; m < 16; m <<= 1) s += __shfl_xor(s, m, 16);
    sinv[r] = 1.0f / s;
    const int nrow = w * 16 + fq * 4 + r;
    Ps[nrow][fm]      = f2bf(v0);
    Ps[nrow][16 + fm] = f2bf(v1);
    Ps[nrow][32 + fm] = f2bf(v2);
    Ps[nrow][48 + fm] = f2bf(v3);
  }
  f32x4 o[2] = {};
  #pragma unroll
  for(int ks = 0; ks < 2; ks++){
    bf16x8 ap = ld_frag8(&Ps[w * 16 + fm][ks * 32 + fq * 8]);
    #pragma unroll
    for(int jt = 0; jt < 2; jt++){
      bf16x8 bv = ld_frag8(&Vs[jt * 16 + fm][ks * 32 + fq * 8]);
      o[jt] = __builtin_amdgcn_mfma_f32_16x16x32_bf16(ap, bv, o[jt], 0, 0, 0);
    }
  }
  #pragma unroll
  for(int jt = 0; jt < 2; jt++)
    #pragma unroll
    for(int r = 0; r < 4; r++)
      Cs[jt * 16 + fm][w * 16 + fq * 4 + r] = f2bf(o[jt][r] * sinv[r]);
  __syncthreads();
  {
    const int jv = t >> 3, ns = (t & 7) * 8;
    u16 e[8];
    #pragma unroll
    for(int i = 0; i < 8; i++) e[i] = Cs[jv][ns + i];
    *(uint4*)(xsa + ((size_t)(b * 8 + h) * 32 + jv) * 4096 + n0 + ns) = *(uint4*)e;
  }
}

// ---------------------------------------------------------------------------
// K7: tiled out-writer (vc rows now at Y offset 768, stride_b 1024).
// ---------------------------------------------------------------------------
__global__ __launch_bounds__(256) void k_out2(const u16* __restrict__ Y,
                                              const float* __restrict__ attn,
                                              const u16* __restrict__ xsa,
                                              float* __restrict__ out){
  __shared__ u16 VcL[32][520];
  __shared__ u16 xs[32][16][34];
  __shared__ float arL[32][32];
  const int t = threadIdx.x;
  const int jg = blockIdx.x, hc = blockIdx.y, b = blockIdx.z;
  const int nn0 = jg * 512;
  {
    const float* ap = attn + (size_t)(b * 8 + hc) * 1024;
    #pragma unroll
    for(int i = 0; i < 4; i++) ((float*)arL)[t + 256 * i] = ap[t + 256 * i];
  }
  {
    const int e = t >> 3, ch = (t & 7) * 64;
    const u16* src = Y + (size_t)(b * 1024 + 768 + hc * 32 + e) * 4096 + nn0 + ch;
    #pragma unroll
    for(int i = 0; i < 8; i++)
      *(uint4*)&VcL[e][ch + i * 8] = *(const uint4*)(src + i * 8);
  }
  #pragma unroll
  for(int rep = 0; rep < 2; rep++){
    const int s = rep * 256 + t;
    const int hj = s >> 4, nh = s & 15;
    const int h = hj & 7, jj = hj >> 3;
    const u16* src = xsa + ((size_t)(b * 8 + h) * 32 + jg * 4 + jj) * 4096 + nh * 256 + hc * 32;
    uint4 v0 = *(const uint4*)src;
    uint4 v1 = *(const uint4*)(src + 8);
    u16* dst = &xs[hj][nh][0];
    u32* d32 = (u32*)dst;
    d32[0] = v0.x; d32[1] = v0.y; d32[2] = v0.z; d32[3] = v0.w;
    d32[4] = v1.x; d32[5] = v1.y; d32[6] = v1.z; d32[7] = v1.w;
    uint4 v2 = *(const uint4*)(src + 16);
    uint4 v3 = *(const uint4*)(src + 24);
    d32[8]  = v2.x; d32[9]  = v2.y; d32[10] = v2.z; d32[11] = v2.w;
    d32[12] = v3.x; d32[13] = v3.y; d32[14] = v3.z; d32[15] = v3.w;
  }
  __syncthreads();
  const int nl0 = 2 * t;
  const int hj0 = nl0 >> 4, nh0 = nl0 & 15;
  for(int row = 0; row < 32; row++){
    float acc0 = 0.f, acc1 = 0.f;
    #pragma unroll
    for(int e = 0; e < 32; e++){
      const float a = arL[row][e];
      const u32 v = *(const u32*)&VcL[e][nl0];
      acc0 += a * bf2f((u16)(v & 0xFFFF));
      acc1 += a * bf2f((u16)(v >> 16));
    }
    const float sa0 = bf2f(xs[hj0][nh0][row]);
    const float sa1 = bf2f(xs[hj0][nh0 + 1][row]);
    float2 o; o.x = acc0 + sa0; o.y = acc1 + sa1;
    *(float2*)&out[(size_t)(b * 256 + hc * 32 + row) * 4096 + nn0 + nl0] = o;
  }
}

// ---------------------------------------------------------------------------
// Workspace layout (bytes), total ~101.8 MB.
//   xsa overlays xb (xb dead after k_xef8); xefp overlays xT (dead after k_qkv).
// ---------------------------------------------------------------------------
#define OFF_XB    ((size_t)0)            // u16 [8][256][4096]  16,777,216 (reused as xsa)
#define OFF_XT    ((size_t)16777216)     // u16 [8][4096][256]  16,777,216 (reused as xefp)
#define OFF_Y     ((size_t)33554432)     // u16 [8][1024][4096] 67,108,864
#define OFF_WSAF  ((size_t)100663296)    // f32 [1024][256]      1,048,576
#define OFF_WCAT  ((size_t)101711872)    // u16 [1024][256]        524,288
#define OFF_EFF   ((size_t)102236160)    // f32 [4096][64]       1,048,576
#define OFF_XEF   ((size_t)103284736)    // f32 [8][256][64]       524,288
#define OFF_KPT   ((size_t)103809024)    // u16 [8][8][64][32]     262,144
#define OFF_VPB   ((size_t)104071168)    // u16 [8][8][32][64]     262,144
#define OFF_ISA   ((size_t)104333312)    // f32 [8][256]             8,192
#define OFF_IQC   ((size_t)104341504)
#define OFF_IKC   ((size_t)104349696)
#define OFF_GP    ((size_t)104357888)    // f32 [8][8][8][32][32] 2,097,152
#define OFF_ATT   ((size_t)106455040)    // f32 [8][8][32][32]      262,144
#define OFF_TF    ((size_t)106717184)    // f32 [16]
#define OFF_FLAG  ((size_t)106717248)    // u32
#define OFF_XEFP  OFF_XT                 // f32 [8][8][256][64]   4,194,304 (overlay)

extern "C" void kernel_launch(void* const* d_in, const int* in_sizes, int n_in,
                              void* d_out, int out_size, void* d_ws, size_t ws_size,
                              hipStream_t stream){
  (void)in_sizes; (void)n_in; (void)out_size; (void)ws_size;
  char* ws = (char*)d_ws;
  u16*   xb    = (u16*)  (ws + OFF_XB);
  u16*   xsa   = (u16*)  (ws + OFF_XB);    // overlay
  u16*   xT    = (u16*)  (ws + OFF_XT);
  u16*   Y     = (u16*)  (ws + OFF_Y);
  float* Wsaf  = (float*)(ws + OFF_WSAF);
  u16*   Wcat  = (u16*)  (ws + OFF_WCAT);
  float* EFf   = (float*)(ws + OFF_EFF);
  float* xef   = (float*)(ws + OFF_XEF);
  u16*   kpT   = (u16*)  (ws + OFF_KPT);
  u16*   vpb   = (u16*)  (ws + OFF_VPB);
  float* invsa = (float*)(ws + OFF_ISA);
  float* invqc = (float*)(ws + OFF_IQC);
  float* invkc = (float*)(ws + OFF_IKC);
  float* Gp    = (float*)(ws + OFF_GP);
  float* attn  = (float*)(ws + OFF_ATT);
  float* tf    = (float*)(ws + OFF_TF);
  u32*   flag  = (u32*)  (ws + OFF_FLAG);
  float* xefp  = (float*)(ws + OFF_XEFP);  // overlay on xT (dead after k_qkv)
  float* out = (float*)d_out;

  // dtype detect + canonicalize (+ x transpose)
  k_detect<<<1, 256, 0, stream>>>((const u16*)d_in[0], flag);
  k_convT<<<dim3(64, 4, 8), 256, 0, stream>>>(d_in[0], xb, xT, flag);
  k_conv_both<<<256, 256, 0, stream>>>(d_in[1], Wsaf, Wcat, 262144, 65536, flag); // W_sa: f32 full + bf16 q rows
  k_conv_f32 <<<256, 256, 0, stream>>>(d_in[2], EFf, 262144, flag);               // EF -> f32
  k_conv_bf  <<<96,  256, 0, stream>>>(d_in[4], Wcat + 65536, 196608, flag);      // W_sc rows 0:768 -> Wcat 256:1024
  k_conv_f32 <<<1,   256, 0, stream>>>(d_in[3], tf,      8, flag);                // temp2_sa
  k_conv_f32 <<<1,   256, 0, stream>>>(d_in[5], tf + 8,  8, flag);                // temp_sc

  // Fused QKV GEMM (q | qc | kc | vc), m97 structure
  k_qkv<<<dim3(32, 8, 8), 256, 0, stream>>>(Wcat, xT, Y);
  // Linformer projection: split-K xef partials + reduce (xefp overlays dead xT)
  k_xef8<<<dim3(8, 8, 8), 256, 0, stream>>>(xb, EFf, xefp);
  k_xred<<<128, 256, 0, stream>>>(xefp, xef);
  // L2 norms
  k_norm<<<dim3(256, 8), 256, 0, stream>>>(Y, invsa, 1024, 0);
  k_norm<<<dim3(256, 8), 256, 0, stream>>>(Y, invqc, 1024, 256);
  k_norm<<<dim3(256, 8), 256, 0, stream>>>(Y, invkc, 1024, 512);
  // kpT (scaled) + vpb, bf16
  k_kv4b<<<dim3(128, 8), 256, 0, stream>>>(Wsaf, xef, invsa, kpT, vpb);
  // Channel attention matrix (MFMA gram) + softmax
  k_gram_mfma<<<dim3(8, 8, 8), 256, 0, stream>>>(Y, Gp);
  k_softmax_ca<<<dim3(8, 8), 32, 0, stream>>>(Gp, invqc, invkc, tf + 8, attn);
  // Spatial attention (full MFMA) -> xsa, then tiled scramble-gather -> fp32 out
  k_sa_mfma<<<dim3(64, 8, 8), 256, 0, stream>>>(Y, kpT, vpb, tf, xsa);
  k_out2<<<dim3(8, 8, 8), 256, 0, stream>>>(Y, attn, xsa, out);
}

// Round 2
// 231.346 us; speedup vs baseline: 1.2554x; 1.1117x over previous
//
#include <hip/hip_runtime.h>

typedef unsigned short u16;
typedef unsigned int   u32;

typedef __attribute__((ext_vector_type(4))) short short4v;
typedef __attribute__((ext_vector_type(8))) short bf16x8;  // 8 bf16 (4 VGPRs)
typedef __attribute__((ext_vector_type(4))) float f32x4;

// Problem: B=8, C=256, N=4096, heads=8, d=32, P=64. Inputs fp32 (auto-detect),
// output FP32. r13: fused QKV GEMM (m97 structure) on xT. r14: xef = x@EF moved
// to MFMA (split-K, direct-global fragments, EF pre-transposed to bf16 EFT).

__device__ __forceinline__ float bf2f(u16 u){
  union { u32 i; float f; } v; v.i = ((u32)u) << 16; return v.f;
}
__device__ __forceinline__ u16 f2bf(float f){
  u32 u = __float_as_uint(f);
  u32 r = u + 0x7FFFu + ((u >> 16) & 1u);   // RNE
  return (u16)(r >> 16);
}

__device__ __forceinline__ void gload_lds16(const u16* g, u16* l){
  __builtin_amdgcn_global_load_lds((const __attribute__((address_space(1))) void*)g,
                                   (__attribute__((address_space(3))) void*)l,
                                   16, 0, 0);
}

// ---------------------------------------------------------------------------
// K0a: dtype detector on x. flag=1 => fp32 input.
// ---------------------------------------------------------------------------
__global__ void k_detect(const u16* __restrict__ x, u32* __restrict__ flag){
  __shared__ int cnt[256];
  const int t = threadIdx.x;
  int c = 0;
  #pragma unroll
  for(int i = 0; i < 4; i++){
    u16 v = x[t * 4 + i];
    int e = (v >> 7) & 0xFF;
    if(e >= 112 && e <= 134) c++;
  }
  cnt[t] = c;
  __syncthreads();
  for(int s = 128; s > 0; s >>= 1){
    if(t < s) cnt[t] += cnt[t + s];
    __syncthreads();
  }
  if(t == 0) *flag = (cnt[0] < 800) ? 1u : 0u;
}

// ---------------------------------------------------------------------------
// K0b: canonicalize to bf16 (8 elems/thread).
// ---------------------------------------------------------------------------
__global__ __launch_bounds__(256) void k_conv_bf(const void* __restrict__ src,
                                                 u16* __restrict__ dst, int n,
                                                 const u32* __restrict__ flag){
  const int i0 = (blockIdx.x * 256 + threadIdx.x) * 8;
  if(i0 >= n) return;
  const bool isf32 = (*flag != 0);
  if(isf32){
    const float4 a = *(const float4*)((const float*)src + i0);
    const float4 b = *(const float4*)((const float*)src + i0 + 4);
    uint4 o;
    o.x = (u32)f2bf(a.x) | ((u32)f2bf(a.y) << 16);
    o.y = (u32)f2bf(a.z) | ((u32)f2bf(a.w) << 16);
    o.z = (u32)f2bf(b.x) | ((u32)f2bf(b.y) << 16);
    o.w = (u32)f2bf(b.z) | ((u32)f2bf(b.w) << 16);
    *(uint4*)(dst + i0) = o;
  } else {
    *(uint4*)(dst + i0) = *(const uint4*)((const u16*)src + i0);
  }
}

// ---------------------------------------------------------------------------
// K0c: canonicalize to fp32 (4 elems/thread).
// ---------------------------------------------------------------------------
__global__ __launch_bounds__(256) void k_conv_f32(const void* __restrict__ src,
                                                  float* __restrict__ dst, int n,
                                                  const u32* __restrict__ flag){
  const int i0 = (blockIdx.x * 256 + threadIdx.x) * 4;
  if(i0 >= n) return;
  const bool isf32 = (*flag != 0);
  if(isf32){
    *(float4*)(dst + i0) = *(const float4*)((const float*)src + i0);
  } else {
    const uint2 a = *(const uint2*)((const u16*)src + i0);
    float4 o;
    o.x = bf2f((u16)(a.x & 0xFFFF)); o.y = bf2f((u16)(a.x >> 16));
    o.z = bf2f((u16)(a.y & 0xFFFF)); o.w = bf2f((u16)(a.y >> 16));
    *(float4*)(dst + i0) = o;
  }
}

// ---------------------------------------------------------------------------
// K0d: canonicalize to fp32 (all n) + bf16 (first nb elems) — for W_sa.
// ---------------------------------------------------------------------------
__global__ __launch_bounds__(256) void k_conv_both(const void* __restrict__ src,
                                                   float* __restrict__ dstf,
                                                   u16* __restrict__ dstb, int n,
                                                   int nb,
                                                   const u32* __restrict__ flag){
  const int i0 = (blockIdx.x * 256 + threadIdx.x) * 4;
  if(i0 >= n) return;
  const bool isf32 = (*flag != 0);
  float4 o;
  if(isf32){
    o = *(const float4*)((const float*)src + i0);
  } else {
    const uint2 a = *(const uint2*)((const u16*)src + i0);
    o.x = bf2f((u16)(a.x & 0xFFFF)); o.y = bf2f((u16)(a.x >> 16));
    o.z = bf2f((u16)(a.y & 0xFFFF)); o.w = bf2f((u16)(a.y >> 16));
  }
  *(float4*)(dstf + i0) = o;
  if(i0 < nb){
    uint2 pk;
    pk.x = (u32)f2bf(o.x) | ((u32)f2bf(o.y) << 16);
    pk.y = (u32)f2bf(o.z) | ((u32)f2bf(o.w) << 16);
    *(uint2*)(dstb + i0) = pk;
  }
}

// ---------------------------------------------------------------------------
// K0e: x -> xb[b][c][n] bf16 AND xT[b][n][c] bf16 (LDS 64x64 transpose).
// ---------------------------------------------------------------------------
__global__ __launch_bounds__(256) void k_convT(const void* __restrict__ src,
                                               u16* __restrict__ xb,
                                               u16* __restrict__ xT,
                                               const u32* __restrict__ flag){
  __shared__ u16 T[64][72];
  const int t = threadIdx.x;
  const int n0 = blockIdx.x * 64, c0 = blockIdx.y * 64, b = blockIdx.z;
  const int cl = t >> 2, ns = (t & 3) * 16;
  const bool isf32 = (*flag != 0);
  const size_t srcoff = ((size_t)(b * 256 + c0 + cl)) * 4096 + n0 + ns;
  u16 e[16];
  if(isf32){
    const float* sp = (const float*)src + srcoff;
    #pragma unroll
    for(int i = 0; i < 4; i++){
      const float4 v = *(const float4*)(sp + i * 4);
      e[i*4+0] = f2bf(v.x); e[i*4+1] = f2bf(v.y);
      e[i*4+2] = f2bf(v.z); e[i*4+3] = f2bf(v.w);
    }
  } else {
    const u16* sp = (const u16*)src + srcoff;
    *(uint4*)&e[0] = *(const uint4*)sp;
    *(uint4*)&e[8] = *(const uint4*)(sp + 8);
  }
  u16* xbp = xb + srcoff;
  *(uint4*)xbp       = *(uint4*)&e[0];
  *(uint4*)(xbp + 8) = *(uint4*)&e[8];
  #pragma unroll
  for(int i = 0; i < 16; i++) T[ns + i][cl] = e[i];
  __syncthreads();
  const int nl = t >> 2, cs = (t & 3) * 16;
  u16* xtp = xT + ((size_t)b * 4096 + n0 + nl) * 256 + c0 + cs;
  *(uint4*)xtp       = *(const uint4*)&T[nl][cs];
  *(uint4*)(xtp + 8) = *(const uint4*)&T[nl][cs + 8];
}

// ---------------------------------------------------------------------------
// K0f (new): EF[n][p] -> EFT[p][n] bf16 (LDS 64x64 transpose). Grid 64.
// ---------------------------------------------------------------------------
__global__ __launch_bounds__(256) void k_conv_efT(const void* __restrict__ src,
                                                  u16* __restrict__ EFT,
                                                  const u32* __restrict__ flag){
  __shared__ u16 T[64][72];
  const int t = threadIdx.x;
  const int n0 = blockIdx.x * 64;
  const int nl = t >> 2, p0 = (t & 3) * 16;
  const bool isf32 = (*flag != 0);
  const size_t off = (size_t)(n0 + nl) * 64 + p0;
  u16 e[16];
  if(isf32){
    const float* sp = (const float*)src + off;
    #pragma unroll
    for(int i = 0; i < 4; i++){
      const float4 v = *(const float4*)(sp + i * 4);
      e[i*4+0] = f2bf(v.x); e[i*4+1] = f2bf(v.y);
      e[i*4+2] = f2bf(v.z); e[i*4+3] = f2bf(v.w);
    }
  } else {
    const u16* sp = (const u16*)src + off;
    *(uint4*)&e[0] = *(const uint4*)sp;
    *(uint4*)&e[8] = *(const uint4*)(sp + 8);
  }
  #pragma unroll
  for(int i = 0; i < 16; i++) T[p0 + i][nl] = e[i];
  __syncthreads();
  const int pr = t >> 2, nn = (t & 3) * 16;
  u16* dp = EFT + (size_t)pr * 4096 + n0 + nn;
  *(uint4*)dp       = *(const uint4*)&T[pr][nn];
  *(uint4*)(dp + 8) = *(const uint4*)&T[pr][nn + 8];
}

// ---------------------------------------------------------------------------
// K1: fused QKV GEMM, m97 structure (unchanged from r13).
// ---------------------------------------------------------------------------
__global__ __launch_bounds__(256) void k_qkv(const u16* __restrict__ Wc,
                                             const u16* __restrict__ xT,
                                             u16* __restrict__ Y){
  __shared__ union {
    struct { u16 Ws[128][64]; u16 Xs[128][64]; } s;
    u16 Cs[128][136];
  } L;
  const int t = threadIdx.x;
  const int n0 = blockIdx.x * 128, m0 = blockIdx.y * 128, b = blockIdx.z;
  const int w = t >> 6, lane = t & 63;
  const int fm = lane & 15, fq = lane >> 4;
  const int wm = w >> 1, wn = w & 1;
  const int lr = lane >> 3, lc = (lane & 7) * 8;
  const u16* gw = Wc + (size_t)m0 * 256;
  const u16* gx = xT + ((size_t)b * 4096 + n0) * 256;
  f32x4 acc[4][4] = {};
  for(int kc = 0; kc < 256; kc += 64){
    #pragma unroll
    for(int i = 0; i < 4; i++){
      const int row = w * 32 + i * 8;          // wave-uniform LDS base row
      gload_lds16(gw + (size_t)(row + lr) * 256 + kc + lc, &L.s.Ws[row][0]);
      gload_lds16(gx + (size_t)(row + lr) * 256 + kc + lc, &L.s.Xs[row][0]);
    }
    __syncthreads();
    #pragma unroll
    for(int kh = 0; kh < 2; kh++){
      bf16x8 af[4], bx[4];
      #pragma unroll
      for(int mt = 0; mt < 4; mt++)
        af[mt] = *(const bf16x8*)&L.s.Ws[wm * 64 + mt * 16 + fm][kh * 32 + fq * 8];
      #pragma unroll
      for(int nt = 0; nt < 4; nt++)
        bx[nt] = *(const bf16x8*)&L.s.Xs[wn * 64 + nt * 16 + fm][kh * 32 + fq * 8];
      #pragma unroll
      for(int mt = 0; mt < 4; mt++)
        #pragma unroll
        for(int nt = 0; nt < 4; nt++)
          acc[mt][nt] = __builtin_amdgcn_mfma_f32_16x16x32_bf16(af[mt], bx[nt],
                                                                acc[mt][nt], 0, 0, 0);
    }
    __syncthreads();
  }
  #pragma unroll
  for(int mt = 0; mt < 4; mt++)
    #pragma unroll
    for(int nt = 0; nt < 4; nt++)
      #pragma unroll
      for(int r = 0; r < 4; r++)
        L.Cs[wm * 64 + mt * 16 + fq * 4 + r][wn * 64 + nt * 16 + fm] =
          f2bf(acc[mt][nt][r]);
  __syncthreads();
  #pragma unroll
  for(int i = 0; i < 8; i++){
    const int row = i * 16 + (t >> 4), ce = (t & 15) * 8;
    *(uint4*)(Y + ((size_t)b * 1024 + m0 + row) * 4096 + n0 + ce) =
      *(const uint4*)&L.Cs[row][ce];
  }
}

// ---------------------------------------------------------------------------
// K2 (new): split-K MFMA xef partials. xefp[s][b][c][p] = xb[b][c][ks]·EFT[p][ks].
// Grid (2 m-half, 16 k-split, 8 b), 4 waves; wave owns 32 c-rows, full P=64.
// ---------------------------------------------------------------------------
__global__ __launch_bounds__(256) void k_xef_mfma(const u16* __restrict__ xb,
                                                  const u16* __restrict__ EFT,
                                                  float* __restrict__ xefp){
  const int t = threadIdx.x;
  const int mh = blockIdx.x, s = blockIdx.y, b = blockIdx.z;
  const int w = t >> 6, lane = t & 63;
  const int fm = lane & 15, fq = lane >> 4;
  const int c0 = mh * 128 + w * 32;
  const u16* ar = xb + ((size_t)(b * 256 + c0 + fm)) * 4096 + s * 256 + fq * 8;
  const u16* br = EFT + (size_t)fm * 4096 + s * 256 + fq * 8;
  f32x4 acc[2][4] = {};
  #pragma unroll
  for(int kk = 0; kk < 8; kk++){
    bf16x8 bfr[4];
    #pragma unroll
    for(int nt = 0; nt < 4; nt++)
      bfr[nt] = *(const bf16x8*)(br + (size_t)nt * 16 * 4096 + kk * 32);
    #pragma unroll
    for(int mt = 0; mt < 2; mt++){
      bf16x8 af = *(const bf16x8*)(ar + (size_t)mt * 16 * 4096 + kk * 32);
      #pragma unroll
      for(int nt = 0; nt < 4; nt++)
        acc[mt][nt] = __builtin_amdgcn_mfma_f32_16x16x32_bf16(af, bfr[nt],
                                                              acc[mt][nt], 0, 0, 0);
    }
  }
  float* dst = xefp + (size_t)s * 131072 + (size_t)(b * 256 + c0) * 64;
  #pragma unroll
  for(int mt = 0; mt < 2; mt++)
    #pragma unroll
    for(int nt = 0; nt < 4; nt++)
      #pragma unroll
      for(int r = 0; r < 4; r++)
        dst[(mt * 16 + fq * 4 + r) * 64 + nt * 16 + fm] = acc[mt][nt][r];
}

// ---------------------------------------------------------------------------
// K2b: reduce partials: xef[i] = sum_s xefp[s][i] (16 slices).
// ---------------------------------------------------------------------------
__global__ __launch_bounds__(256) void k_xred(const float* __restrict__ xefp,
                                              float* __restrict__ xef){
  const int i0 = (blockIdx.x * 256 + threadIdx.x) * 4;
  float4 a = *(const float4*)(xefp + i0);
  #pragma unroll
  for(int s = 1; s < 16; s++){
    const float4 v = *(const float4*)(xefp + (size_t)s * 131072 + i0);
    a.x += v.x; a.y += v.y; a.z += v.z; a.w += v.w;
  }
  *(float4*)(xef + i0) = a;
}

// ---------------------------------------------------------------------------
// K3: kvp -> bf16 kpT/vpb (unchanged).
// ---------------------------------------------------------------------------
__global__ __launch_bounds__(256) void k_kv4b(const float* __restrict__ Wsaf,
                                              const float* __restrict__ xef,
                                              const float* __restrict__ invsa,
                                              u16* __restrict__ kpT,
                                              u16* __restrict__ vpb){
  const int t = threadIdx.x;
  const int ri = t >> 6, p = t & 63;
  const int r = blockIdx.x * 4 + ri, b = blockIdx.y;
  const int row_w = (r < 256) ? (256 + r) : (512 + r);
  const float* wr = Wsaf + (size_t)row_w * 256;
  const float* xr = xef + (size_t)(b * 256) * 64 + p;
  float acc = 0.f;
  for(int c = 0; c < 256; c++)
    acc += wr[c] * xr[(size_t)c * 64];
  if(r < 256){
    const float sc = invsa[b * 256 + r];
    kpT[((size_t)(b * 8 + (r >> 5)) * 64 + p) * 32 + (r & 31)] = f2bf(acc * sc);
  } else {
    const int rv = r - 256;
    vpb[((size_t)(b * 8 + (rv >> 5)) * 32 + (rv & 31)) * 64 + p] = f2bf(acc);
  }
}

// ---------------------------------------------------------------------------
// K4: dst[b*256+r] = 1 / max(||row||_2, 1e-12), LDS tree reduction.
// ---------------------------------------------------------------------------
__global__ __launch_bounds__(256) void k_norm(const u16* __restrict__ src,
                                              float* __restrict__ dst,
                                              int stride_b, int row_off){
  __shared__ float red[256];
  const int r = blockIdx.x, b = blockIdx.y, t = threadIdx.x;
  const u16* row = src + (size_t)(b * stride_b + row_off + r) * 4096;
  float s = 0.f;
  #pragma unroll
  for(int i = 0; i < 16; i++){ float v = bf2f(row[t + 256 * i]); s += v * v; }
  red[t] = s;
  __syncthreads();
  for(int s2 = 128; s2 > 0; s2 >>= 1){
    if(t < s2) red[t] += red[t + s2];
    __syncthreads();
  }
  if(t == 0) dst[b * 256 + r] = 1.0f / fmaxf(sqrtf(red[0]), 1e-12f);
}

// ---------------------------------------------------------------------------
// K5: MFMA Gram partials (unchanged).
// ---------------------------------------------------------------------------
__device__ __forceinline__ bf16x8 ld_frag8(const u16* p){
  short4v lo = *(const short4v*)p;
  short4v hi = *(const short4v*)(p + 4);
  bf16x8 r;
  r[0]=lo[0]; r[1]=lo[1]; r[2]=lo[2]; r[3]=lo[3];
  r[4]=hi[0]; r[5]=hi[1]; r[6]=hi[2]; r[7]=hi[3];
  return r;
}

__global__ __launch_bounds__(256) void k_gram_mfma(const u16* __restrict__ Y,
                                                   float* __restrict__ Gp){
  const int t = threadIdx.x;
  const int s = blockIdx.x, h = blockIdx.y, b = blockIdx.z;
  const int w = t >> 6, lane = t & 63;
  const int fm = lane & 15, fq = lane >> 4;
  const int j0 = (w >> 1) * 16, e0 = (w & 1) * 16;
  const u16* qrow = Y + (size_t)(b * 1024 + 256 + h * 32 + j0 + fm) * 4096;
  const u16* krow = Y + (size_t)(b * 1024 + 512 + h * 32 + e0 + fm) * 4096;
  f32x4 acc = {};
  const int nb0 = s * 512 + fq * 8;
  #pragma unroll 4
  for(int it = 0; it < 16; it++){
    const int nb = nb0 + it * 32;
    bf16x8 a  = ld_frag8(qrow + nb);
    bf16x8 bb = ld_frag8(krow + nb);
    acc = __builtin_amdgcn_mfma_f32_16x16x32_bf16(a, bb, acc, 0, 0, 0);
  }
  float* dst = Gp + ((size_t)((s * 8 + b) * 8 + h) * 1024);
  #pragma unroll
  for(int r = 0; r < 4; r++)
    dst[(j0 + fq * 4 + r) * 32 + e0 + fm] = acc[r];
}

// ---------------------------------------------------------------------------
// K5b: channel softmax (unchanged).
// ---------------------------------------------------------------------------
__global__ void k_softmax_ca(const float* __restrict__ Gp,
                             const float* __restrict__ invq,
                             const float* __restrict__ invk,
                             const float* __restrict__ temp,
                             float* __restrict__ attn){
  const int j = threadIdx.x, h = blockIdx.x, b = blockIdx.y;
  const float tm = temp[h];
  const float iq = invq[b * 256 + h * 32 + j];
  float v[32];
  float m = -1e30f;
  #pragma unroll
  for(int e = 0; e < 32; e++){
    float g = 0.f;
    #pragma unroll
    for(int s = 0; s < 8; s++)
      g += Gp[(size_t)s * 65536 + (size_t)(b * 8 + h) * 1024 + j * 32 + e];
    float val = g * iq * invk[b * 256 + h * 32 + e] * tm;
    v[e] = val; m = fmaxf(m, val);
  }
  float sum = 0.f;
  #pragma unroll
  for(int e = 0; e < 32; e++){ v[e] = __expf(v[e] - m); sum += v[e]; }
  const float inv = 1.0f / sum;
  #pragma unroll
  for(int e = 0; e < 32; e++) attn[(size_t)(b * 8 + h) * 1024 + j * 32 + e] = v[e] * inv;
}

// ---------------------------------------------------------------------------
// K6: full-MFMA spatial attention (unchanged).
// ---------------------------------------------------------------------------
__global__ __launch_bounds__(256) void k_sa_mfma(const u16* __restrict__ Y,
                                                 const u16* __restrict__ kpT,
                                                 const u16* __restrict__ vpb,
                                                 const float* __restrict__ temp2,
                                                 u16* __restrict__ xsa){
  __shared__ u16 As[64][36];
  __shared__ u16 Ks[64][36];
  __shared__ u16 Vs[32][68];
  __shared__ u16 Ps[64][68];
  __shared__ u16 Cs[32][68];
  const int t = threadIdx.x;
  const int ntile = blockIdx.x, h = blockIdx.y, b = blockIdx.z;
  const int n0 = ntile * 64;
  const int w = t >> 6, lane = t & 63;
  const int fm = lane & 15, fq = lane >> 4;
  {
    const int j = t >> 3, ns = (t & 7) * 8;
    const u16* src = Y + (size_t)(b * 1024 + h * 32 + j) * 4096 + n0 + ns;
    uint4 v = *(const uint4*)src;
    u16 e[8]; *(uint4*)e = v;
    #pragma unroll
    for(int i = 0; i < 8; i++) As[ns + i][j] = e[i];
  }
  {
    const int p = t >> 2, jb = (t & 3) * 8;
    *(uint4*)&Ks[p][jb] =
      *(const uint4*)(kpT + ((size_t)(b * 8 + h) * 64 + p) * 32 + jb);
  }
  {
    const int jv = t >> 3, ps = (t & 7) * 8;
    *(uint4*)&Vs[jv][ps] =
      *(const uint4*)(vpb + ((size_t)(b * 8 + h) * 32 + jv) * 64 + ps);
  }
  __syncthreads();
  bf16x8 a = ld_frag8(&As[w * 16 + fm][fq * 8]);
  f32x4 lg[4];
  #pragma unroll
  for(int pt = 0; pt < 4; pt++){
    bf16x8 bk = ld_frag8(&Ks[pt * 16 + fm][fq * 8]);
    f32x4 z = {};
    lg[pt] = __builtin_amdgcn_mfma_f32_16x16x32_bf16(a, bk, z, 0, 0, 0);
  }
  const float tm = temp2[h];
  float sinv[4];
  #pragma unroll
  for(int r = 0; r < 4; r++){
    float v0 = lg[0][r]*tm, v1 = lg[1][r]*tm, v2 = lg[2][r]*tm, v3 = lg[3][r]*tm;
    float mx = fmaxf(fmaxf(v0, v1), fmaxf(v2, v3));
    #pragma unroll
    for(int m = 1; m < 16; m <<= 1) mx = fmaxf(mx, __shfl_xor(mx, m, 16));
    v0 = __expf(v0 - mx); v1 = __expf(v1 - mx);
    v2 = __expf(v2 - mx); v3 = __expf(v3 - mx);
    float s = v0 + v1 + v2 + v3;
    #pragma unroll
    for(int m = 1; m < 16; m <<= 1) s += __shfl_xor(s, m, 16);
    sinv[r] = 1.0f / s;
    const int nrow = w * 16 + fq * 4 + r;
    Ps[nrow][fm]      = f2bf(v0);
    Ps[nrow][16 + fm] = f2bf(v1);
    Ps[nrow][32 + fm] = f2bf(v2);
    Ps[nrow][48 + fm] = f2bf(v3);
  }
  f32x4 o[2] = {};
  #pragma unroll
  for(int ks = 0; ks < 2; ks++){
    bf16x8 ap = ld_frag8(&Ps[w * 16 + fm][ks * 32 + fq * 8]);
    #pragma unroll
    for(int jt = 0; jt < 2; jt++){
      bf16x8 bv = ld_frag8(&Vs[jt * 16 + fm][ks * 32 + fq * 8]);
      o[jt] = __builtin_amdgcn_mfma_f32_16x16x32_bf16(ap, bv, o[jt], 0, 0, 0);
    }
  }
  #pragma unroll
  for(int jt = 0; jt < 2; jt++)
    #pragma unroll
    for(int r = 0; r < 4; r++)
      Cs[jt * 16 + fm][w * 16 + fq * 4 + r] = f2bf(o[jt][r] * sinv[r]);
  __syncthreads();
  {
    const int jv = t >> 3, ns = (t & 7) * 8;
    u16 e[8];
    #pragma unroll
    for(int i = 0; i < 8; i++) e[i] = Cs[jv][ns + i];
    *(uint4*)(xsa + ((size_t)(b * 8 + h) * 32 + jv) * 4096 + n0 + ns) = *(uint4*)e;
  }
}

// ---------------------------------------------------------------------------
// K7: tiled out-writer (unchanged).
// ---------------------------------------------------------------------------
__global__ __launch_bounds__(256) void k_out2(const u16* __restrict__ Y,
                                              const float* __restrict__ attn,
                                              const u16* __restrict__ xsa,
                                              float* __restrict__ out){
  __shared__ u16 VcL[32][520];
  __shared__ u16 xs[32][16][34];
  __shared__ float arL[32][32];
  const int t = threadIdx.x;
  const int jg = blockIdx.x, hc = blockIdx.y, b = blockIdx.z;
  const int nn0 = jg * 512;
  {
    const float* ap = attn + (size_t)(b * 8 + hc) * 1024;
    #pragma unroll
    for(int i = 0; i < 4; i++) ((float*)arL)[t + 256 * i] = ap[t + 256 * i];
  }
  {
    const int e = t >> 3, ch = (t & 7) * 64;
    const u16* src = Y + (size_t)(b * 1024 + 768 + hc * 32 + e) * 4096 + nn0 + ch;
    #pragma unroll
    for(int i = 0; i < 8; i++)
      *(uint4*)&VcL[e][ch + i * 8] = *(const uint4*)(src + i * 8);
  }
  #pragma unroll
  for(int rep = 0; rep < 2; rep++){
    const int s = rep * 256 + t;
    const int hj = s >> 4, nh = s & 15;
    const int h = hj & 7, jj = hj >> 3;
    const u16* src = xsa + ((size_t)(b * 8 + h) * 32 + jg * 4 + jj) * 4096 + nh * 256 + hc * 32;
    uint4 v0 = *(const uint4*)src;
    uint4 v1 = *(const uint4*)(src + 8);
    u16* dst = &xs[hj][nh][0];
    u32* d32 = (u32*)dst;
    d32[0] = v0.x; d32[1] = v0.y; d32[2] = v0.z; d32[3] = v0.w;
    d32[4] = v1.x; d32[5] = v1.y; d32[6] = v1.z; d32[7] = v1.w;
    uint4 v2 = *(const uint4*)(src + 16);
    uint4 v3 = *(const uint4*)(src + 24);
    d32[8]  = v2.x; d32[9]  = v2.y; d32[10] = v2.z; d32[11] = v2.w;
    d32[12] = v3.x; d32[13] = v3.y; d32[14] = v3.z; d32[15] = v3.w;
  }
  __syncthreads();
  const int nl0 = 2 * t;
  const int hj0 = nl0 >> 4, nh0 = nl0 & 15;
  for(int row = 0; row < 32; row++){
    float acc0 = 0.f, acc1 = 0.f;
    #pragma unroll
    for(int e = 0; e < 32; e++){
      const float a = arL[row][e];
      const u32 v = *(const u32*)&VcL[e][nl0];
      acc0 += a * bf2f((u16)(v & 0xFFFF));
      acc1 += a * bf2f((u16)(v >> 16));
    }
    const float sa0 = bf2f(xs[hj0][nh0][row]);
    const float sa1 = bf2f(xs[hj0][nh0 + 1][row]);
    float2 o; o.x = acc0 + sa0; o.y = acc1 + sa1;
    *(float2*)&out[(size_t)(b * 256 + hc * 32 + row) * 4096 + nn0 + nl0] = o;
  }
}

// ---------------------------------------------------------------------------
// Workspace layout (bytes).
// ---------------------------------------------------------------------------
#define OFF_XB    ((size_t)0)            // u16 [8][256][4096]  16,777,216 (reused as xsa)
#define OFF_XT    ((size_t)16777216)     // u16 [8][4096][256]  16,777,216 (reused as xefp)
#define OFF_Y     ((size_t)33554432)     // u16 [8][1024][4096] 67,108,864
#define OFF_WSAF  ((size_t)100663296)    // f32 [1024][256]      1,048,576
#define OFF_WCAT  ((size_t)101711872)    // u16 [1024][256]        524,288
#define OFF_EFT   ((size_t)102236160)    // u16 [64][4096]         524,288
#define OFF_XEF   ((size_t)103284736)    // f32 [8][256][64]       524,288
#define OFF_KPT   ((size_t)103809024)    // u16 [8][8][64][32]     262,144
#define OFF_VPB   ((size_t)104071168)    // u16 [8][8][32][64]     262,144
#define OFF_ISA   ((size_t)104333312)    // f32 [8][256]             8,192
#define OFF_IQC   ((size_t)104341504)
#define OFF_IKC   ((size_t)104349696)
#define OFF_GP    ((size_t)104357888)    // f32 [8][8][8][32][32] 2,097,152
#define OFF_ATT   ((size_t)106455040)    // f32 [8][8][32][32]      262,144
#define OFF_TF    ((size_t)106717184)    // f32 [16]
#define OFF_FLAG  ((size_t)106717248)    // u32
#define OFF_XEFP  OFF_XT                 // f32 [16][8][256][64]  8,388,608 (overlay)

extern "C" void kernel_launch(void* const* d_in, const int* in_sizes, int n_in,
                              void* d_out, int out_size, void* d_ws, size_t ws_size,
                              hipStream_t stream){
  (void)in_sizes; (void)n_in; (void)out_size; (void)ws_size;
  char* ws = (char*)d_ws;
  u16*   xb    = (u16*)  (ws + OFF_XB);
  u16*   xsa   = (u16*)  (ws + OFF_XB);    // overlay
  u16*   xT    = (u16*)  (ws + OFF_XT);
  u16*   Y     = (u16*)  (ws + OFF_Y);
  float* Wsaf  = (float*)(ws + OFF_WSAF);
  u16*   Wcat  = (u16*)  (ws + OFF_WCAT);
  u16*   EFT   = (u16*)  (ws + OFF_EFT);
  float* xef   = (float*)(ws + OFF_XEF);
  u16*   kpT   = (u16*)  (ws + OFF_KPT);
  u16*   vpb   = (u16*)  (ws + OFF_VPB);
  float* invsa = (float*)(ws + OFF_ISA);
  float* invqc = (float*)(ws + OFF_IQC);
  float* invkc = (float*)(ws + OFF_IKC);
  float* Gp    = (float*)(ws + OFF_GP);
  float* attn  = (float*)(ws + OFF_ATT);
  float* tf    = (float*)(ws + OFF_TF);
  u32*   flag  = (u32*)  (ws + OFF_FLAG);
  float* xefp  = (float*)(ws + OFF_XEFP);  // overlay on xT (dead after k_qkv)
  float* out = (float*)d_out;

  // dtype detect + canonicalize (+ x transpose, EF transpose)
  k_detect<<<1, 256, 0, stream>>>((const u16*)d_in[0], flag);
  k_convT<<<dim3(64, 4, 8), 256, 0, stream>>>(d_in[0], xb, xT, flag);
  k_conv_both<<<256, 256, 0, stream>>>(d_in[1], Wsaf, Wcat, 262144, 65536, flag); // W_sa: f32 full + bf16 q rows
  k_conv_efT<<<64, 256, 0, stream>>>(d_in[2], EFT, flag);                         // EF -> bf16 EFT[p][n]
  k_conv_bf  <<<96,  256, 0, stream>>>(d_in[4], Wcat + 65536, 196608, flag);      // W_sc rows 0:768 -> Wcat 256:1024
  k_conv_f32 <<<1,   256, 0, stream>>>(d_in[3], tf,      8, flag);                // temp2_sa
  k_conv_f32 <<<1,   256, 0, stream>>>(d_in[5], tf + 8,  8, flag);                // temp_sc

  // Fused QKV GEMM (q | qc | kc | vc), m97 structure
  k_qkv<<<dim3(32, 8, 8), 256, 0, stream>>>(Wcat, xT, Y);
  // Linformer projection: split-K MFMA partials + reduce (xefp overlays dead xT)
  k_xef_mfma<<<dim3(2, 16, 8), 256, 0, stream>>>(xb, EFT, xefp);
  k_xred<<<128, 256, 0, stream>>>(xefp, xef);
  // L2 norms
  k_norm<<<dim3(256, 8), 256, 0, stream>>>(Y, invsa, 1024, 0);
  k_norm<<<dim3(256, 8), 256, 0, stream>>>(Y, invqc, 1024, 256);
  k_norm<<<dim3(256, 8), 256, 0, stream>>>(Y, invkc, 1024, 512);
  // kpT (scaled) + vpb, bf16
  k_kv4b<<<dim3(128, 8), 256, 0, stream>>>(Wsaf, xef, invsa, kpT, vpb);
  // Channel attention matrix (MFMA gram) + softmax
  k_gram_mfma<<<dim3(8, 8, 8), 256, 0, stream>>>(Y, Gp);
  k_softmax_ca<<<dim3(8, 8), 32, 0, stream>>>(Gp, invqc, invkc, tf + 8, attn);
  // Spatial attention (full MFMA) -> xsa, then tiled scramble-gather -> fp32 out
  k_sa_mfma<<<dim3(64, 8, 8), 256, 0, stream>>>(Y, kpT, vpb, tf, xsa);
  k_out2<<<dim3(8, 8, 8), 256, 0, stream>>>(Y, attn, xsa, out);
}

// Round 3
// 217.052 us; speedup vs baseline: 1.3381x; 1.0659x over previous
//
#include <hip/hip_runtime.h>

typedef unsigned short u16;
typedef unsigned int   u32;

typedef __attribute__((ext_vector_type(4))) short short4v;
typedef __attribute__((ext_vector_type(8))) short bf16x8;  // 8 bf16 (4 VGPRs)
typedef __attribute__((ext_vector_type(4))) float f32x4;

// Problem: B=8, C=256, N=4096, heads=8, d=32, P=64. Inputs fp32 (auto-detect),
// output FP32. r13: fused QKV GEMM (m97). r14: MFMA xef. r15: k_out2 -> MFMA
// (split-bf16 attn hi/lo, LDS-transposed Vc), fused k_norm3, merged tf conv.

__device__ __forceinline__ float bf2f(u16 u){
  union { u32 i; float f; } v; v.i = ((u32)u) << 16; return v.f;
}
__device__ __forceinline__ u16 f2bf(float f){
  u32 u = __float_as_uint(f);
  u32 r = u + 0x7FFFu + ((u >> 16) & 1u);   // RNE
  return (u16)(r >> 16);
}

__device__ __forceinline__ void gload_lds16(const u16* g, u16* l){
  __builtin_amdgcn_global_load_lds((const __attribute__((address_space(1))) void*)g,
                                   (__attribute__((address_space(3))) void*)l,
                                   16, 0, 0);
}

// ---------------------------------------------------------------------------
// K0a: dtype detector on x. flag=1 => fp32 input.
// ---------------------------------------------------------------------------
__global__ void k_detect(const u16* __restrict__ x, u32* __restrict__ flag){
  __shared__ int cnt[256];
  const int t = threadIdx.x;
  int c = 0;
  #pragma unroll
  for(int i = 0; i < 4; i++){
    u16 v = x[t * 4 + i];
    int e = (v >> 7) & 0xFF;
    if(e >= 112 && e <= 134) c++;
  }
  cnt[t] = c;
  __syncthreads();
  for(int s = 128; s > 0; s >>= 1){
    if(t < s) cnt[t] += cnt[t + s];
    __syncthreads();
  }
  if(t == 0) *flag = (cnt[0] < 800) ? 1u : 0u;
}

// ---------------------------------------------------------------------------
// K0b: canonicalize to bf16 (8 elems/thread).
// ---------------------------------------------------------------------------
__global__ __launch_bounds__(256) void k_conv_bf(const void* __restrict__ src,
                                                 u16* __restrict__ dst, int n,
                                                 const u32* __restrict__ flag){
  const int i0 = (blockIdx.x * 256 + threadIdx.x) * 8;
  if(i0 >= n) return;
  const bool isf32 = (*flag != 0);
  if(isf32){
    const float4 a = *(const float4*)((const float*)src + i0);
    const float4 b = *(const float4*)((const float*)src + i0 + 4);
    uint4 o;
    o.x = (u32)f2bf(a.x) | ((u32)f2bf(a.y) << 16);
    o.y = (u32)f2bf(a.z) | ((u32)f2bf(a.w) << 16);
    o.z = (u32)f2bf(b.x) | ((u32)f2bf(b.y) << 16);
    o.w = (u32)f2bf(b.z) | ((u32)f2bf(b.w) << 16);
    *(uint4*)(dst + i0) = o;
  } else {
    *(uint4*)(dst + i0) = *(const uint4*)((const u16*)src + i0);
  }
}

// ---------------------------------------------------------------------------
// K0d: canonicalize to fp32 (all n) + bf16 (first nb elems) — for W_sa.
// ---------------------------------------------------------------------------
__global__ __launch_bounds__(256) void k_conv_both(const void* __restrict__ src,
                                                   float* __restrict__ dstf,
                                                   u16* __restrict__ dstb, int n,
                                                   int nb,
                                                   const u32* __restrict__ flag){
  const int i0 = (blockIdx.x * 256 + threadIdx.x) * 4;
  if(i0 >= n) return;
  const bool isf32 = (*flag != 0);
  float4 o;
  if(isf32){
    o = *(const float4*)((const float*)src + i0);
  } else {
    const uint2 a = *(const uint2*)((const u16*)src + i0);
    o.x = bf2f((u16)(a.x & 0xFFFF)); o.y = bf2f((u16)(a.x >> 16));
    o.z = bf2f((u16)(a.y & 0xFFFF)); o.w = bf2f((u16)(a.y >> 16));
  }
  *(float4*)(dstf + i0) = o;
  if(i0 < nb){
    uint2 pk;
    pk.x = (u32)f2bf(o.x) | ((u32)f2bf(o.y) << 16);
    pk.y = (u32)f2bf(o.z) | ((u32)f2bf(o.w) << 16);
    *(uint2*)(dstb + i0) = pk;
  }
}

// ---------------------------------------------------------------------------
// K0t: both temperature vectors (8 f32 each) in one launch.
// ---------------------------------------------------------------------------
__global__ void k_conv_tf(const void* __restrict__ s0, const void* __restrict__ s1,
                          float* __restrict__ tf, const u32* __restrict__ flag){
  const int t = threadIdx.x;
  if(t >= 16) return;
  const void* s = (t < 8) ? s0 : s1;
  const int i = t & 7;
  if(*flag != 0) tf[t] = ((const float*)s)[i];
  else           tf[t] = bf2f(((const u16*)s)[i]);
}

// ---------------------------------------------------------------------------
// K0e: x -> xb[b][c][n] bf16 AND xT[b][n][c] bf16 (LDS 64x64 transpose).
// ---------------------------------------------------------------------------
__global__ __launch_bounds__(256) void k_convT(const void* __restrict__ src,
                                               u16* __restrict__ xb,
                                               u16* __restrict__ xT,
                                               const u32* __restrict__ flag){
  __shared__ u16 T[64][72];
  const int t = threadIdx.x;
  const int n0 = blockIdx.x * 64, c0 = blockIdx.y * 64, b = blockIdx.z;
  const int cl = t >> 2, ns = (t & 3) * 16;
  const bool isf32 = (*flag != 0);
  const size_t srcoff = ((size_t)(b * 256 + c0 + cl)) * 4096 + n0 + ns;
  u16 e[16];
  if(isf32){
    const float* sp = (const float*)src + srcoff;
    #pragma unroll
    for(int i = 0; i < 4; i++){
      const float4 v = *(const float4*)(sp + i * 4);
      e[i*4+0] = f2bf(v.x); e[i*4+1] = f2bf(v.y);
      e[i*4+2] = f2bf(v.z); e[i*4+3] = f2bf(v.w);
    }
  } else {
    const u16* sp = (const u16*)src + srcoff;
    *(uint4*)&e[0] = *(const uint4*)sp;
    *(uint4*)&e[8] = *(const uint4*)(sp + 8);
  }
  u16* xbp = xb + srcoff;
  *(uint4*)xbp       = *(uint4*)&e[0];
  *(uint4*)(xbp + 8) = *(uint4*)&e[8];
  #pragma unroll
  for(int i = 0; i < 16; i++) T[ns + i][cl] = e[i];
  __syncthreads();
  const int nl = t >> 2, cs = (t & 3) * 16;
  u16* xtp = xT + ((size_t)b * 4096 + n0 + nl) * 256 + c0 + cs;
  *(uint4*)xtp       = *(const uint4*)&T[nl][cs];
  *(uint4*)(xtp + 8) = *(const uint4*)&T[nl][cs + 8];
}

// ---------------------------------------------------------------------------
// K0f: EF[n][p] -> EFT[p][n] bf16 (LDS 64x64 transpose). Grid 64.
// ---------------------------------------------------------------------------
__global__ __launch_bounds__(256) void k_conv_efT(const void* __restrict__ src,
                                                  u16* __restrict__ EFT,
                                                  const u32* __restrict__ flag){
  __shared__ u16 T[64][72];
  const int t = threadIdx.x;
  const int n0 = blockIdx.x * 64;
  const int nl = t >> 2, p0 = (t & 3) * 16;
  const bool isf32 = (*flag != 0);
  const size_t off = (size_t)(n0 + nl) * 64 + p0;
  u16 e[16];
  if(isf32){
    const float* sp = (const float*)src + off;
    #pragma unroll
    for(int i = 0; i < 4; i++){
      const float4 v = *(const float4*)(sp + i * 4);
      e[i*4+0] = f2bf(v.x); e[i*4+1] = f2bf(v.y);
      e[i*4+2] = f2bf(v.z); e[i*4+3] = f2bf(v.w);
    }
  } else {
    const u16* sp = (const u16*)src + off;
    *(uint4*)&e[0] = *(const uint4*)sp;
    *(uint4*)&e[8] = *(const uint4*)(sp + 8);
  }
  #pragma unroll
  for(int i = 0; i < 16; i++) T[p0 + i][nl] = e[i];
  __syncthreads();
  const int pr = t >> 2, nn = (t & 3) * 16;
  u16* dp = EFT + (size_t)pr * 4096 + n0 + nn;
  *(uint4*)dp       = *(const uint4*)&T[pr][nn];
  *(uint4*)(dp + 8) = *(const uint4*)&T[pr][nn + 8];
}

// ---------------------------------------------------------------------------
// K1: fused QKV GEMM, m97 structure (unchanged).
// ---------------------------------------------------------------------------
__global__ __launch_bounds__(256) void k_qkv(const u16* __restrict__ Wc,
                                             const u16* __restrict__ xT,
                                             u16* __restrict__ Y){
  __shared__ union {
    struct { u16 Ws[128][64]; u16 Xs[128][64]; } s;
    u16 Cs[128][136];
  } L;
  const int t = threadIdx.x;
  const int n0 = blockIdx.x * 128, m0 = blockIdx.y * 128, b = blockIdx.z;
  const int w = t >> 6, lane = t & 63;
  const int fm = lane & 15, fq = lane >> 4;
  const int wm = w >> 1, wn = w & 1;
  const int lr = lane >> 3, lc = (lane & 7) * 8;
  const u16* gw = Wc + (size_t)m0 * 256;
  const u16* gx = xT + ((size_t)b * 4096 + n0) * 256;
  f32x4 acc[4][4] = {};
  for(int kc = 0; kc < 256; kc += 64){
    #pragma unroll
    for(int i = 0; i < 4; i++){
      const int row = w * 32 + i * 8;
      gload_lds16(gw + (size_t)(row + lr) * 256 + kc + lc, &L.s.Ws[row][0]);
      gload_lds16(gx + (size_t)(row + lr) * 256 + kc + lc, &L.s.Xs[row][0]);
    }
    __syncthreads();
    #pragma unroll
    for(int kh = 0; kh < 2; kh++){
      bf16x8 af[4], bx[4];
      #pragma unroll
      for(int mt = 0; mt < 4; mt++)
        af[mt] = *(const bf16x8*)&L.s.Ws[wm * 64 + mt * 16 + fm][kh * 32 + fq * 8];
      #pragma unroll
      for(int nt = 0; nt < 4; nt++)
        bx[nt] = *(const bf16x8*)&L.s.Xs[wn * 64 + nt * 16 + fm][kh * 32 + fq * 8];
      #pragma unroll
      for(int mt = 0; mt < 4; mt++)
        #pragma unroll
        for(int nt = 0; nt < 4; nt++)
          acc[mt][nt] = __builtin_amdgcn_mfma_f32_16x16x32_bf16(af[mt], bx[nt],
                                                                acc[mt][nt], 0, 0, 0);
    }
    __syncthreads();
  }
  #pragma unroll
  for(int mt = 0; mt < 4; mt++)
    #pragma unroll
    for(int nt = 0; nt < 4; nt++)
      #pragma unroll
      for(int r = 0; r < 4; r++)
        L.Cs[wm * 64 + mt * 16 + fq * 4 + r][wn * 64 + nt * 16 + fm] =
          f2bf(acc[mt][nt][r]);
  __syncthreads();
  #pragma unroll
  for(int i = 0; i < 8; i++){
    const int row = i * 16 + (t >> 4), ce = (t & 15) * 8;
    *(uint4*)(Y + ((size_t)b * 1024 + m0 + row) * 4096 + n0 + ce) =
      *(const uint4*)&L.Cs[row][ce];
  }
}

// ---------------------------------------------------------------------------
// K2: split-K MFMA xef partials (unchanged).
// ---------------------------------------------------------------------------
__global__ __launch_bounds__(256) void k_xef_mfma(const u16* __restrict__ xb,
                                                  const u16* __restrict__ EFT,
                                                  float* __restrict__ xefp){
  const int t = threadIdx.x;
  const int mh = blockIdx.x, s = blockIdx.y, b = blockIdx.z;
  const int w = t >> 6, lane = t & 63;
  const int fm = lane & 15, fq = lane >> 4;
  const int c0 = mh * 128 + w * 32;
  const u16* ar = xb + ((size_t)(b * 256 + c0 + fm)) * 4096 + s * 256 + fq * 8;
  const u16* br = EFT + (size_t)fm * 4096 + s * 256 + fq * 8;
  f32x4 acc[2][4] = {};
  #pragma unroll
  for(int kk = 0; kk < 8; kk++){
    bf16x8 bfr[4];
    #pragma unroll
    for(int nt = 0; nt < 4; nt++)
      bfr[nt] = *(const bf16x8*)(br + (size_t)nt * 16 * 4096 + kk * 32);
    #pragma unroll
    for(int mt = 0; mt < 2; mt++){
      bf16x8 af = *(const bf16x8*)(ar + (size_t)mt * 16 * 4096 + kk * 32);
      #pragma unroll
      for(int nt = 0; nt < 4; nt++)
        acc[mt][nt] = __builtin_amdgcn_mfma_f32_16x16x32_bf16(af, bfr[nt],
                                                              acc[mt][nt], 0, 0, 0);
    }
  }
  float* dst = xefp + (size_t)s * 131072 + (size_t)(b * 256 + c0) * 64;
  #pragma unroll
  for(int mt = 0; mt < 2; mt++)
    #pragma unroll
    for(int nt = 0; nt < 4; nt++)
      #pragma unroll
      for(int r = 0; r < 4; r++)
        dst[(mt * 16 + fq * 4 + r) * 64 + nt * 16 + fm] = acc[mt][nt][r];
}

// ---------------------------------------------------------------------------
// K2b: reduce partials: xef[i] = sum_s xefp[s][i] (16 slices).
// ---------------------------------------------------------------------------
__global__ __launch_bounds__(256) void k_xred(const float* __restrict__ xefp,
                                              float* __restrict__ xef){
  const int i0 = (blockIdx.x * 256 + threadIdx.x) * 4;
  float4 a = *(const float4*)(xefp + i0);
  #pragma unroll
  for(int s = 1; s < 16; s++){
    const float4 v = *(const float4*)(xefp + (size_t)s * 131072 + i0);
    a.x += v.x; a.y += v.y; a.z += v.z; a.w += v.w;
  }
  *(float4*)(xef + i0) = a;
}

// ---------------------------------------------------------------------------
// K3: kvp -> bf16 kpT/vpb (unchanged).
// ---------------------------------------------------------------------------
__global__ __launch_bounds__(256) void k_kv4b(const float* __restrict__ Wsaf,
                                              const float* __restrict__ xef,
                                              const float* __restrict__ invsa,
                                              u16* __restrict__ kpT,
                                              u16* __restrict__ vpb){
  const int t = threadIdx.x;
  const int ri = t >> 6, p = t & 63;
  const int r = blockIdx.x * 4 + ri, b = blockIdx.y;
  const int row_w = (r < 256) ? (256 + r) : (512 + r);
  const float* wr = Wsaf + (size_t)row_w * 256;
  const float* xr = xef + (size_t)(b * 256) * 64 + p;
  float acc = 0.f;
  for(int c = 0; c < 256; c++)
    acc += wr[c] * xr[(size_t)c * 64];
  if(r < 256){
    const float sc = invsa[b * 256 + r];
    kpT[((size_t)(b * 8 + (r >> 5)) * 64 + p) * 32 + (r & 31)] = f2bf(acc * sc);
  } else {
    const int rv = r - 256;
    vpb[((size_t)(b * 8 + (rv >> 5)) * 32 + (rv & 31)) * 64 + p] = f2bf(acc);
  }
}

// ---------------------------------------------------------------------------
// K4 (new): fused L2 norms for Y rows 0:768 -> inv3[seg][b][r].
//   seg 0 = q (invsa), 1 = qc (invqc), 2 = kc (invkc). Vectorized uint4 loads.
// ---------------------------------------------------------------------------
__global__ __launch_bounds__(256) void k_norm3(const u16* __restrict__ Y,
                                               float* __restrict__ inv3){
  __shared__ float red[256];
  const int r = blockIdx.x, b = blockIdx.y, t = threadIdx.x;
  const u16* row = Y + (size_t)(b * 1024 + r) * 4096 + t * 16;
  u16 e[16];
  *(uint4*)&e[0] = *(const uint4*)row;
  *(uint4*)&e[8] = *(const uint4*)(row + 8);
  float s = 0.f;
  #pragma unroll
  for(int i = 0; i < 16; i++){ float v = bf2f(e[i]); s += v * v; }
  red[t] = s;
  __syncthreads();
  for(int s2 = 128; s2 > 0; s2 >>= 1){
    if(t < s2) red[t] += red[t + s2];
    __syncthreads();
  }
  if(t == 0)
    inv3[(r >> 8) * 2048 + b * 256 + (r & 255)] =
      1.0f / fmaxf(sqrtf(red[0]), 1e-12f);
}

// ---------------------------------------------------------------------------
// K5: MFMA Gram partials (unchanged).
// ---------------------------------------------------------------------------
__device__ __forceinline__ bf16x8 ld_frag8(const u16* p){
  short4v lo = *(const short4v*)p;
  short4v hi = *(const short4v*)(p + 4);
  bf16x8 r;
  r[0]=lo[0]; r[1]=lo[1]; r[2]=lo[2]; r[3]=lo[3];
  r[4]=hi[0]; r[5]=hi[1]; r[6]=hi[2]; r[7]=hi[3];
  return r;
}

__global__ __launch_bounds__(256) void k_gram_mfma(const u16* __restrict__ Y,
                                                   float* __restrict__ Gp){
  const int t = threadIdx.x;
  const int s = blockIdx.x, h = blockIdx.y, b = blockIdx.z;
  const int w = t >> 6, lane = t & 63;
  const int fm = lane & 15, fq = lane >> 4;
  const int j0 = (w >> 1) * 16, e0 = (w & 1) * 16;
  const u16* qrow = Y + (size_t)(b * 1024 + 256 + h * 32 + j0 + fm) * 4096;
  const u16* krow = Y + (size_t)(b * 1024 + 512 + h * 32 + e0 + fm) * 4096;
  f32x4 acc = {};
  const int nb0 = s * 512 + fq * 8;
  #pragma unroll 4
  for(int it = 0; it < 16; it++){
    const int nb = nb0 + it * 32;
    bf16x8 a  = ld_frag8(qrow + nb);
    bf16x8 bb = ld_frag8(krow + nb);
    acc = __builtin_amdgcn_mfma_f32_16x16x32_bf16(a, bb, acc, 0, 0, 0);
  }
  float* dst = Gp + ((size_t)((s * 8 + b) * 8 + h) * 1024);
  #pragma unroll
  for(int r = 0; r < 4; r++)
    dst[(j0 + fq * 4 + r) * 32 + e0 + fm] = acc[r];
}

// ---------------------------------------------------------------------------
// K5b: channel softmax (unchanged).
// ---------------------------------------------------------------------------
__global__ void k_softmax_ca(const float* __restrict__ Gp,
                             const float* __restrict__ invq,
                             const float* __restrict__ invk,
                             const float* __restrict__ temp,
                             float* __restrict__ attn){
  const int j = threadIdx.x, h = blockIdx.x, b = blockIdx.y;
  const float tm = temp[h];
  const float iq = invq[b * 256 + h * 32 + j];
  float v[32];
  float m = -1e30f;
  #pragma unroll
  for(int e = 0; e < 32; e++){
    float g = 0.f;
    #pragma unroll
    for(int s = 0; s < 8; s++)
      g += Gp[(size_t)s * 65536 + (size_t)(b * 8 + h) * 1024 + j * 32 + e];
    float val = g * iq * invk[b * 256 + h * 32 + e] * tm;
    v[e] = val; m = fmaxf(m, val);
  }
  float sum = 0.f;
  #pragma unroll
  for(int e = 0; e < 32; e++){ v[e] = __expf(v[e] - m); sum += v[e]; }
  const float inv = 1.0f / sum;
  #pragma unroll
  for(int e = 0; e < 32; e++) attn[(size_t)(b * 8 + h) * 1024 + j * 32 + e] = v[e] * inv;
}

// ---------------------------------------------------------------------------
// K6: full-MFMA spatial attention (unchanged).
// ---------------------------------------------------------------------------
__global__ __launch_bounds__(256) void k_sa_mfma(const u16* __restrict__ Y,
                                                 const u16* __restrict__ kpT,
                                                 const u16* __restrict__ vpb,
                                                 const float* __restrict__ temp2,
                                                 u16* __restrict__ xsa){
  __shared__ u16 As[64][36];
  __shared__ u16 Ks[64][36];
  __shared__ u16 Vs[32][68];
  __shared__ u16 Ps[64][68];
  __shared__ u16 Cs[32][68];
  const int t = threadIdx.x;
  const int ntile = blockIdx.x, h = blockIdx.y, b = blockIdx.z;
  const int n0 = ntile * 64;
  const int w = t >> 6, lane = t & 63;
  const int fm = lane & 15, fq = lane >> 4;
  {
    const int j = t >> 3, ns = (t & 7) * 8;
    const u16* src = Y + (size_t)(b * 1024 + h * 32 + j) * 4096 + n0 + ns;
    uint4 v = *(const uint4*)src;
    u16 e[8]; *(uint4*)e = v;
    #pragma unroll
    for(int i = 0; i < 8; i++) As[ns + i][j] = e[i];
  }
  {
    const int p = t >> 2, jb = (t & 3) * 8;
    *(uint4*)&Ks[p][jb] =
      *(const uint4*)(kpT + ((size_t)(b * 8 + h) * 64 + p) * 32 + jb);
  }
  {
    const int jv = t >> 3, ps = (t & 7) * 8;
    *(uint4*)&Vs[jv][ps] =
      *(const uint4*)(vpb + ((size_t)(b * 8 + h) * 32 + jv) * 64 + ps);
  }
  __syncthreads();
  bf16x8 a = ld_frag8(&As[w * 16 + fm][fq * 8]);
  f32x4 lg[4];
  #pragma unroll
  for(int pt = 0; pt < 4; pt++){
    bf16x8 bk = ld_frag8(&Ks[pt * 16 + fm][fq * 8]);
    f32x4 z = {};
    lg[pt] = __builtin_amdgcn_mfma_f32_16x16x32_bf16(a, bk, z, 0, 0, 0);
  }
  const float tm = temp2[h];
  float sinv[4];
  #pragma unroll
  for(int r = 0; r < 4; r++){
    float v0 = lg[0][r]*tm, v1 = lg[1][r]*tm, v2 = lg[2][r]*tm, v3 = lg[3][r]*tm;
    float mx = fmaxf(fmaxf(v0, v1), fmaxf(v2, v3));
    #pragma unroll
    for(int m = 1; m < 16; m <<= 1) mx = fmaxf(mx, __shfl_xor(mx, m, 16));
    v0 = __expf(v0 - mx); v1 = __expf(v1 - mx);
    v2 = __expf(v2 - mx); v3 = __expf(v3 - mx);
    float s = v0 + v1 + v2 + v3;
    #pragma unroll
    for(int m = 1; m < 16; m <<= 1) s += __shfl_xor(s, m, 16);
    sinv[r] = 1.0f / s;
    const int nrow = w * 16 + fq * 4 + r;
    Ps[nrow][fm]      = f2bf(v0);
    Ps[nrow][16 + fm] = f2bf(v1);
    Ps[nrow][32 + fm] = f2bf(v2);
    Ps[nrow][48 + fm] = f2bf(v3);
  }
  f32x4 o[2] = {};
  #pragma unroll
  for(int ks = 0; ks < 2; ks++){
    bf16x8 ap = ld_frag8(&Ps[w * 16 + fm][ks * 32 + fq * 8]);
    #pragma unroll
    for(int jt = 0; jt < 2; jt++){
      bf16x8 bv = ld_frag8(&Vs[jt * 16 + fm][ks * 32 + fq * 8]);
      o[jt] = __builtin_amdgcn_mfma_f32_16x16x32_bf16(ap, bv, o[jt], 0, 0, 0);
    }
  }
  #pragma unroll
  for(int jt = 0; jt < 2; jt++)
    #pragma unroll
    for(int r = 0; r < 4; r++)
      Cs[jt * 16 + fm][w * 16 + fq * 4 + r] = f2bf(o[jt][r] * sinv[r]);
  __syncthreads();
  {
    const int jv = t >> 3, ns = (t & 7) * 8;
    u16 e[8];
    #pragma unroll
    for(int i = 0; i < 8; i++) e[i] = Cs[jv][ns + i];
    *(uint4*)(xsa + ((size_t)(b * 8 + h) * 32 + jv) * 4096 + n0 + ns) = *(uint4*)e;
  }
}

// ---------------------------------------------------------------------------
// K7 (new): MFMA out-writer. out[b][hc*32+row][nn0+col] =
//   (attn_hi + attn_lo) @ Vc  (MFMA, K=32, split-bf16 attn)  + xsa-scramble.
// Grid (jg=8 n-chunks of 512, hc=8, b=8), 4 waves; wave w owns cols w*128..+128.
// ---------------------------------------------------------------------------
__global__ __launch_bounds__(256) void k_out_mfma(const u16* __restrict__ Y,
                                                  const float* __restrict__ attn,
                                                  const u16* __restrict__ xsa,
                                                  float* __restrict__ out){
  __shared__ u16 Vt[32][516];      // Vc rows [e][n-chunk], pad 516 (bank-spread)
  __shared__ u16 xs[32][16][34];   // xsa scramble-gather tile
  __shared__ u16 Ah[32][40];       // attn hi (bf16)
  __shared__ u16 Al[32][40];       // attn residual lo (bf16)
  const int t = threadIdx.x;
  const int jg = blockIdx.x, hc = blockIdx.y, b = blockIdx.z;
  const int nn0 = jg * 512;
  const int w = t >> 6, lane = t & 63;
  const int fm = lane & 15, fq = lane >> 4;
  // stage attn -> hi/lo bf16
  {
    const float4 v = *(const float4*)(attn + (size_t)(b * 8 + hc) * 1024 + t * 4);
    const int j = t >> 3, e0 = (t & 7) * 4;
    float vv[4] = {v.x, v.y, v.z, v.w};
    #pragma unroll
    for(int i = 0; i < 4; i++){
      u16 hi = f2bf(vv[i]);
      Ah[j][e0 + i] = hi;
      Al[j][e0 + i] = f2bf(vv[i] - bf2f(hi));
    }
  }
  // stage Vc rows (coalesced read, uint2-granular LDS writes)
  {
    const int e = t >> 3, ch = (t & 7) * 64;
    const u16* src = Y + (size_t)(b * 1024 + 768 + hc * 32 + e) * 4096 + nn0 + ch;
    #pragma unroll
    for(int i = 0; i < 8; i++){
      uint4 v = *(const uint4*)(src + i * 8);
      uint2 lo; lo.x = v.x; lo.y = v.y;
      uint2 hi; hi.x = v.z; hi.y = v.w;
      *(uint2*)&Vt[e][ch + i * 8]     = lo;
      *(uint2*)&Vt[e][ch + i * 8 + 4] = hi;
    }
  }
  // stage xsa scramble tile (as in r9-r14)
  #pragma unroll
  for(int rep = 0; rep < 2; rep++){
    const int s = rep * 256 + t;
    const int hj = s >> 4, nh = s & 15;
    const int h = hj & 7, jj = hj >> 3;
    const u16* src = xsa + ((size_t)(b * 8 + h) * 32 + jg * 4 + jj) * 4096 + nh * 256 + hc * 32;
    uint4 v0 = *(const uint4*)src;
    uint4 v1 = *(const uint4*)(src + 8);
    u32* d32 = (u32*)&xs[hj][nh][0];
    d32[0] = v0.x; d32[1] = v0.y; d32[2] = v0.z; d32[3] = v0.w;
    d32[4] = v1.x; d32[5] = v1.y; d32[6] = v1.z; d32[7] = v1.w;
    uint4 v2 = *(const uint4*)(src + 16);
    uint4 v3 = *(const uint4*)(src + 24);
    d32[8]  = v2.x; d32[9]  = v2.y; d32[10] = v2.z; d32[11] = v2.w;
    d32[12] = v3.x; d32[13] = v3.y; d32[14] = v3.z; d32[15] = v3.w;
  }
  __syncthreads();
  // MFMA: D = (Ah + Al) @ Vc^T-frags
  bf16x8 ah[2], al[2];
  #pragma unroll
  for(int mt = 0; mt < 2; mt++){
    ah[mt] = *(const bf16x8*)&Ah[mt * 16 + fm][fq * 8];
    al[mt] = *(const bf16x8*)&Al[mt * 16 + fm][fq * 8];
  }
  f32x4 acc[2][8] = {};
  #pragma unroll
  for(int nt = 0; nt < 8; nt++){
    const int colb = w * 128 + nt * 16 + fm;
    bf16x8 bv;
    #pragma unroll
    for(int i = 0; i < 8; i++) bv[i] = (short)Vt[fq * 8 + i][colb];
    #pragma unroll
    for(int mt = 0; mt < 2; mt++){
      acc[mt][nt] = __builtin_amdgcn_mfma_f32_16x16x32_bf16(ah[mt], bv, acc[mt][nt], 0, 0, 0);
      acc[mt][nt] = __builtin_amdgcn_mfma_f32_16x16x32_bf16(al[mt], bv, acc[mt][nt], 0, 0, 0);
    }
  }
  // epilogue: + xsa, fp32 store
  #pragma unroll
  for(int mt = 0; mt < 2; mt++)
    #pragma unroll
    for(int nt = 0; nt < 8; nt++){
      const int col = w * 128 + nt * 16 + fm;
      float* op = out + (size_t)(b * 256 + hc * 32 + mt * 16 + fq * 4) * 4096 + nn0 + col;
      #pragma unroll
      for(int r = 0; r < 4; r++){
        const float sa = bf2f(xs[w * 8 + nt][fm][mt * 16 + fq * 4 + r]);
        op[(size_t)r * 4096] = acc[mt][nt][r] + sa;
      }
    }
}

// ---------------------------------------------------------------------------
// Workspace layout (bytes).
// ---------------------------------------------------------------------------
#define OFF_XB    ((size_t)0)            // u16 [8][256][4096]  16,777,216 (reused as xsa)
#define OFF_XT    ((size_t)16777216)     // u16 [8][4096][256]  16,777,216 (reused as xefp)
#define OFF_Y     ((size_t)33554432)     // u16 [8][1024][4096] 67,108,864
#define OFF_WSAF  ((size_t)100663296)    // f32 [1024][256]      1,048,576
#define OFF_WCAT  ((size_t)101711872)    // u16 [1024][256]        524,288
#define OFF_EFT   ((size_t)102236160)    // u16 [64][4096]         524,288
#define OFF_XEF   ((size_t)103284736)    // f32 [8][256][64]       524,288
#define OFF_KPT   ((size_t)103809024)    // u16 [8][8][64][32]     262,144
#define OFF_VPB   ((size_t)104071168)    // u16 [8][8][32][64]     262,144
#define OFF_ISA   ((size_t)104333312)    // f32 [3][8][256]         24,576 (isa|iqc|ikc)
#define OFF_IQC   ((size_t)104341504)
#define OFF_IKC   ((size_t)104349696)
#define OFF_GP    ((size_t)104357888)    // f32 [8][8][8][32][32] 2,097,152
#define OFF_ATT   ((size_t)106455040)    // f32 [8][8][32][32]      262,144
#define OFF_TF    ((size_t)106717184)    // f32 [16]
#define OFF_FLAG  ((size_t)106717248)    // u32
#define OFF_XEFP  OFF_XT                 // f32 [16][8][256][64]  8,388,608 (overlay)

extern "C" void kernel_launch(void* const* d_in, const int* in_sizes, int n_in,
                              void* d_out, int out_size, void* d_ws, size_t ws_size,
                              hipStream_t stream){
  (void)in_sizes; (void)n_in; (void)out_size; (void)ws_size;
  char* ws = (char*)d_ws;
  u16*   xb    = (u16*)  (ws + OFF_XB);
  u16*   xsa   = (u16*)  (ws + OFF_XB);    // overlay
  u16*   xT    = (u16*)  (ws + OFF_XT);
  u16*   Y     = (u16*)  (ws + OFF_Y);
  float* Wsaf  = (float*)(ws + OFF_WSAF);
  u16*   Wcat  = (u16*)  (ws + OFF_WCAT);
  u16*   EFT   = (u16*)  (ws + OFF_EFT);
  float* xef   = (float*)(ws + OFF_XEF);
  u16*   kpT   = (u16*)  (ws + OFF_KPT);
  u16*   vpb   = (u16*)  (ws + OFF_VPB);
  float* invsa = (float*)(ws + OFF_ISA);
  float* invqc = (float*)(ws + OFF_IQC);
  float* invkc = (float*)(ws + OFF_IKC);
  float* Gp    = (float*)(ws + OFF_GP);
  float* attn  = (float*)(ws + OFF_ATT);
  float* tf    = (float*)(ws + OFF_TF);
  u32*   flag  = (u32*)  (ws + OFF_FLAG);
  float* xefp  = (float*)(ws + OFF_XEFP);  // overlay on xT (dead after k_qkv)
  float* out = (float*)d_out;

  // dtype detect + canonicalize (+ x transpose, EF transpose)
  k_detect<<<1, 256, 0, stream>>>((const u16*)d_in[0], flag);
  k_convT<<<dim3(64, 4, 8), 256, 0, stream>>>(d_in[0], xb, xT, flag);
  k_conv_both<<<256, 256, 0, stream>>>(d_in[1], Wsaf, Wcat, 262144, 65536, flag); // W_sa: f32 full + bf16 q rows
  k_conv_efT<<<64, 256, 0, stream>>>(d_in[2], EFT, flag);                         // EF -> bf16 EFT[p][n]
  k_conv_bf  <<<96,  256, 0, stream>>>(d_in[4], Wcat + 65536, 196608, flag);      // W_sc rows 0:768 -> Wcat 256:1024
  k_conv_tf  <<<1, 64, 0, stream>>>(d_in[3], d_in[5], tf, flag);                  // temp2_sa | temp_sc

  // Fused QKV GEMM (q | qc | kc | vc), m97 structure
  k_qkv<<<dim3(32, 8, 8), 256, 0, stream>>>(Wcat, xT, Y);
  // Linformer projection: split-K MFMA partials + reduce (xefp overlays dead xT)
  k_xef_mfma<<<dim3(2, 16, 8), 256, 0, stream>>>(xb, EFT, xefp);
  k_xred<<<128, 256, 0, stream>>>(xefp, xef);
  // Fused L2 norms (Y rows 0:768 -> invsa|invqc|invkc)
  k_norm3<<<dim3(768, 8), 256, 0, stream>>>(Y, invsa);
  // kpT (scaled) + vpb, bf16
  k_kv4b<<<dim3(128, 8), 256, 0, stream>>>(Wsaf, xef, invsa, kpT, vpb);
  // Channel attention matrix (MFMA gram) + softmax
  k_gram_mfma<<<dim3(8, 8, 8), 256, 0, stream>>>(Y, Gp);
  k_softmax_ca<<<dim3(8, 8), 32, 0, stream>>>(Gp, invqc, invkc, tf + 8, attn);
  // Spatial attention (full MFMA) -> xsa, then MFMA out-writer
  k_sa_mfma<<<dim3(64, 8, 8), 256, 0, stream>>>(Y, kpT, vpb, tf, xsa);
  k_out_mfma<<<dim3(8, 8, 8), 256, 0, stream>>>(Y, attn, xsa, out);
}

// Round 4
// 211.673 us; speedup vs baseline: 1.3721x; 1.0254x over previous
//
#include <hip/hip_runtime.h>

typedef unsigned short u16;
typedef unsigned int   u32;

typedef __attribute__((ext_vector_type(4))) short short4v;
typedef __attribute__((ext_vector_type(8))) short bf16x8;  // 8 bf16 (4 VGPRs)
typedef __attribute__((ext_vector_type(4))) float f32x4;

// Problem: B=8, C=256, N=4096, heads=8, d=32, P=64. Inputs fp32 (auto-detect),
// output FP32. r13: fused QKV GEMM (m97). r14: MFMA xef. r15: MFMA out-writer.
// r16: row-norm partial sums fused into k_qkv epilogue (k_norm3 deleted),
// small convs merged into one kernel, softmax regridded to 256-thread blocks.

__device__ __forceinline__ float bf2f(u16 u){
  union { u32 i; float f; } v; v.i = ((u32)u) << 16; return v.f;
}
__device__ __forceinline__ u16 f2bf(float f){
  u32 u = __float_as_uint(f);
  u32 r = u + 0x7FFFu + ((u >> 16) & 1u);   // RNE
  return (u16)(r >> 16);
}

__device__ __forceinline__ void gload_lds16(const u16* g, u16* l){
  __builtin_amdgcn_global_load_lds((const __attribute__((address_space(1))) void*)g,
                                   (__attribute__((address_space(3))) void*)l,
                                   16, 0, 0);
}

// ---------------------------------------------------------------------------
// K0a: dtype detector on x. flag=1 => fp32 input.
// ---------------------------------------------------------------------------
__global__ void k_detect(const u16* __restrict__ x, u32* __restrict__ flag){
  __shared__ int cnt[256];
  const int t = threadIdx.x;
  int c = 0;
  #pragma unroll
  for(int i = 0; i < 4; i++){
    u16 v = x[t * 4 + i];
    int e = (v >> 7) & 0xFF;
    if(e >= 112 && e <= 134) c++;
  }
  cnt[t] = c;
  __syncthreads();
  for(int s = 128; s > 0; s >>= 1){
    if(t < s) cnt[t] += cnt[t + s];
    __syncthreads();
  }
  if(t == 0) *flag = (cnt[0] < 800) ? 1u : 0u;
}

// ---------------------------------------------------------------------------
// K0e: x -> xb[b][c][n] bf16 AND xT[b][n][c] bf16 (LDS 64x64 transpose).
// ---------------------------------------------------------------------------
__global__ __launch_bounds__(256) void k_convT(const void* __restrict__ src,
                                               u16* __restrict__ xb,
                                               u16* __restrict__ xT,
                                               const u32* __restrict__ flag){
  __shared__ u16 T[64][72];
  const int t = threadIdx.x;
  const int n0 = blockIdx.x * 64, c0 = blockIdx.y * 64, b = blockIdx.z;
  const int cl = t >> 2, ns = (t & 3) * 16;
  const bool isf32 = (*flag != 0);
  const size_t srcoff = ((size_t)(b * 256 + c0 + cl)) * 4096 + n0 + ns;
  u16 e[16];
  if(isf32){
    const float* sp = (const float*)src + srcoff;
    #pragma unroll
    for(int i = 0; i < 4; i++){
      const float4 v = *(const float4*)(sp + i * 4);
      e[i*4+0] = f2bf(v.x); e[i*4+1] = f2bf(v.y);
      e[i*4+2] = f2bf(v.z); e[i*4+3] = f2bf(v.w);
    }
  } else {
    const u16* sp = (const u16*)src + srcoff;
    *(uint4*)&e[0] = *(const uint4*)sp;
    *(uint4*)&e[8] = *(const uint4*)(sp + 8);
  }
  u16* xbp = xb + srcoff;
  *(uint4*)xbp       = *(uint4*)&e[0];
  *(uint4*)(xbp + 8) = *(uint4*)&e[8];
  #pragma unroll
  for(int i = 0; i < 16; i++) T[ns + i][cl] = e[i];
  __syncthreads();
  const int nl = t >> 2, cs = (t & 3) * 16;
  u16* xtp = xT + ((size_t)b * 4096 + n0 + nl) * 256 + c0 + cs;
  *(uint4*)xtp       = *(const uint4*)&T[nl][cs];
  *(uint4*)(xtp + 8) = *(const uint4*)&T[nl][cs + 8];
}

// ---------------------------------------------------------------------------
// K0m (new): all small weight/EF/temp conversions in ONE launch, block-split.
//   blocks [0,256):   W_sa -> Wsaf f32 (all 262144) + Wcat bf16 (first 65536)
//   blocks [256,320): EF -> EFT[p][n] bf16 (LDS transpose)
//   blocks [320,416): W_sc rows 0:768 -> Wcat+65536 bf16
//   block  416:       temp2_sa | temp_sc -> tf[16]
// ---------------------------------------------------------------------------
__global__ __launch_bounds__(256) void k_conv_misc(const void* __restrict__ Wsa,
                                                   const void* __restrict__ EF,
                                                   const void* __restrict__ Wsc,
                                                   const void* __restrict__ t2,
                                                   const void* __restrict__ tsc,
                                                   float* __restrict__ Wsaf,
                                                   u16* __restrict__ Wcat,
                                                   u16* __restrict__ EFT,
                                                   float* __restrict__ tf,
                                                   const u32* __restrict__ flag){
  __shared__ u16 T[64][72];
  const int bx = blockIdx.x, t = threadIdx.x;
  const bool isf32 = (*flag != 0);
  if(bx < 256){
    const int i0 = (bx * 256 + t) * 4;
    float4 o;
    if(isf32){
      o = *(const float4*)((const float*)Wsa + i0);
    } else {
      const uint2 a = *(const uint2*)((const u16*)Wsa + i0);
      o.x = bf2f((u16)(a.x & 0xFFFF)); o.y = bf2f((u16)(a.x >> 16));
      o.z = bf2f((u16)(a.y & 0xFFFF)); o.w = bf2f((u16)(a.y >> 16));
    }
    *(float4*)(Wsaf + i0) = o;
    if(i0 < 65536){
      uint2 pk;
      pk.x = (u32)f2bf(o.x) | ((u32)f2bf(o.y) << 16);
      pk.y = (u32)f2bf(o.z) | ((u32)f2bf(o.w) << 16);
      *(uint2*)(Wcat + i0) = pk;
    }
  } else if(bx < 320){
    const int n0 = (bx - 256) * 64;
    const int nl = t >> 2, p0 = (t & 3) * 16;
    const size_t off = (size_t)(n0 + nl) * 64 + p0;
    u16 e[16];
    if(isf32){
      const float* sp = (const float*)EF + off;
      #pragma unroll
      for(int i = 0; i < 4; i++){
        const float4 v = *(const float4*)(sp + i * 4);
        e[i*4+0] = f2bf(v.x); e[i*4+1] = f2bf(v.y);
        e[i*4+2] = f2bf(v.z); e[i*4+3] = f2bf(v.w);
      }
    } else {
      const u16* sp = (const u16*)EF + off;
      *(uint4*)&e[0] = *(const uint4*)sp;
      *(uint4*)&e[8] = *(const uint4*)(sp + 8);
    }
    #pragma unroll
    for(int i = 0; i < 16; i++) T[p0 + i][nl] = e[i];
    __syncthreads();
    const int pr = t >> 2, nn = (t & 3) * 16;
    u16* dp = EFT + (size_t)pr * 4096 + n0 + nn;
    *(uint4*)dp       = *(const uint4*)&T[pr][nn];
    *(uint4*)(dp + 8) = *(const uint4*)&T[pr][nn + 8];
  } else if(bx < 416){
    const int i0 = ((bx - 320) * 256 + t) * 8;
    u16* dst = Wcat + 65536;
    if(isf32){
      const float4 a = *(const float4*)((const float*)Wsc + i0);
      const float4 b = *(const float4*)((const float*)Wsc + i0 + 4);
      uint4 o;
      o.x = (u32)f2bf(a.x) | ((u32)f2bf(a.y) << 16);
      o.y = (u32)f2bf(a.z) | ((u32)f2bf(a.w) << 16);
      o.z = (u32)f2bf(b.x) | ((u32)f2bf(b.y) << 16);
      o.w = (u32)f2bf(b.z) | ((u32)f2bf(b.w) << 16);
      *(uint4*)(dst + i0) = o;
    } else {
      *(uint4*)(dst + i0) = *(const uint4*)((const u16*)Wsc + i0);
    }
  } else {
    if(t < 16){
      const void* s = (t < 8) ? t2 : tsc;
      const int i = t & 7;
      if(isf32) tf[t] = ((const float*)s)[i];
      else      tf[t] = bf2f(((const u16*)s)[i]);
    }
  }
}

// ---------------------------------------------------------------------------
// K1: fused QKV GEMM, m97 structure + fused row-norm partials.
//   nrmp[ntile][b][m] (m<768) = sum of squares of this block's 128-col slice.
// ---------------------------------------------------------------------------
__global__ __launch_bounds__(256) void k_qkv(const u16* __restrict__ Wc,
                                             const u16* __restrict__ xT,
                                             u16* __restrict__ Y,
                                             float* __restrict__ nrmp){
  __shared__ union {
    struct { u16 Ws[128][64]; u16 Xs[128][64]; } s;
    u16 Cs[128][136];
  } L;
  const int t = threadIdx.x;
  const int n0 = blockIdx.x * 128, m0 = blockIdx.y * 128, b = blockIdx.z;
  const int w = t >> 6, lane = t & 63;
  const int fm = lane & 15, fq = lane >> 4;
  const int wm = w >> 1, wn = w & 1;
  const int lr = lane >> 3, lc = (lane & 7) * 8;
  const u16* gw = Wc + (size_t)m0 * 256;
  const u16* gx = xT + ((size_t)b * 4096 + n0) * 256;
  f32x4 acc[4][4] = {};
  for(int kc = 0; kc < 256; kc += 64){
    #pragma unroll
    for(int i = 0; i < 4; i++){
      const int row = w * 32 + i * 8;
      gload_lds16(gw + (size_t)(row + lr) * 256 + kc + lc, &L.s.Ws[row][0]);
      gload_lds16(gx + (size_t)(row + lr) * 256 + kc + lc, &L.s.Xs[row][0]);
    }
    __syncthreads();
    #pragma unroll
    for(int kh = 0; kh < 2; kh++){
      bf16x8 af[4], bx[4];
      #pragma unroll
      for(int mt = 0; mt < 4; mt++)
        af[mt] = *(const bf16x8*)&L.s.Ws[wm * 64 + mt * 16 + fm][kh * 32 + fq * 8];
      #pragma unroll
      for(int nt = 0; nt < 4; nt++)
        bx[nt] = *(const bf16x8*)&L.s.Xs[wn * 64 + nt * 16 + fm][kh * 32 + fq * 8];
      #pragma unroll
      for(int mt = 0; mt < 4; mt++)
        #pragma unroll
        for(int nt = 0; nt < 4; nt++)
          acc[mt][nt] = __builtin_amdgcn_mfma_f32_16x16x32_bf16(af[mt], bx[nt],
                                                                acc[mt][nt], 0, 0, 0);
    }
    __syncthreads();
  }
  #pragma unroll
  for(int mt = 0; mt < 4; mt++)
    #pragma unroll
    for(int nt = 0; nt < 4; nt++)
      #pragma unroll
      for(int r = 0; r < 4; r++)
        L.Cs[wm * 64 + mt * 16 + fq * 4 + r][wn * 64 + nt * 16 + fm] =
          f2bf(acc[mt][nt][r]);
  __syncthreads();
  const bool do_norm = (blockIdx.y < 6);       // rows 0:768 = q|qc|kc
  float* npb = nrmp + (size_t)blockIdx.x * 6144 + (size_t)b * 768 + m0;
  #pragma unroll
  for(int i = 0; i < 8; i++){
    const int row = i * 16 + (t >> 4), ce = (t & 15) * 8;
    uint4 pk = *(const uint4*)&L.Cs[row][ce];
    *(uint4*)(Y + ((size_t)b * 1024 + m0 + row) * 4096 + n0 + ce) = pk;
    if(do_norm){
      u16 e[8]; *(uint4*)e = pk;
      float s = 0.f;
      #pragma unroll
      for(int k2 = 0; k2 < 8; k2++){ float v = bf2f(e[k2]); s += v * v; }
      #pragma unroll
      for(int m2 = 1; m2 < 16; m2 <<= 1) s += __shfl_xor(s, m2, 16);
      if((t & 15) == 0) npb[row] = s;
    }
  }
}

// ---------------------------------------------------------------------------
// K2: split-K MFMA xef partials (unchanged).
// ---------------------------------------------------------------------------
__global__ __launch_bounds__(256) void k_xef_mfma(const u16* __restrict__ xb,
                                                  const u16* __restrict__ EFT,
                                                  float* __restrict__ xefp){
  const int t = threadIdx.x;
  const int mh = blockIdx.x, s = blockIdx.y, b = blockIdx.z;
  const int w = t >> 6, lane = t & 63;
  const int fm = lane & 15, fq = lane >> 4;
  const int c0 = mh * 128 + w * 32;
  const u16* ar = xb + ((size_t)(b * 256 + c0 + fm)) * 4096 + s * 256 + fq * 8;
  const u16* br = EFT + (size_t)fm * 4096 + s * 256 + fq * 8;
  f32x4 acc[2][4] = {};
  #pragma unroll
  for(int kk = 0; kk < 8; kk++){
    bf16x8 bfr[4];
    #pragma unroll
    for(int nt = 0; nt < 4; nt++)
      bfr[nt] = *(const bf16x8*)(br + (size_t)nt * 16 * 4096 + kk * 32);
    #pragma unroll
    for(int mt = 0; mt < 2; mt++){
      bf16x8 af = *(const bf16x8*)(ar + (size_t)mt * 16 * 4096 + kk * 32);
      #pragma unroll
      for(int nt = 0; nt < 4; nt++)
        acc[mt][nt] = __builtin_amdgcn_mfma_f32_16x16x32_bf16(af, bfr[nt],
                                                              acc[mt][nt], 0, 0, 0);
    }
  }
  float* dst = xefp + (size_t)s * 131072 + (size_t)(b * 256 + c0) * 64;
  #pragma unroll
  for(int mt = 0; mt < 2; mt++)
    #pragma unroll
    for(int nt = 0; nt < 4; nt++)
      #pragma unroll
      for(int r = 0; r < 4; r++)
        dst[(mt * 16 + fq * 4 + r) * 64 + nt * 16 + fm] = acc[mt][nt][r];
}

// ---------------------------------------------------------------------------
// K2b: xef reduce (blocks 0:128) + norm finalize (blocks 128:152).
//   inv3[seg][b][r] = 1/max(sqrt(sum_nt nrmp),1e-12), seg 0=q 1=qc 2=kc.
// ---------------------------------------------------------------------------
__global__ __launch_bounds__(256) void k_xred_nfin(const float* __restrict__ xefp,
                                                   float* __restrict__ xef,
                                                   const float* __restrict__ nrmp,
                                                   float* __restrict__ inv3){
  const int bx = blockIdx.x, t = threadIdx.x;
  if(bx < 128){
    const int i0 = (bx * 256 + t) * 4;
    float4 a = *(const float4*)(xefp + i0);
    #pragma unroll
    for(int s = 1; s < 16; s++){
      const float4 v = *(const float4*)(xefp + (size_t)s * 131072 + i0);
      a.x += v.x; a.y += v.y; a.z += v.z; a.w += v.w;
    }
    *(float4*)(xef + i0) = a;
  } else {
    const int tid = (bx - 128) * 256 + t;          // [0, 6144)
    float s = 0.f;
    #pragma unroll
    for(int nt = 0; nt < 32; nt++) s += nrmp[(size_t)nt * 6144 + tid];
    const int b = tid / 768, m = tid - b * 768;
    inv3[(m >> 8) * 2048 + b * 256 + (m & 255)] = 1.0f / fmaxf(sqrtf(s), 1e-12f);
  }
}

// ---------------------------------------------------------------------------
// K3: kvp -> bf16 kpT/vpb (unchanged).
// ---------------------------------------------------------------------------
__global__ __launch_bounds__(256) void k_kv4b(const float* __restrict__ Wsaf,
                                              const float* __restrict__ xef,
                                              const float* __restrict__ invsa,
                                              u16* __restrict__ kpT,
                                              u16* __restrict__ vpb){
  const int t = threadIdx.x;
  const int ri = t >> 6, p = t & 63;
  const int r = blockIdx.x * 4 + ri, b = blockIdx.y;
  const int row_w = (r < 256) ? (256 + r) : (512 + r);
  const float* wr = Wsaf + (size_t)row_w * 256;
  const float* xr = xef + (size_t)(b * 256) * 64 + p;
  float acc = 0.f;
  for(int c = 0; c < 256; c++)
    acc += wr[c] * xr[(size_t)c * 64];
  if(r < 256){
    const float sc = invsa[b * 256 + r];
    kpT[((size_t)(b * 8 + (r >> 5)) * 64 + p) * 32 + (r & 31)] = f2bf(acc * sc);
  } else {
    const int rv = r - 256;
    vpb[((size_t)(b * 8 + (rv >> 5)) * 32 + (rv & 31)) * 64 + p] = f2bf(acc);
  }
}

// ---------------------------------------------------------------------------
// K5: MFMA Gram partials (unchanged).
// ---------------------------------------------------------------------------
__device__ __forceinline__ bf16x8 ld_frag8(const u16* p){
  short4v lo = *(const short4v*)p;
  short4v hi = *(const short4v*)(p + 4);
  bf16x8 r;
  r[0]=lo[0]; r[1]=lo[1]; r[2]=lo[2]; r[3]=lo[3];
  r[4]=hi[0]; r[5]=hi[1]; r[6]=hi[2]; r[7]=hi[3];
  return r;
}

__global__ __launch_bounds__(256) void k_gram_mfma(const u16* __restrict__ Y,
                                                   float* __restrict__ Gp){
  const int t = threadIdx.x;
  const int s = blockIdx.x, h = blockIdx.y, b = blockIdx.z;
  const int w = t >> 6, lane = t & 63;
  const int fm = lane & 15, fq = lane >> 4;
  const int j0 = (w >> 1) * 16, e0 = (w & 1) * 16;
  const u16* qrow = Y + (size_t)(b * 1024 + 256 + h * 32 + j0 + fm) * 4096;
  const u16* krow = Y + (size_t)(b * 1024 + 512 + h * 32 + e0 + fm) * 4096;
  f32x4 acc = {};
  const int nb0 = s * 512 + fq * 8;
  #pragma unroll 4
  for(int it = 0; it < 16; it++){
    const int nb = nb0 + it * 32;
    bf16x8 a  = ld_frag8(qrow + nb);
    bf16x8 bb = ld_frag8(krow + nb);
    acc = __builtin_amdgcn_mfma_f32_16x16x32_bf16(a, bb, acc, 0, 0, 0);
  }
  float* dst = Gp + ((size_t)((s * 8 + b) * 8 + h) * 1024);
  #pragma unroll
  for(int r = 0; r < 4; r++)
    dst[(j0 + fq * 4 + r) * 32 + e0 + fm] = acc[r];
}

// ---------------------------------------------------------------------------
// K5b: channel softmax — regridded to 256-thread blocks (h = t>>5).
// ---------------------------------------------------------------------------
__global__ __launch_bounds__(256) void k_softmax_ca(const float* __restrict__ Gp,
                             const float* __restrict__ invq,
                             const float* __restrict__ invk,
                             const float* __restrict__ temp,
                             float* __restrict__ attn){
  const int t = threadIdx.x, b = blockIdx.x;
  const int h = t >> 5, j = t & 31;
  const float tm = temp[h];
  const float iq = invq[b * 256 + h * 32 + j];
  float v[32];
  float m = -1e30f;
  #pragma unroll
  for(int e = 0; e < 32; e++){
    float g = 0.f;
    #pragma unroll
    for(int s = 0; s < 8; s++)
      g += Gp[(size_t)s * 65536 + (size_t)(b * 8 + h) * 1024 + j * 32 + e];
    float val = g * iq * invk[b * 256 + h * 32 + e] * tm;
    v[e] = val; m = fmaxf(m, val);
  }
  float sum = 0.f;
  #pragma unroll
  for(int e = 0; e < 32; e++){ v[e] = __expf(v[e] - m); sum += v[e]; }
  const float inv = 1.0f / sum;
  #pragma unroll
  for(int e = 0; e < 32; e++) attn[(size_t)(b * 8 + h) * 1024 + j * 32 + e] = v[e] * inv;
}

// ---------------------------------------------------------------------------
// K6: full-MFMA spatial attention (unchanged).
// ---------------------------------------------------------------------------
__global__ __launch_bounds__(256) void k_sa_mfma(const u16* __restrict__ Y,
                                                 const u16* __restrict__ kpT,
                                                 const u16* __restrict__ vpb,
                                                 const float* __restrict__ temp2,
                                                 u16* __restrict__ xsa){
  __shared__ u16 As[64][36];
  __shared__ u16 Ks[64][36];
  __shared__ u16 Vs[32][68];
  __shared__ u16 Ps[64][68];
  __shared__ u16 Cs[32][68];
  const int t = threadIdx.x;
  const int ntile = blockIdx.x, h = blockIdx.y, b = blockIdx.z;
  const int n0 = ntile * 64;
  const int w = t >> 6, lane = t & 63;
  const int fm = lane & 15, fq = lane >> 4;
  {
    const int j = t >> 3, ns = (t & 7) * 8;
    const u16* src = Y + (size_t)(b * 1024 + h * 32 + j) * 4096 + n0 + ns;
    uint4 v = *(const uint4*)src;
    u16 e[8]; *(uint4*)e = v;
    #pragma unroll
    for(int i = 0; i < 8; i++) As[ns + i][j] = e[i];
  }
  {
    const int p = t >> 2, jb = (t & 3) * 8;
    *(uint4*)&Ks[p][jb] =
      *(const uint4*)(kpT + ((size_t)(b * 8 + h) * 64 + p) * 32 + jb);
  }
  {
    const int jv = t >> 3, ps = (t & 7) * 8;
    *(uint4*)&Vs[jv][ps] =
      *(const uint4*)(vpb + ((size_t)(b * 8 + h) * 32 + jv) * 64 + ps);
  }
  __syncthreads();
  bf16x8 a = ld_frag8(&As[w * 16 + fm][fq * 8]);
  f32x4 lg[4];
  #pragma unroll
  for(int pt = 0; pt < 4; pt++){
    bf16x8 bk = ld_frag8(&Ks[pt * 16 + fm][fq * 8]);
    f32x4 z = {};
    lg[pt] = __builtin_amdgcn_mfma_f32_16x16x32_bf16(a, bk, z, 0, 0, 0);
  }
  const float tm = temp2[h];
  float sinv[4];
  #pragma unroll
  for(int r = 0; r < 4; r++){
    float v0 = lg[0][r]*tm, v1 = lg[1][r]*tm, v2 = lg[2][r]*tm, v3 = lg[3][r]*tm;
    float mx = fmaxf(fmaxf(v0, v1), fmaxf(v2, v3));
    #pragma unroll
    for(int m = 1; m < 16; m <<= 1) mx = fmaxf(mx, __shfl_xor(mx, m, 16));
    v0 = __expf(v0 - mx); v1 = __expf(v1 - mx);
    v2 = __expf(v2 - mx); v3 = __expf(v3 - mx);
    float s = v0 + v1 + v2 + v3;
    #pragma unroll
    for(int m = 1; m < 16; m <<= 1) s += __shfl_xor(s, m, 16);
    sinv[r] = 1.0f / s;
    const int nrow = w * 16 + fq * 4 + r;
    Ps[nrow][fm]      = f2bf(v0);
    Ps[nrow][16 + fm] = f2bf(v1);
    Ps[nrow][32 + fm] = f2bf(v2);
    Ps[nrow][48 + fm] = f2bf(v3);
  }
  f32x4 o[2] = {};
  #pragma unroll
  for(int ks = 0; ks < 2; ks++){
    bf16x8 ap = ld_frag8(&Ps[w * 16 + fm][ks * 32 + fq * 8]);
    #pragma unroll
    for(int jt = 0; jt < 2; jt++){
      bf16x8 bv = ld_frag8(&Vs[jt * 16 + fm][ks * 32 + fq * 8]);
      o[jt] = __builtin_amdgcn_mfma_f32_16x16x32_bf16(ap, bv, o[jt], 0, 0, 0);
    }
  }
  #pragma unroll
  for(int jt = 0; jt < 2; jt++)
    #pragma unroll
    for(int r = 0; r < 4; r++)
      Cs[jt * 16 + fm][w * 16 + fq * 4 + r] = f2bf(o[jt][r] * sinv[r]);
  __syncthreads();
  {
    const int jv = t >> 3, ns = (t & 7) * 8;
    u16 e[8];
    #pragma unroll
    for(int i = 0; i < 8; i++) e[i] = Cs[jv][ns + i];
    *(uint4*)(xsa + ((size_t)(b * 8 + h) * 32 + jv) * 4096 + n0 + ns) = *(uint4*)e;
  }
}

// ---------------------------------------------------------------------------
// K7: MFMA out-writer (unchanged from r15).
// ---------------------------------------------------------------------------
__global__ __launch_bounds__(256) void k_out_mfma(const u16* __restrict__ Y,
                                                  const float* __restrict__ attn,
                                                  const u16* __restrict__ xsa,
                                                  float* __restrict__ out){
  __shared__ u16 Vt[32][516];
  __shared__ u16 xs[32][16][34];
  __shared__ u16 Ah[32][40];
  __shared__ u16 Al[32][40];
  const int t = threadIdx.x;
  const int jg = blockIdx.x, hc = blockIdx.y, b = blockIdx.z;
  const int nn0 = jg * 512;
  const int w = t >> 6, lane = t & 63;
  const int fm = lane & 15, fq = lane >> 4;
  {
    const float4 v = *(const float4*)(attn + (size_t)(b * 8 + hc) * 1024 + t * 4);
    const int j = t >> 3, e0 = (t & 7) * 4;
    float vv[4] = {v.x, v.y, v.z, v.w};
    #pragma unroll
    for(int i = 0; i < 4; i++){
      u16 hi = f2bf(vv[i]);
      Ah[j][e0 + i] = hi;
      Al[j][e0 + i] = f2bf(vv[i] - bf2f(hi));
    }
  }
  {
    const int e = t >> 3, ch = (t & 7) * 64;
    const u16* src = Y + (size_t)(b * 1024 + 768 + hc * 32 + e) * 4096 + nn0 + ch;
    #pragma unroll
    for(int i = 0; i < 8; i++){
      uint4 v = *(const uint4*)(src + i * 8);
      uint2 lo; lo.x = v.x; lo.y = v.y;
      uint2 hi; hi.x = v.z; hi.y = v.w;
      *(uint2*)&Vt[e][ch + i * 8]     = lo;
      *(uint2*)&Vt[e][ch + i * 8 + 4] = hi;
    }
  }
  #pragma unroll
  for(int rep = 0; rep < 2; rep++){
    const int s = rep * 256 + t;
    const int hj = s >> 4, nh = s & 15;
    const int h = hj & 7, jj = hj >> 3;
    const u16* src = xsa + ((size_t)(b * 8 + h) * 32 + jg * 4 + jj) * 4096 + nh * 256 + hc * 32;
    uint4 v0 = *(const uint4*)src;
    uint4 v1 = *(const uint4*)(src + 8);
    u32* d32 = (u32*)&xs[hj][nh][0];
    d32[0] = v0.x; d32[1] = v0.y; d32[2] = v0.z; d32[3] = v0.w;
    d32[4] = v1.x; d32[5] = v1.y; d32[6] = v1.z; d32[7] = v1.w;
    uint4 v2 = *(const uint4*)(src + 16);
    uint4 v3 = *(const uint4*)(src + 24);
    d32[8]  = v2.x; d32[9]  = v2.y; d32[10] = v2.z; d32[11] = v2.w;
    d32[12] = v3.x; d32[13] = v3.y; d32[14] = v3.z; d32[15] = v3.w;
  }
  __syncthreads();
  bf16x8 ah[2], al[2];
  #pragma unroll
  for(int mt = 0; mt < 2; mt++){
    ah[mt] = *(const bf16x8*)&Ah[mt * 16 + fm][fq * 8];
    al[mt] = *(const bf16x8*)&Al[mt * 16 + fm][fq * 8];
  }
  f32x4 acc[2][8] = {};
  #pragma unroll
  for(int nt = 0; nt < 8; nt++){
    const int colb = w * 128 + nt * 16 + fm;
    bf16x8 bv;
    #pragma unroll
    for(int i = 0; i < 8; i++) bv[i] = (short)Vt[fq * 8 + i][colb];
    #pragma unroll
    for(int mt = 0; mt < 2; mt++){
      acc[mt][nt] = __builtin_amdgcn_mfma_f32_16x16x32_bf16(ah[mt], bv, acc[mt][nt], 0, 0, 0);
      acc[mt][nt] = __builtin_amdgcn_mfma_f32_16x16x32_bf16(al[mt], bv, acc[mt][nt], 0, 0, 0);
    }
  }
  #pragma unroll
  for(int mt = 0; mt < 2; mt++)
    #pragma unroll
    for(int nt = 0; nt < 8; nt++){
      const int col = w * 128 + nt * 16 + fm;
      float* op = out + (size_t)(b * 256 + hc * 32 + mt * 16 + fq * 4) * 4096 + nn0 + col;
      #pragma unroll
      for(int r = 0; r < 4; r++){
        const float sa = bf2f(xs[w * 8 + nt][fm][mt * 16 + fq * 4 + r]);
        op[(size_t)r * 4096] = acc[mt][nt][r] + sa;
      }
    }
}

// ---------------------------------------------------------------------------
// Workspace layout (bytes).
// ---------------------------------------------------------------------------
#define OFF_XB    ((size_t)0)            // u16 [8][256][4096]  16,777,216 (reused as xsa)
#define OFF_XT    ((size_t)16777216)     // u16 [8][4096][256]  16,777,216 (reused as xefp)
#define OFF_Y     ((size_t)33554432)     // u16 [8][1024][4096] 67,108,864
#define OFF_WSAF  ((size_t)100663296)    // f32 [1024][256]      1,048,576
#define OFF_WCAT  ((size_t)101711872)    // u16 [1024][256]        524,288
#define OFF_EFT   ((size_t)102236160)    // u16 [64][4096]         524,288
#define OFF_XEF   ((size_t)103284736)    // f32 [8][256][64]       524,288
#define OFF_KPT   ((size_t)103809024)    // u16 [8][8][64][32]     262,144
#define OFF_VPB   ((size_t)104071168)    // u16 [8][8][32][64]     262,144
#define OFF_ISA   ((size_t)104333312)    // f32 [3][8][256]         24,576 (isa|iqc|ikc)
#define OFF_IQC   ((size_t)104341504)
#define OFF_IKC   ((size_t)104349696)
#define OFF_GP    ((size_t)104357888)    // f32 [8][8][8][32][32] 2,097,152
#define OFF_ATT   ((size_t)106455040)    // f32 [8][8][32][32]      262,144
#define OFF_TF    ((size_t)106717184)    // f32 [16]
#define OFF_FLAG  ((size_t)106717248)    // u32
#define OFF_NRM   ((size_t)106717312)    // f32 [32][8][768]        786,432
#define OFF_XEFP  OFF_XT                 // f32 [16][8][256][64]  8,388,608 (overlay)

extern "C" void kernel_launch(void* const* d_in, const int* in_sizes, int n_in,
                              void* d_out, int out_size, void* d_ws, size_t ws_size,
                              hipStream_t stream){
  (void)in_sizes; (void)n_in; (void)out_size; (void)ws_size;
  char* ws = (char*)d_ws;
  u16*   xb    = (u16*)  (ws + OFF_XB);
  u16*   xsa   = (u16*)  (ws + OFF_XB);    // overlay
  u16*   xT    = (u16*)  (ws + OFF_XT);
  u16*   Y     = (u16*)  (ws + OFF_Y);
  float* Wsaf  = (float*)(ws + OFF_WSAF);
  u16*   Wcat  = (u16*)  (ws + OFF_WCAT);
  u16*   EFT   = (u16*)  (ws + OFF_EFT);
  float* xef   = (float*)(ws + OFF_XEF);
  u16*   kpT   = (u16*)  (ws + OFF_KPT);
  u16*   vpb   = (u16*)  (ws + OFF_VPB);
  float* invsa = (float*)(ws + OFF_ISA);
  float* invqc = (float*)(ws + OFF_IQC);
  float* invkc = (float*)(ws + OFF_IKC);
  float* Gp    = (float*)(ws + OFF_GP);
  float* attn  = (float*)(ws + OFF_ATT);
  float* tf    = (float*)(ws + OFF_TF);
  u32*   flag  = (u32*)  (ws + OFF_FLAG);
  float* nrmp  = (float*)(ws + OFF_NRM);
  float* xefp  = (float*)(ws + OFF_XEFP);  // overlay on xT (dead after k_qkv)
  float* out = (float*)d_out;

  // dtype detect + canonicalize (x transpose; all small convs in one launch)
  k_detect<<<1, 256, 0, stream>>>((const u16*)d_in[0], flag);
  k_convT<<<dim3(64, 4, 8), 256, 0, stream>>>(d_in[0], xb, xT, flag);
  k_conv_misc<<<417, 256, 0, stream>>>(d_in[1], d_in[2], d_in[4], d_in[3], d_in[5],
                                       Wsaf, Wcat, EFT, tf, flag);

  // Fused QKV GEMM (q | qc | kc | vc) + row-norm partials
  k_qkv<<<dim3(32, 8, 8), 256, 0, stream>>>(Wcat, xT, Y, nrmp);
  // Linformer projection: split-K MFMA partials; reduce + norm finalize
  k_xef_mfma<<<dim3(2, 16, 8), 256, 0, stream>>>(xb, EFT, xefp);
  k_xred_nfin<<<152, 256, 0, stream>>>(xefp, xef, nrmp, invsa);
  // kpT (scaled) + vpb, bf16
  k_kv4b<<<dim3(128, 8), 256, 0, stream>>>(Wsaf, xef, invsa, kpT, vpb);
  // Channel attention matrix (MFMA gram) + softmax
  k_gram_mfma<<<dim3(8, 8, 8), 256, 0, stream>>>(Y, Gp);
  k_softmax_ca<<<8, 256, 0, stream>>>(Gp, invqc, invkc, tf + 8, attn);
  // Spatial attention (full MFMA) -> xsa, then MFMA out-writer
  k_sa_mfma<<<dim3(64, 8, 8), 256, 0, stream>>>(Y, kpT, vpb, tf, xsa);
  k_out_mfma<<<dim3(8, 8, 8), 256, 0, stream>>>(Y, attn, xsa, out);
}

// Round 5
// 205.175 us; speedup vs baseline: 1.4155x; 1.0317x over previous
//
#include <hip/hip_runtime.h>

typedef unsigned short u16;
typedef unsigned int   u32;

typedef __attribute__((ext_vector_type(4))) short short4v;
typedef __attribute__((ext_vector_type(8))) short bf16x8;  // 8 bf16 (4 VGPRs)
typedef __attribute__((ext_vector_type(4))) float f32x4;

// Problem: B=8, C=256, N=4096, heads=8, d=32, P=64. Inputs fp32 (auto-detect),
// output FP32. r13: fused QKV GEMM (m97). r14: MFMA xef. r15: MFMA out-writer.
// r16: norm partials fused into k_qkv epilogue. r17: T2 XOR-swizzle on k_qkv
// staging tiles (pre-swizzled global src + swizzled ds_read; LDS dest linear).

__device__ __forceinline__ float bf2f(u16 u){
  union { u32 i; float f; } v; v.i = ((u32)u) << 16; return v.f;
}
__device__ __forceinline__ u16 f2bf(float f){
  u32 u = __float_as_uint(f);
  u32 r = u + 0x7FFFu + ((u >> 16) & 1u);   // RNE
  return (u16)(r >> 16);
}

__device__ __forceinline__ void gload_lds16(const u16* g, u16* l){
  __builtin_amdgcn_global_load_lds((const __attribute__((address_space(1))) void*)g,
                                   (__attribute__((address_space(3))) void*)l,
                                   16, 0, 0);
}

// ---------------------------------------------------------------------------
// K0a: dtype detector on x. flag=1 => fp32 input.
// ---------------------------------------------------------------------------
__global__ void k_detect(const u16* __restrict__ x, u32* __restrict__ flag){
  __shared__ int cnt[256];
  const int t = threadIdx.x;
  int c = 0;
  #pragma unroll
  for(int i = 0; i < 4; i++){
    u16 v = x[t * 4 + i];
    int e = (v >> 7) & 0xFF;
    if(e >= 112 && e <= 134) c++;
  }
  cnt[t] = c;
  __syncthreads();
  for(int s = 128; s > 0; s >>= 1){
    if(t < s) cnt[t] += cnt[t + s];
    __syncthreads();
  }
  if(t == 0) *flag = (cnt[0] < 800) ? 1u : 0u;
}

// ---------------------------------------------------------------------------
// K0e: x -> xb[b][c][n] bf16 AND xT[b][n][c] bf16 (LDS 64x64 transpose).
// ---------------------------------------------------------------------------
__global__ __launch_bounds__(256) void k_convT(const void* __restrict__ src,
                                               u16* __restrict__ xb,
                                               u16* __restrict__ xT,
                                               const u32* __restrict__ flag){
  __shared__ u16 T[64][72];
  const int t = threadIdx.x;
  const int n0 = blockIdx.x * 64, c0 = blockIdx.y * 64, b = blockIdx.z;
  const int cl = t >> 2, ns = (t & 3) * 16;
  const bool isf32 = (*flag != 0);
  const size_t srcoff = ((size_t)(b * 256 + c0 + cl)) * 4096 + n0 + ns;
  u16 e[16];
  if(isf32){
    const float* sp = (const float*)src + srcoff;
    #pragma unroll
    for(int i = 0; i < 4; i++){
      const float4 v = *(const float4*)(sp + i * 4);
      e[i*4+0] = f2bf(v.x); e[i*4+1] = f2bf(v.y);
      e[i*4+2] = f2bf(v.z); e[i*4+3] = f2bf(v.w);
    }
  } else {
    const u16* sp = (const u16*)src + srcoff;
    *(uint4*)&e[0] = *(const uint4*)sp;
    *(uint4*)&e[8] = *(const uint4*)(sp + 8);
  }
  u16* xbp = xb + srcoff;
  *(uint4*)xbp       = *(uint4*)&e[0];
  *(uint4*)(xbp + 8) = *(uint4*)&e[8];
  #pragma unroll
  for(int i = 0; i < 16; i++) T[ns + i][cl] = e[i];
  __syncthreads();
  const int nl = t >> 2, cs = (t & 3) * 16;
  u16* xtp = xT + ((size_t)b * 4096 + n0 + nl) * 256 + c0 + cs;
  *(uint4*)xtp       = *(const uint4*)&T[nl][cs];
  *(uint4*)(xtp + 8) = *(const uint4*)&T[nl][cs + 8];
}

// ---------------------------------------------------------------------------
// K0m: all small weight/EF/temp conversions in ONE launch, block-split.
// ---------------------------------------------------------------------------
__global__ __launch_bounds__(256) void k_conv_misc(const void* __restrict__ Wsa,
                                                   const void* __restrict__ EF,
                                                   const void* __restrict__ Wsc,
                                                   const void* __restrict__ t2,
                                                   const void* __restrict__ tsc,
                                                   float* __restrict__ Wsaf,
                                                   u16* __restrict__ Wcat,
                                                   u16* __restrict__ EFT,
                                                   float* __restrict__ tf,
                                                   const u32* __restrict__ flag){
  __shared__ u16 T[64][72];
  const int bx = blockIdx.x, t = threadIdx.x;
  const bool isf32 = (*flag != 0);
  if(bx < 256){
    const int i0 = (bx * 256 + t) * 4;
    float4 o;
    if(isf32){
      o = *(const float4*)((const float*)Wsa + i0);
    } else {
      const uint2 a = *(const uint2*)((const u16*)Wsa + i0);
      o.x = bf2f((u16)(a.x & 0xFFFF)); o.y = bf2f((u16)(a.x >> 16));
      o.z = bf2f((u16)(a.y & 0xFFFF)); o.w = bf2f((u16)(a.y >> 16));
    }
    *(float4*)(Wsaf + i0) = o;
    if(i0 < 65536){
      uint2 pk;
      pk.x = (u32)f2bf(o.x) | ((u32)f2bf(o.y) << 16);
      pk.y = (u32)f2bf(o.z) | ((u32)f2bf(o.w) << 16);
      *(uint2*)(Wcat + i0) = pk;
    }
  } else if(bx < 320){
    const int n0 = (bx - 256) * 64;
    const int nl = t >> 2, p0 = (t & 3) * 16;
    const size_t off = (size_t)(n0 + nl) * 64 + p0;
    u16 e[16];
    if(isf32){
      const float* sp = (const float*)EF + off;
      #pragma unroll
      for(int i = 0; i < 4; i++){
        const float4 v = *(const float4*)(sp + i * 4);
        e[i*4+0] = f2bf(v.x); e[i*4+1] = f2bf(v.y);
        e[i*4+2] = f2bf(v.z); e[i*4+3] = f2bf(v.w);
      }
    } else {
      const u16* sp = (const u16*)EF + off;
      *(uint4*)&e[0] = *(const uint4*)sp;
      *(uint4*)&e[8] = *(const uint4*)(sp + 8);
    }
    #pragma unroll
    for(int i = 0; i < 16; i++) T[p0 + i][nl] = e[i];
    __syncthreads();
    const int pr = t >> 2, nn = (t & 3) * 16;
    u16* dp = EFT + (size_t)pr * 4096 + n0 + nn;
    *(uint4*)dp       = *(const uint4*)&T[pr][nn];
    *(uint4*)(dp + 8) = *(const uint4*)&T[pr][nn + 8];
  } else if(bx < 416){
    const int i0 = ((bx - 320) * 256 + t) * 8;
    u16* dst = Wcat + 65536;
    if(isf32){
      const float4 a = *(const float4*)((const float*)Wsc + i0);
      const float4 b = *(const float4*)((const float*)Wsc + i0 + 4);
      uint4 o;
      o.x = (u32)f2bf(a.x) | ((u32)f2bf(a.y) << 16);
      o.y = (u32)f2bf(a.z) | ((u32)f2bf(a.w) << 16);
      o.z = (u32)f2bf(b.x) | ((u32)f2bf(b.y) << 16);
      o.w = (u32)f2bf(b.z) | ((u32)f2bf(b.w) << 16);
      *(uint4*)(dst + i0) = o;
    } else {
      *(uint4*)(dst + i0) = *(const uint4*)((const u16*)Wsc + i0);
    }
  } else {
    if(t < 16){
      const void* s = (t < 8) ? t2 : tsc;
      const int i = t & 7;
      if(isf32) tf[t] = ((const float*)s)[i];
      else      tf[t] = bf2f(((const u16*)s)[i]);
    }
  }
}

// ---------------------------------------------------------------------------
// K1: fused QKV GEMM, m97 structure + fused row-norm partials.
// r17: T2 XOR-swizzle. Staging: lane fetches logical 16B-slot (lane&7)^(lane>>3)
// so physical LDS slot s at row r holds logical slot s^(r&7). Reads use
// slot = (kh*4+fq)^(fm&7) -> wave footprint covers all 32 banks (was 16).
// ---------------------------------------------------------------------------
__global__ __launch_bounds__(256) void k_qkv(const u16* __restrict__ Wc,
                                             const u16* __restrict__ xT,
                                             u16* __restrict__ Y,
                                             float* __restrict__ nrmp){
  __shared__ union {
    struct { u16 Ws[128][64]; u16 Xs[128][64]; } s;
    u16 Cs[128][136];
  } L;
  const int t = threadIdx.x;
  const int n0 = blockIdx.x * 128, m0 = blockIdx.y * 128, b = blockIdx.z;
  const int w = t >> 6, lane = t & 63;
  const int fm = lane & 15, fq = lane >> 4;
  const int wm = w >> 1, wn = w & 1;
  const int lr = lane >> 3;
  const int lcs = ((lane & 7) ^ lr) * 8;     // swizzled source column (u16)
  const u16* gw = Wc + (size_t)m0 * 256;
  const u16* gx = xT + ((size_t)b * 4096 + n0) * 256;
  f32x4 acc[4][4] = {};
  for(int kc = 0; kc < 256; kc += 64){
    #pragma unroll
    for(int i = 0; i < 4; i++){
      const int row = w * 32 + i * 8;          // wave-uniform LDS base row
      gload_lds16(gw + (size_t)(row + lr) * 256 + kc + lcs, &L.s.Ws[row][0]);
      gload_lds16(gx + (size_t)(row + lr) * 256 + kc + lcs, &L.s.Xs[row][0]);
    }
    __syncthreads();
    #pragma unroll
    for(int kh = 0; kh < 2; kh++){
      const int sl = ((kh * 4 + fq) ^ (fm & 7)) * 8;   // swizzled read slot
      bf16x8 af[4], bx[4];
      #pragma unroll
      for(int mt = 0; mt < 4; mt++)
        af[mt] = *(const bf16x8*)&L.s.Ws[wm * 64 + mt * 16 + fm][sl];
      #pragma unroll
      for(int nt = 0; nt < 4; nt++)
        bx[nt] = *(const bf16x8*)&L.s.Xs[wn * 64 + nt * 16 + fm][sl];
      #pragma unroll
      for(int mt = 0; mt < 4; mt++)
        #pragma unroll
        for(int nt = 0; nt < 4; nt++)
          acc[mt][nt] = __builtin_amdgcn_mfma_f32_16x16x32_bf16(af[mt], bx[nt],
                                                                acc[mt][nt], 0, 0, 0);
    }
    __syncthreads();
  }
  #pragma unroll
  for(int mt = 0; mt < 4; mt++)
    #pragma unroll
    for(int nt = 0; nt < 4; nt++)
      #pragma unroll
      for(int r = 0; r < 4; r++)
        L.Cs[wm * 64 + mt * 16 + fq * 4 + r][wn * 64 + nt * 16 + fm] =
          f2bf(acc[mt][nt][r]);
  __syncthreads();
  const bool do_norm = (blockIdx.y < 6);       // rows 0:768 = q|qc|kc
  float* npb = nrmp + (size_t)blockIdx.x * 6144 + (size_t)b * 768 + m0;
  #pragma unroll
  for(int i = 0; i < 8; i++){
    const int row = i * 16 + (t >> 4), ce = (t & 15) * 8;
    uint4 pk = *(const uint4*)&L.Cs[row][ce];
    *(uint4*)(Y + ((size_t)b * 1024 + m0 + row) * 4096 + n0 + ce) = pk;
    if(do_norm){
      u16 e[8]; *(uint4*)e = pk;
      float s = 0.f;
      #pragma unroll
      for(int k2 = 0; k2 < 8; k2++){ float v = bf2f(e[k2]); s += v * v; }
      #pragma unroll
      for(int m2 = 1; m2 < 16; m2 <<= 1) s += __shfl_xor(s, m2, 16);
      if((t & 15) == 0) npb[row] = s;
    }
  }
}

// ---------------------------------------------------------------------------
// K2: split-K MFMA xef partials (unchanged).
// ---------------------------------------------------------------------------
__global__ __launch_bounds__(256) void k_xef_mfma(const u16* __restrict__ xb,
                                                  const u16* __restrict__ EFT,
                                                  float* __restrict__ xefp){
  const int t = threadIdx.x;
  const int mh = blockIdx.x, s = blockIdx.y, b = blockIdx.z;
  const int w = t >> 6, lane = t & 63;
  const int fm = lane & 15, fq = lane >> 4;
  const int c0 = mh * 128 + w * 32;
  const u16* ar = xb + ((size_t)(b * 256 + c0 + fm)) * 4096 + s * 256 + fq * 8;
  const u16* br = EFT + (size_t)fm * 4096 + s * 256 + fq * 8;
  f32x4 acc[2][4] = {};
  #pragma unroll
  for(int kk = 0; kk < 8; kk++){
    bf16x8 bfr[4];
    #pragma unroll
    for(int nt = 0; nt < 4; nt++)
      bfr[nt] = *(const bf16x8*)(br + (size_t)nt * 16 * 4096 + kk * 32);
    #pragma unroll
    for(int mt = 0; mt < 2; mt++){
      bf16x8 af = *(const bf16x8*)(ar + (size_t)mt * 16 * 4096 + kk * 32);
      #pragma unroll
      for(int nt = 0; nt < 4; nt++)
        acc[mt][nt] = __builtin_amdgcn_mfma_f32_16x16x32_bf16(af, bfr[nt],
                                                              acc[mt][nt], 0, 0, 0);
    }
  }
  float* dst = xefp + (size_t)s * 131072 + (size_t)(b * 256 + c0) * 64;
  #pragma unroll
  for(int mt = 0; mt < 2; mt++)
    #pragma unroll
    for(int nt = 0; nt < 4; nt++)
      #pragma unroll
      for(int r = 0; r < 4; r++)
        dst[(mt * 16 + fq * 4 + r) * 64 + nt * 16 + fm] = acc[mt][nt][r];
}

// ---------------------------------------------------------------------------
// K2b: xef reduce (blocks 0:128) + norm finalize (blocks 128:152).
// ---------------------------------------------------------------------------
__global__ __launch_bounds__(256) void k_xred_nfin(const float* __restrict__ xefp,
                                                   float* __restrict__ xef,
                                                   const float* __restrict__ nrmp,
                                                   float* __restrict__ inv3){
  const int bx = blockIdx.x, t = threadIdx.x;
  if(bx < 128){
    const int i0 = (bx * 256 + t) * 4;
    float4 a = *(const float4*)(xefp + i0);
    #pragma unroll
    for(int s = 1; s < 16; s++){
      const float4 v = *(const float4*)(xefp + (size_t)s * 131072 + i0);
      a.x += v.x; a.y += v.y; a.z += v.z; a.w += v.w;
    }
    *(float4*)(xef + i0) = a;
  } else {
    const int tid = (bx - 128) * 256 + t;          // [0, 6144)
    float s = 0.f;
    #pragma unroll
    for(int nt = 0; nt < 32; nt++) s += nrmp[(size_t)nt * 6144 + tid];
    const int b = tid / 768, m = tid - b * 768;
    inv3[(m >> 8) * 2048 + b * 256 + (m & 255)] = 1.0f / fmaxf(sqrtf(s), 1e-12f);
  }
}

// ---------------------------------------------------------------------------
// K3: kvp -> bf16 kpT/vpb (unchanged).
// ---------------------------------------------------------------------------
__global__ __launch_bounds__(256) void k_kv4b(const float* __restrict__ Wsaf,
                                              const float* __restrict__ xef,
                                              const float* __restrict__ invsa,
                                              u16* __restrict__ kpT,
                                              u16* __restrict__ vpb){
  const int t = threadIdx.x;
  const int ri = t >> 6, p = t & 63;
  const int r = blockIdx.x * 4 + ri, b = blockIdx.y;
  const int row_w = (r < 256) ? (256 + r) : (512 + r);
  const float* wr = Wsaf + (size_t)row_w * 256;
  const float* xr = xef + (size_t)(b * 256) * 64 + p;
  float acc = 0.f;
  for(int c = 0; c < 256; c++)
    acc += wr[c] * xr[(size_t)c * 64];
  if(r < 256){
    const float sc = invsa[b * 256 + r];
    kpT[((size_t)(b * 8 + (r >> 5)) * 64 + p) * 32 + (r & 31)] = f2bf(acc * sc);
  } else {
    const int rv = r - 256;
    vpb[((size_t)(b * 8 + (rv >> 5)) * 32 + (rv & 31)) * 64 + p] = f2bf(acc);
  }
}

// ---------------------------------------------------------------------------
// K5: MFMA Gram partials (unchanged).
// ---------------------------------------------------------------------------
__device__ __forceinline__ bf16x8 ld_frag8(const u16* p){
  short4v lo = *(const short4v*)p;
  short4v hi = *(const short4v*)(p + 4);
  bf16x8 r;
  r[0]=lo[0]; r[1]=lo[1]; r[2]=lo[2]; r[3]=lo[3];
  r[4]=hi[0]; r[5]=hi[1]; r[6]=hi[2]; r[7]=hi[3];
  return r;
}

__global__ __launch_bounds__(256) void k_gram_mfma(const u16* __restrict__ Y,
                                                   float* __restrict__ Gp){
  const int t = threadIdx.x;
  const int s = blockIdx.x, h = blockIdx.y, b = blockIdx.z;
  const int w = t >> 6, lane = t & 63;
  const int fm = lane & 15, fq = lane >> 4;
  const int j0 = (w >> 1) * 16, e0 = (w & 1) * 16;
  const u16* qrow = Y + (size_t)(b * 1024 + 256 + h * 32 + j0 + fm) * 4096;
  const u16* krow = Y + (size_t)(b * 1024 + 512 + h * 32 + e0 + fm) * 4096;
  f32x4 acc = {};
  const int nb0 = s * 512 + fq * 8;
  #pragma unroll 4
  for(int it = 0; it < 16; it++){
    const int nb = nb0 + it * 32;
    bf16x8 a  = ld_frag8(qrow + nb);
    bf16x8 bb = ld_frag8(krow + nb);
    acc = __builtin_amdgcn_mfma_f32_16x16x32_bf16(a, bb, acc, 0, 0, 0);
  }
  float* dst = Gp + ((size_t)((s * 8 + b) * 8 + h) * 1024);
  #pragma unroll
  for(int r = 0; r < 4; r++)
    dst[(j0 + fq * 4 + r) * 32 + e0 + fm] = acc[r];
}

// ---------------------------------------------------------------------------
// K5b: channel softmax (256-thread blocks).
// ---------------------------------------------------------------------------
__global__ __launch_bounds__(256) void k_softmax_ca(const float* __restrict__ Gp,
                             const float* __restrict__ invq,
                             const float* __restrict__ invk,
                             const float* __restrict__ temp,
                             float* __restrict__ attn){
  const int t = threadIdx.x, b = blockIdx.x;
  const int h = t >> 5, j = t & 31;
  const float tm = temp[h];
  const float iq = invq[b * 256 + h * 32 + j];
  float v[32];
  float m = -1e30f;
  #pragma unroll
  for(int e = 0; e < 32; e++){
    float g = 0.f;
    #pragma unroll
    for(int s = 0; s < 8; s++)
      g += Gp[(size_t)s * 65536 + (size_t)(b * 8 + h) * 1024 + j * 32 + e];
    float val = g * iq * invk[b * 256 + h * 32 + e] * tm;
    v[e] = val; m = fmaxf(m, val);
  }
  float sum = 0.f;
  #pragma unroll
  for(int e = 0; e < 32; e++){ v[e] = __expf(v[e] - m); sum += v[e]; }
  const float inv = 1.0f / sum;
  #pragma unroll
  for(int e = 0; e < 32; e++) attn[(size_t)(b * 8 + h) * 1024 + j * 32 + e] = v[e] * inv;
}

// ---------------------------------------------------------------------------
// K6: full-MFMA spatial attention (unchanged).
// ---------------------------------------------------------------------------
__global__ __launch_bounds__(256) void k_sa_mfma(const u16* __restrict__ Y,
                                                 const u16* __restrict__ kpT,
                                                 const u16* __restrict__ vpb,
                                                 const float* __restrict__ temp2,
                                                 u16* __restrict__ xsa){
  __shared__ u16 As[64][36];
  __shared__ u16 Ks[64][36];
  __shared__ u16 Vs[32][68];
  __shared__ u16 Ps[64][68];
  __shared__ u16 Cs[32][68];
  const int t = threadIdx.x;
  const int ntile = blockIdx.x, h = blockIdx.y, b = blockIdx.z;
  const int n0 = ntile * 64;
  const int w = t >> 6, lane = t & 63;
  const int fm = lane & 15, fq = lane >> 4;
  {
    const int j = t >> 3, ns = (t & 7) * 8;
    const u16* src = Y + (size_t)(b * 1024 + h * 32 + j) * 4096 + n0 + ns;
    uint4 v = *(const uint4*)src;
    u16 e[8]; *(uint4*)e = v;
    #pragma unroll
    for(int i = 0; i < 8; i++) As[ns + i][j] = e[i];
  }
  {
    const int p = t >> 2, jb = (t & 3) * 8;
    *(uint4*)&Ks[p][jb] =
      *(const uint4*)(kpT + ((size_t)(b * 8 + h) * 64 + p) * 32 + jb);
  }
  {
    const int jv = t >> 3, ps = (t & 7) * 8;
    *(uint4*)&Vs[jv][ps] =
      *(const uint4*)(vpb + ((size_t)(b * 8 + h) * 32 + jv) * 64 + ps);
  }
  __syncthreads();
  bf16x8 a = ld_frag8(&As[w * 16 + fm][fq * 8]);
  f32x4 lg[4];
  #pragma unroll
  for(int pt = 0; pt < 4; pt++){
    bf16x8 bk = ld_frag8(&Ks[pt * 16 + fm][fq * 8]);
    f32x4 z = {};
    lg[pt] = __builtin_amdgcn_mfma_f32_16x16x32_bf16(a, bk, z, 0, 0, 0);
  }
  const float tm = temp2[h];
  float sinv[4];
  #pragma unroll
  for(int r = 0; r < 4; r++){
    float v0 = lg[0][r]*tm, v1 = lg[1][r]*tm, v2 = lg[2][r]*tm, v3 = lg[3][r]*tm;
    float mx = fmaxf(fmaxf(v0, v1), fmaxf(v2, v3));
    #pragma unroll
    for(int m = 1; m < 16; m <<= 1) mx = fmaxf(mx, __shfl_xor(mx, m, 16));
    v0 = __expf(v0 - mx); v1 = __expf(v1 - mx);
    v2 = __expf(v2 - mx); v3 = __expf(v3 - mx);
    float s = v0 + v1 + v2 + v3;
    #pragma unroll
    for(int m = 1; m < 16; m <<= 1) s += __shfl_xor(s, m, 16);
    sinv[r] = 1.0f / s;
    const int nrow = w * 16 + fq * 4 + r;
    Ps[nrow][fm]      = f2bf(v0);
    Ps[nrow][16 + fm] = f2bf(v1);
    Ps[nrow][32 + fm] = f2bf(v2);
    Ps[nrow][48 + fm] = f2bf(v3);
  }
  f32x4 o[2] = {};
  #pragma unroll
  for(int ks = 0; ks < 2; ks++){
    bf16x8 ap = ld_frag8(&Ps[w * 16 + fm][ks * 32 + fq * 8]);
    #pragma unroll
    for(int jt = 0; jt < 2; jt++){
      bf16x8 bv = ld_frag8(&Vs[jt * 16 + fm][ks * 32 + fq * 8]);
      o[jt] = __builtin_amdgcn_mfma_f32_16x16x32_bf16(ap, bv, o[jt], 0, 0, 0);
    }
  }
  #pragma unroll
  for(int jt = 0; jt < 2; jt++)
    #pragma unroll
    for(int r = 0; r < 4; r++)
      Cs[jt * 16 + fm][w * 16 + fq * 4 + r] = f2bf(o[jt][r] * sinv[r]);
  __syncthreads();
  {
    const int jv = t >> 3, ns = (t & 7) * 8;
    u16 e[8];
    #pragma unroll
    for(int i = 0; i < 8; i++) e[i] = Cs[jv][ns + i];
    *(uint4*)(xsa + ((size_t)(b * 8 + h) * 32 + jv) * 4096 + n0 + ns) = *(uint4*)e;
  }
}

// ---------------------------------------------------------------------------
// K7: MFMA out-writer (unchanged).
// ---------------------------------------------------------------------------
__global__ __launch_bounds__(256) void k_out_mfma(const u16* __restrict__ Y,
                                                  const float* __restrict__ attn,
                                                  const u16* __restrict__ xsa,
                                                  float* __restrict__ out){
  __shared__ u16 Vt[32][516];
  __shared__ u16 xs[32][16][34];
  __shared__ u16 Ah[32][40];
  __shared__ u16 Al[32][40];
  const int t = threadIdx.x;
  const int jg = blockIdx.x, hc = blockIdx.y, b = blockIdx.z;
  const int nn0 = jg * 512;
  const int w = t >> 6, lane = t & 63;
  const int fm = lane & 15, fq = lane >> 4;
  {
    const float4 v = *(const float4*)(attn + (size_t)(b * 8 + hc) * 1024 + t * 4);
    const int j = t >> 3, e0 = (t & 7) * 4;
    float vv[4] = {v.x, v.y, v.z, v.w};
    #pragma unroll
    for(int i = 0; i < 4; i++){
      u16 hi = f2bf(vv[i]);
      Ah[j][e0 + i] = hi;
      Al[j][e0 + i] = f2bf(vv[i] - bf2f(hi));
    }
  }
  {
    const int e = t >> 3, ch = (t & 7) * 64;
    const u16* src = Y + (size_t)(b * 1024 + 768 + hc * 32 + e) * 4096 + nn0 + ch;
    #pragma unroll
    for(int i = 0; i < 8; i++){
      uint4 v = *(const uint4*)(src + i * 8);
      uint2 lo; lo.x = v.x; lo.y = v.y;
      uint2 hi; hi.x = v.z; hi.y = v.w;
      *(uint2*)&Vt[e][ch + i * 8]     = lo;
      *(uint2*)&Vt[e][ch + i * 8 + 4] = hi;
    }
  }
  #pragma unroll
  for(int rep = 0; rep < 2; rep++){
    const int s = rep * 256 + t;
    const int hj = s >> 4, nh = s & 15;
    const int h = hj & 7, jj = hj >> 3;
    const u16* src = xsa + ((size_t)(b * 8 + h) * 32 + jg * 4 + jj) * 4096 + nh * 256 + hc * 32;
    uint4 v0 = *(const uint4*)src;
    uint4 v1 = *(const uint4*)(src + 8);
    u32* d32 = (u32*)&xs[hj][nh][0];
    d32[0] = v0.x; d32[1] = v0.y; d32[2] = v0.z; d32[3] = v0.w;
    d32[4] = v1.x; d32[5] = v1.y; d32[6] = v1.z; d32[7] = v1.w;
    uint4 v2 = *(const uint4*)(src + 16);
    uint4 v3 = *(const uint4*)(src + 24);
    d32[8]  = v2.x; d32[9]  = v2.y; d32[10] = v2.z; d32[11] = v2.w;
    d32[12] = v3.x; d32[13] = v3.y; d32[14] = v3.z; d32[15] = v3.w;
  }
  __syncthreads();
  bf16x8 ah[2], al[2];
  #pragma unroll
  for(int mt = 0; mt < 2; mt++){
    ah[mt] = *(const bf16x8*)&Ah[mt * 16 + fm][fq * 8];
    al[mt] = *(const bf16x8*)&Al[mt * 16 + fm][fq * 8];
  }
  f32x4 acc[2][8] = {};
  #pragma unroll
  for(int nt = 0; nt < 8; nt++){
    const int colb = w * 128 + nt * 16 + fm;
    bf16x8 bv;
    #pragma unroll
    for(int i = 0; i < 8; i++) bv[i] = (short)Vt[fq * 8 + i][colb];
    #pragma unroll
    for(int mt = 0; mt < 2; mt++){
      acc[mt][nt] = __builtin_amdgcn_mfma_f32_16x16x32_bf16(ah[mt], bv, acc[mt][nt], 0, 0, 0);
      acc[mt][nt] = __builtin_amdgcn_mfma_f32_16x16x32_bf16(al[mt], bv, acc[mt][nt], 0, 0, 0);
    }
  }
  #pragma unroll
  for(int mt = 0; mt < 2; mt++)
    #pragma unroll
    for(int nt = 0; nt < 8; nt++){
      const int col = w * 128 + nt * 16 + fm;
      float* op = out + (size_t)(b * 256 + hc * 32 + mt * 16 + fq * 4) * 4096 + nn0 + col;
      #pragma unroll
      for(int r = 0; r < 4; r++){
        const float sa = bf2f(xs[w * 8 + nt][fm][mt * 16 + fq * 4 + r]);
        op[(size_t)r * 4096] = acc[mt][nt][r] + sa;
      }
    }
}

// ---------------------------------------------------------------------------
// Workspace layout (bytes).
// ---------------------------------------------------------------------------
#define OFF_XB    ((size_t)0)            // u16 [8][256][4096]  16,777,216 (reused as xsa)
#define OFF_XT    ((size_t)16777216)     // u16 [8][4096][256]  16,777,216 (reused as xefp)
#define OFF_Y     ((size_t)33554432)     // u16 [8][1024][4096] 67,108,864
#define OFF_WSAF  ((size_t)100663296)    // f32 [1024][256]      1,048,576
#define OFF_WCAT  ((size_t)101711872)    // u16 [1024][256]        524,288
#define OFF_EFT   ((size_t)102236160)    // u16 [64][4096]         524,288
#define OFF_XEF   ((size_t)103284736)    // f32 [8][256][64]       524,288
#define OFF_KPT   ((size_t)103809024)    // u16 [8][8][64][32]     262,144
#define OFF_VPB   ((size_t)104071168)    // u16 [8][8][32][64]     262,144
#define OFF_ISA   ((size_t)104333312)    // f32 [3][8][256]         24,576 (isa|iqc|ikc)
#define OFF_IQC   ((size_t)104341504)
#define OFF_IKC   ((size_t)104349696)
#define OFF_GP    ((size_t)104357888)    // f32 [8][8][8][32][32] 2,097,152
#define OFF_ATT   ((size_t)106455040)    // f32 [8][8][32][32]      262,144
#define OFF_TF    ((size_t)106717184)    // f32 [16]
#define OFF_FLAG  ((size_t)106717248)    // u32
#define OFF_NRM   ((size_t)106717312)    // f32 [32][8][768]        786,432
#define OFF_XEFP  OFF_XT                 // f32 [16][8][256][64]  8,388,608 (overlay)

extern "C" void kernel_launch(void* const* d_in, const int* in_sizes, int n_in,
                              void* d_out, int out_size, void* d_ws, size_t ws_size,
                              hipStream_t stream){
  (void)in_sizes; (void)n_in; (void)out_size; (void)ws_size;
  char* ws = (char*)d_ws;
  u16*   xb    = (u16*)  (ws + OFF_XB);
  u16*   xsa   = (u16*)  (ws + OFF_XB);    // overlay
  u16*   xT    = (u16*)  (ws + OFF_XT);
  u16*   Y     = (u16*)  (ws + OFF_Y);
  float* Wsaf  = (float*)(ws + OFF_WSAF);
  u16*   Wcat  = (u16*)  (ws + OFF_WCAT);
  u16*   EFT   = (u16*)  (ws + OFF_EFT);
  float* xef   = (float*)(ws + OFF_XEF);
  u16*   kpT   = (u16*)  (ws + OFF_KPT);
  u16*   vpb   = (u16*)  (ws + OFF_VPB);
  float* invsa = (float*)(ws + OFF_ISA);
  float* invqc = (float*)(ws + OFF_IQC);
  float* invkc = (float*)(ws + OFF_IKC);
  float* Gp    = (float*)(ws + OFF_GP);
  float* attn  = (float*)(ws + OFF_ATT);
  float* tf    = (float*)(ws + OFF_TF);
  u32*   flag  = (u32*)  (ws + OFF_FLAG);
  float* nrmp  = (float*)(ws + OFF_NRM);
  float* xefp  = (float*)(ws + OFF_XEFP);  // overlay on xT (dead after k_qkv)
  float* out = (float*)d_out;

  // dtype detect + canonicalize (x transpose; all small convs in one launch)
  k_detect<<<1, 256, 0, stream>>>((const u16*)d_in[0], flag);
  k_convT<<<dim3(64, 4, 8), 256, 0, stream>>>(d_in[0], xb, xT, flag);
  k_conv_misc<<<417, 256, 0, stream>>>(d_in[1], d_in[2], d_in[4], d_in[3], d_in[5],
                                       Wsaf, Wcat, EFT, tf, flag);

  // Fused QKV GEMM (q | qc | kc | vc) + row-norm partials
  k_qkv<<<dim3(32, 8, 8), 256, 0, stream>>>(Wcat, xT, Y, nrmp);
  // Linformer projection: split-K MFMA partials; reduce + norm finalize
  k_xef_mfma<<<dim3(2, 16, 8), 256, 0, stream>>>(xb, EFT, xefp);
  k_xred_nfin<<<152, 256, 0, stream>>>(xefp, xef, nrmp, invsa);
  // kpT (scaled) + vpb, bf16
  k_kv4b<<<dim3(128, 8), 256, 0, stream>>>(Wsaf, xef, invsa, kpT, vpb);
  // Channel attention matrix (MFMA gram) + softmax
  k_gram_mfma<<<dim3(8, 8, 8), 256, 0, stream>>>(Y, Gp);
  k_softmax_ca<<<8, 256, 0, stream>>>(Gp, invqc, invkc, tf + 8, attn);
  // Spatial attention (full MFMA) -> xsa, then MFMA out-writer
  k_sa_mfma<<<dim3(64, 8, 8), 256, 0, stream>>>(Y, kpT, vpb, tf, xsa);
  k_out_mfma<<<dim3(8, 8, 8), 256, 0, stream>>>(Y, attn, xsa, out);
}

// Round 6
// 197.134 us; speedup vs baseline: 1.4733x; 1.0408x over previous
//
#include <hip/hip_runtime.h>

typedef unsigned short u16;
typedef unsigned int   u32;

typedef __attribute__((ext_vector_type(4))) short short4v;
typedef __attribute__((ext_vector_type(8))) short bf16x8;  // 8 bf16 (4 VGPRs)
typedef __attribute__((ext_vector_type(4))) float f32x4;

// Problem: B=8, C=256, N=4096, heads=8, d=32, P=64. Inputs fp32 (auto-detect),
// output FP32. r17: T2 swizzle on k_qkv. r18: (a) 2-phase double-buffered k_qkv
// (T3 minimum recipe: raw s_barrier + asm vmcnt, 1 barrier/iter, stage latency
// hidden under MFMA); (b) launch merges 11->7 (convT+misc, qkv+xef, kv4b+gram,
// sa+softmax); xefp moved off the xT overlay so xef can co-run with qkv.

__device__ __forceinline__ float bf2f(u16 u){
  union { u32 i; float f; } v; v.i = ((u32)u) << 16; return v.f;
}
__device__ __forceinline__ u16 f2bf(float f){
  u32 u = __float_as_uint(f);
  u32 r = u + 0x7FFFu + ((u >> 16) & 1u);   // RNE
  return (u16)(r >> 16);
}

__device__ __forceinline__ void gload_lds16(const u16* g, u16* l){
  __builtin_amdgcn_global_load_lds((const __attribute__((address_space(1))) void*)g,
                                   (__attribute__((address_space(3))) void*)l,
                                   16, 0, 0);
}

// ---------------------------------------------------------------------------
// K0a: dtype detector on x. flag=1 => fp32 input.
// ---------------------------------------------------------------------------
__global__ void k_detect(const u16* __restrict__ x, u32* __restrict__ flag){
  __shared__ int cnt[256];
  const int t = threadIdx.x;
  int c = 0;
  #pragma unroll
  for(int i = 0; i < 4; i++){
    u16 v = x[t * 4 + i];
    int e = (v >> 7) & 0xFF;
    if(e >= 112 && e <= 134) c++;
  }
  cnt[t] = c;
  __syncthreads();
  for(int s = 128; s > 0; s >>= 1){
    if(t < s) cnt[t] += cnt[t + s];
    __syncthreads();
  }
  if(t == 0) *flag = (cnt[0] < 800) ? 1u : 0u;
}

// ---------------------------------------------------------------------------
// K0 (merged): x transpose (y<4) + all small weight/EF/temp convs (y==4).
// Grid (64, 5, 8).
// ---------------------------------------------------------------------------
__global__ __launch_bounds__(256) void k_conv_all(const void* __restrict__ xsrc,
                                                  const void* __restrict__ Wsa,
                                                  const void* __restrict__ EF,
                                                  const void* __restrict__ Wsc,
                                                  const void* __restrict__ t2,
                                                  const void* __restrict__ tsc,
                                                  u16* __restrict__ xb,
                                                  u16* __restrict__ xT,
                                                  float* __restrict__ Wsaf,
                                                  u16* __restrict__ Wcat,
                                                  u16* __restrict__ EFT,
                                                  float* __restrict__ tf,
                                                  const u32* __restrict__ flag){
  __shared__ u16 T[64][72];
  const int t = threadIdx.x;
  const bool isf32 = (*flag != 0);
  if(blockIdx.y < 4){
    // ---- convT: x -> xb[b][c][n] + xT[b][n][c]
    const int n0 = blockIdx.x * 64, c0 = blockIdx.y * 64, b = blockIdx.z;
    const int cl = t >> 2, ns = (t & 3) * 16;
    const size_t srcoff = ((size_t)(b * 256 + c0 + cl)) * 4096 + n0 + ns;
    u16 e[16];
    if(isf32){
      const float* sp = (const float*)xsrc + srcoff;
      #pragma unroll
      for(int i = 0; i < 4; i++){
        const float4 v = *(const float4*)(sp + i * 4);
        e[i*4+0] = f2bf(v.x); e[i*4+1] = f2bf(v.y);
        e[i*4+2] = f2bf(v.z); e[i*4+3] = f2bf(v.w);
      }
    } else {
      const u16* sp = (const u16*)xsrc + srcoff;
      *(uint4*)&e[0] = *(const uint4*)sp;
      *(uint4*)&e[8] = *(const uint4*)(sp + 8);
    }
    u16* xbp = xb + srcoff;
    *(uint4*)xbp       = *(uint4*)&e[0];
    *(uint4*)(xbp + 8) = *(uint4*)&e[8];
    #pragma unroll
    for(int i = 0; i < 16; i++) T[ns + i][cl] = e[i];
    __syncthreads();
    const int nl = t >> 2, cs = (t & 3) * 16;
    u16* xtp = xT + ((size_t)b * 4096 + n0 + nl) * 256 + c0 + cs;
    *(uint4*)xtp       = *(const uint4*)&T[nl][cs];
    *(uint4*)(xtp + 8) = *(const uint4*)&T[nl][cs + 8];
    return;
  }
  // ---- misc convs, mid in [0, 417)
  const int mid = blockIdx.x + 64 * blockIdx.z;
  if(mid < 256){
    const int i0 = (mid * 256 + t) * 4;
    float4 o;
    if(isf32){
      o = *(const float4*)((const float*)Wsa + i0);
    } else {
      const uint2 a = *(const uint2*)((const u16*)Wsa + i0);
      o.x = bf2f((u16)(a.x & 0xFFFF)); o.y = bf2f((u16)(a.x >> 16));
      o.z = bf2f((u16)(a.y & 0xFFFF)); o.w = bf2f((u16)(a.y >> 16));
    }
    *(float4*)(Wsaf + i0) = o;
    if(i0 < 65536){
      uint2 pk;
      pk.x = (u32)f2bf(o.x) | ((u32)f2bf(o.y) << 16);
      pk.y = (u32)f2bf(o.z) | ((u32)f2bf(o.w) << 16);
      *(uint2*)(Wcat + i0) = pk;
    }
  } else if(mid < 320){
    const int n0 = (mid - 256) * 64;
    const int nl = t >> 2, p0 = (t & 3) * 16;
    const size_t off = (size_t)(n0 + nl) * 64 + p0;
    u16 e[16];
    if(isf32){
      const float* sp = (const float*)EF + off;
      #pragma unroll
      for(int i = 0; i < 4; i++){
        const float4 v = *(const float4*)(sp + i * 4);
        e[i*4+0] = f2bf(v.x); e[i*4+1] = f2bf(v.y);
        e[i*4+2] = f2bf(v.z); e[i*4+3] = f2bf(v.w);
      }
    } else {
      const u16* sp = (const u16*)EF + off;
      *(uint4*)&e[0] = *(const uint4*)sp;
      *(uint4*)&e[8] = *(const uint4*)(sp + 8);
    }
    #pragma unroll
    for(int i = 0; i < 16; i++) T[p0 + i][nl] = e[i];
    __syncthreads();
    const int pr = t >> 2, nn = (t & 3) * 16;
    u16* dp = EFT + (size_t)pr * 4096 + n0 + nn;
    *(uint4*)dp       = *(const uint4*)&T[pr][nn];
    *(uint4*)(dp + 8) = *(const uint4*)&T[pr][nn + 8];
  } else if(mid < 416){
    const int i0 = ((mid - 320) * 256 + t) * 8;
    u16* dst = Wcat + 65536;
    if(isf32){
      const float4 a = *(const float4*)((const float*)Wsc + i0);
      const float4 b = *(const float4*)((const float*)Wsc + i0 + 4);
      uint4 o;
      o.x = (u32)f2bf(a.x) | ((u32)f2bf(a.y) << 16);
      o.y = (u32)f2bf(a.z) | ((u32)f2bf(a.w) << 16);
      o.z = (u32)f2bf(b.x) | ((u32)f2bf(b.y) << 16);
      o.w = (u32)f2bf(b.z) | ((u32)f2bf(b.w) << 16);
      *(uint4*)(dst + i0) = o;
    } else {
      *(uint4*)(dst + i0) = *(const uint4*)((const u16*)Wsc + i0);
    }
  } else if(mid == 416){
    if(t < 16){
      const void* s = (t < 8) ? t2 : tsc;
      const int i = t & 7;
      if(isf32) tf[t] = ((const float*)s)[i];
      else      tf[t] = bf2f(((const u16*)s)[i]);
    }
  }
}

// ---------------------------------------------------------------------------
// K1 (merged): fused QKV GEMM (y<8) + split-K MFMA xef partials (y==8).
// Grid (32, 9, 8).
// QKV: 2-phase double-buffered (T3 minimum): per iter {STAGE next; COMPUTE cur;
// vmcnt(0); s_barrier}. Swizzled staging (r17) + fused row-norm partials (r16).
// ---------------------------------------------------------------------------
__global__ __launch_bounds__(256) void k_qkv_xef(const u16* __restrict__ Wc,
                                                 const u16* __restrict__ xT,
                                                 const u16* __restrict__ xb,
                                                 const u16* __restrict__ EFT,
                                                 u16* __restrict__ Y,
                                                 float* __restrict__ nrmp,
                                                 float* __restrict__ xefp){
  __shared__ union {
    struct { u16 W0[128][64]; u16 X0[128][64];
             u16 W1[128][64]; u16 X1[128][64]; } d;
    u16 Cs[128][136];
  } L;
  const int t = threadIdx.x;
  const int w = t >> 6, lane = t & 63;
  const int fm = lane & 15, fq = lane >> 4;

  if(blockIdx.y == 8){
    // ---- xef partition: mh = x&1, s = x>>1, b = z
    const int mh = blockIdx.x & 1, s = blockIdx.x >> 1, b = blockIdx.z;
    const int c0 = mh * 128 + w * 32;
    const u16* ar = xb + ((size_t)(b * 256 + c0 + fm)) * 4096 + s * 256 + fq * 8;
    const u16* br = EFT + (size_t)fm * 4096 + s * 256 + fq * 8;
    f32x4 acc[2][4] = {};
    #pragma unroll
    for(int kk = 0; kk < 8; kk++){
      bf16x8 bfr[4];
      #pragma unroll
      for(int nt = 0; nt < 4; nt++)
        bfr[nt] = *(const bf16x8*)(br + (size_t)nt * 16 * 4096 + kk * 32);
      #pragma unroll
      for(int mt = 0; mt < 2; mt++){
        bf16x8 af = *(const bf16x8*)(ar + (size_t)mt * 16 * 4096 + kk * 32);
        #pragma unroll
        for(int nt = 0; nt < 4; nt++)
          acc[mt][nt] = __builtin_amdgcn_mfma_f32_16x16x32_bf16(af, bfr[nt],
                                                                acc[mt][nt], 0, 0, 0);
      }
    }
    float* dst = xefp + (size_t)s * 131072 + (size_t)(b * 256 + c0) * 64;
    #pragma unroll
    for(int mt = 0; mt < 2; mt++)
      #pragma unroll
      for(int nt = 0; nt < 4; nt++)
        #pragma unroll
        for(int r = 0; r < 4; r++)
          dst[(mt * 16 + fq * 4 + r) * 64 + nt * 16 + fm] = acc[mt][nt][r];
    return;
  }

  // ---- QKV partition
  const int n0 = blockIdx.x * 128, m0 = blockIdx.y * 128, b = blockIdx.z;
  const int wm = w >> 1, wn = w & 1;
  const int lr = lane >> 3;
  const int lcs = ((lane & 7) ^ lr) * 8;     // swizzled source column (u16)
  const u16* gw = Wc + (size_t)m0 * 256;
  const u16* gx = xT + ((size_t)b * 4096 + n0) * 256;
  f32x4 acc[4][4] = {};

#define QKV_STAGE(Wbuf, Xbuf, kc) do{                                          \
    _Pragma("unroll")                                                          \
    for(int i_ = 0; i_ < 4; i_++){                                             \
      const int row_ = w * 32 + i_ * 8;                                        \
      gload_lds16(gw + (size_t)(row_ + lr) * 256 + (kc) + lcs, &Wbuf[row_][0]);\
      gload_lds16(gx + (size_t)(row_ + lr) * 256 + (kc) + lcs, &Xbuf[row_][0]);\
    } }while(0)

#define QKV_COMPUTE(Wbuf, Xbuf) do{                                            \
    _Pragma("unroll")                                                          \
    for(int kh_ = 0; kh_ < 2; kh_++){                                          \
      const int sl_ = ((kh_ * 4 + fq) ^ (fm & 7)) * 8;                         \
      bf16x8 af_[4], bx_[4];                                                   \
      _Pragma("unroll")                                                        \
      for(int mt_ = 0; mt_ < 4; mt_++)                                         \
        af_[mt_] = *(const bf16x8*)&Wbuf[wm * 64 + mt_ * 16 + fm][sl_];        \
      _Pragma("unroll")                                                        \
      for(int nt_ = 0; nt_ < 4; nt_++)                                         \
        bx_[nt_] = *(const bf16x8*)&Xbuf[wn * 64 + nt_ * 16 + fm][sl_];        \
      _Pragma("unroll")                                                        \
      for(int mt_ = 0; mt_ < 4; mt_++)                                         \
        _Pragma("unroll")                                                      \
        for(int nt_ = 0; nt_ < 4; nt_++)                                       \
          acc[mt_][nt_] = __builtin_amdgcn_mfma_f32_16x16x32_bf16(             \
              af_[mt_], bx_[nt_], acc[mt_][nt_], 0, 0, 0);                     \
    } }while(0)

  // prologue: stage tile 0, drain, barrier
  QKV_STAGE(L.d.W0, L.d.X0, 0);
  asm volatile("s_waitcnt vmcnt(0)" ::: "memory");
  __builtin_amdgcn_s_barrier();
  // iter 0: stage kc=64 into buf1, compute buf0
  QKV_STAGE(L.d.W1, L.d.X1, 64);
  QKV_COMPUTE(L.d.W0, L.d.X0);
  asm volatile("s_waitcnt vmcnt(0)" ::: "memory");
  __builtin_amdgcn_s_barrier();
  // iter 1: stage kc=128 into buf0, compute buf1
  QKV_STAGE(L.d.W0, L.d.X0, 128);
  QKV_COMPUTE(L.d.W1, L.d.X1);
  asm volatile("s_waitcnt vmcnt(0)" ::: "memory");
  __builtin_amdgcn_s_barrier();
  // iter 2: stage kc=192 into buf1, compute buf0
  QKV_STAGE(L.d.W1, L.d.X1, 192);
  QKV_COMPUTE(L.d.W0, L.d.X0);
  asm volatile("s_waitcnt vmcnt(0)" ::: "memory");
  __builtin_amdgcn_s_barrier();
  // iter 3: compute buf1 (no prefetch)
  QKV_COMPUTE(L.d.W1, L.d.X1);
  __syncthreads();   // full drain before Cs overlays the dbuf region

  #pragma unroll
  for(int mt = 0; mt < 4; mt++)
    #pragma unroll
    for(int nt = 0; nt < 4; nt++)
      #pragma unroll
      for(int r = 0; r < 4; r++)
        L.Cs[wm * 64 + mt * 16 + fq * 4 + r][wn * 64 + nt * 16 + fm] =
          f2bf(acc[mt][nt][r]);
  __syncthreads();
  const bool do_norm = (blockIdx.y < 6);       // rows 0:768 = q|qc|kc
  float* npb = nrmp + (size_t)blockIdx.x * 6144 + (size_t)b * 768 + m0;
  #pragma unroll
  for(int i = 0; i < 8; i++){
    const int row = i * 16 + (t >> 4), ce = (t & 15) * 8;
    uint4 pk = *(const uint4*)&L.Cs[row][ce];
    *(uint4*)(Y + ((size_t)b * 1024 + m0 + row) * 4096 + n0 + ce) = pk;
    if(do_norm){
      u16 e[8]; *(uint4*)e = pk;
      float s = 0.f;
      #pragma unroll
      for(int k2 = 0; k2 < 8; k2++){ float v = bf2f(e[k2]); s += v * v; }
      #pragma unroll
      for(int m2 = 1; m2 < 16; m2 <<= 1) s += __shfl_xor(s, m2, 16);
      if((t & 15) == 0) npb[row] = s;
    }
  }
#undef QKV_STAGE
#undef QKV_COMPUTE
}

// ---------------------------------------------------------------------------
// K2b: xef reduce (blocks 0:128) + norm finalize (blocks 128:152).
// ---------------------------------------------------------------------------
__global__ __launch_bounds__(256) void k_xred_nfin(const float* __restrict__ xefp,
                                                   float* __restrict__ xef,
                                                   const float* __restrict__ nrmp,
                                                   float* __restrict__ inv3){
  const int bx = blockIdx.x, t = threadIdx.x;
  if(bx < 128){
    const int i0 = (bx * 256 + t) * 4;
    float4 a = *(const float4*)(xefp + i0);
    #pragma unroll
    for(int s = 1; s < 16; s++){
      const float4 v = *(const float4*)(xefp + (size_t)s * 131072 + i0);
      a.x += v.x; a.y += v.y; a.z += v.z; a.w += v.w;
    }
    *(float4*)(xef + i0) = a;
  } else {
    const int tid = (bx - 128) * 256 + t;          // [0, 6144)
    float s = 0.f;
    #pragma unroll
    for(int nt = 0; nt < 32; nt++) s += nrmp[(size_t)nt * 6144 + tid];
    const int b = tid / 768, m = tid - b * 768;
    inv3[(m >> 8) * 2048 + b * 256 + (m & 255)] = 1.0f / fmaxf(sqrtf(s), 1e-12f);
  }
}

// ---------------------------------------------------------------------------
// K3 (merged): gram (x<64) + kv4b (x>=64). Grid (192, 8).
// ---------------------------------------------------------------------------
__device__ __forceinline__ bf16x8 ld_frag8(const u16* p){
  short4v lo = *(const short4v*)p;
  short4v hi = *(const short4v*)(p + 4);
  bf16x8 r;
  r[0]=lo[0]; r[1]=lo[1]; r[2]=lo[2]; r[3]=lo[3];
  r[4]=hi[0]; r[5]=hi[1]; r[6]=hi[2]; r[7]=hi[3];
  return r;
}

__global__ __launch_bounds__(256) void k_kv_gram(const u16* __restrict__ Y,
                                                 const float* __restrict__ Wsaf,
                                                 const float* __restrict__ xef,
                                                 const float* __restrict__ invsa,
                                                 u16* __restrict__ kpT,
                                                 u16* __restrict__ vpb,
                                                 float* __restrict__ Gp){
  const int t = threadIdx.x;
  if(blockIdx.x < 64){
    // ---- gram: s = x>>3, h = x&7, b = y
    const int s = blockIdx.x >> 3, h = blockIdx.x & 7, b = blockIdx.y;
    const int w = t >> 6, lane = t & 63;
    const int fm = lane & 15, fq = lane >> 4;
    const int j0 = (w >> 1) * 16, e0 = (w & 1) * 16;
    const u16* qrow = Y + (size_t)(b * 1024 + 256 + h * 32 + j0 + fm) * 4096;
    const u16* krow = Y + (size_t)(b * 1024 + 512 + h * 32 + e0 + fm) * 4096;
    f32x4 acc = {};
    const int nb0 = s * 512 + fq * 8;
    #pragma unroll 4
    for(int it = 0; it < 16; it++){
      const int nb = nb0 + it * 32;
      bf16x8 a  = ld_frag8(qrow + nb);
      bf16x8 bb = ld_frag8(krow + nb);
      acc = __builtin_amdgcn_mfma_f32_16x16x32_bf16(a, bb, acc, 0, 0, 0);
    }
    float* dst = Gp + ((size_t)((s * 8 + b) * 8 + h) * 1024);
    #pragma unroll
    for(int r = 0; r < 4; r++)
      dst[(j0 + fq * 4 + r) * 32 + e0 + fm] = acc[r];
    return;
  }
  // ---- kv4b: rblk = x-64, b = y
  const int ri = t >> 6, p = t & 63;
  const int r = (blockIdx.x - 64) * 4 + ri, b = blockIdx.y;
  const int row_w = (r < 256) ? (256 + r) : (512 + r);
  const float* wr = Wsaf + (size_t)row_w * 256;
  const float* xr = xef + (size_t)(b * 256) * 64 + p;
  float acc = 0.f;
  for(int c = 0; c < 256; c++)
    acc += wr[c] * xr[(size_t)c * 64];
  if(r < 256){
    const float sc = invsa[b * 256 + r];
    kpT[((size_t)(b * 8 + (r >> 5)) * 64 + p) * 32 + (r & 31)] = f2bf(acc * sc);
  } else {
    const int rv = r - 256;
    vpb[((size_t)(b * 8 + (rv >> 5)) * 32 + (rv & 31)) * 64 + p] = f2bf(acc);
  }
}

// ---------------------------------------------------------------------------
// K4 (merged): spatial attention (x<64) + channel softmax (x==64, y==0).
// Grid (65, 8, 8).
// ---------------------------------------------------------------------------
__global__ __launch_bounds__(256) void k_sa_sm(const u16* __restrict__ Y,
                                               const u16* __restrict__ kpT,
                                               const u16* __restrict__ vpb,
                                               const float* __restrict__ tf,
                                               const float* __restrict__ Gp,
                                               const float* __restrict__ invq,
                                               const float* __restrict__ invk,
                                               u16* __restrict__ xsa,
                                               float* __restrict__ attn){
  __shared__ u16 As[64][36];
  __shared__ u16 Ks[64][36];
  __shared__ u16 Vs[32][68];
  __shared__ u16 Ps[64][68];
  __shared__ u16 Cs[32][68];
  const int t = threadIdx.x;
  if(blockIdx.x == 64){
    if(blockIdx.y != 0) return;
    // ---- channel softmax, b = z
    const int b = blockIdx.z;
    const int h = t >> 5, j = t & 31;
    const float tm = tf[8 + h];
    const float iq = invq[b * 256 + h * 32 + j];
    float v[32];
    float m = -1e30f;
    #pragma unroll
    for(int e = 0; e < 32; e++){
      float g = 0.f;
      #pragma unroll
      for(int s = 0; s < 8; s++)
        g += Gp[(size_t)s * 65536 + (size_t)(b * 8 + h) * 1024 + j * 32 + e];
      float val = g * iq * invk[b * 256 + h * 32 + e] * tm;
      v[e] = val; m = fmaxf(m, val);
    }
    float sum = 0.f;
    #pragma unroll
    for(int e = 0; e < 32; e++){ v[e] = __expf(v[e] - m); sum += v[e]; }
    const float inv = 1.0f / sum;
    #pragma unroll
    for(int e = 0; e < 32; e++)
      attn[(size_t)(b * 8 + h) * 1024 + j * 32 + e] = v[e] * inv;
    return;
  }
  // ---- spatial attention
  const int ntile = blockIdx.x, h = blockIdx.y, b = blockIdx.z;
  const int n0 = ntile * 64;
  const int w = t >> 6, lane = t & 63;
  const int fm = lane & 15, fq = lane >> 4;
  {
    const int j = t >> 3, ns = (t & 7) * 8;
    const u16* src = Y + (size_t)(b * 1024 + h * 32 + j) * 4096 + n0 + ns;
    uint4 v = *(const uint4*)src;
    u16 e[8]; *(uint4*)e = v;
    #pragma unroll
    for(int i = 0; i < 8; i++) As[ns + i][j] = e[i];
  }
  {
    const int p = t >> 2, jb = (t & 3) * 8;
    *(uint4*)&Ks[p][jb] =
      *(const uint4*)(kpT + ((size_t)(b * 8 + h) * 64 + p) * 32 + jb);
  }
  {
    const int jv = t >> 3, ps = (t & 7) * 8;
    *(uint4*)&Vs[jv][ps] =
      *(const uint4*)(vpb + ((size_t)(b * 8 + h) * 32 + jv) * 64 + ps);
  }
  __syncthreads();
  bf16x8 a = ld_frag8(&As[w * 16 + fm][fq * 8]);
  f32x4 lg[4];
  #pragma unroll
  for(int pt = 0; pt < 4; pt++){
    bf16x8 bk = ld_frag8(&Ks[pt * 16 + fm][fq * 8]);
    f32x4 z = {};
    lg[pt] = __builtin_amdgcn_mfma_f32_16x16x32_bf16(a, bk, z, 0, 0, 0);
  }
  const float tm = tf[h];
  float sinv[4];
  #pragma unroll
  for(int r = 0; r < 4; r++){
    float v0 = lg[0][r]*tm, v1 = lg[1][r]*tm, v2 = lg[2][r]*tm, v3 = lg[3][r]*tm;
    float mx = fmaxf(fmaxf(v0, v1), fmaxf(v2, v3));
    #pragma unroll
    for(int m = 1; m < 16; m <<= 1) mx = fmaxf(mx, __shfl_xor(mx, m, 16));
    v0 = __expf(v0 - mx); v1 = __expf(v1 - mx);
    v2 = __expf(v2 - mx); v3 = __expf(v3 - mx);
    float s = v0 + v1 + v2 + v3;
    #pragma unroll
    for(int m = 1; m < 16; m <<= 1) s += __shfl_xor(s, m, 16);
    sinv[r] = 1.0f / s;
    const int nrow = w * 16 + fq * 4 + r;
    Ps[nrow][fm]      = f2bf(v0);
    Ps[nrow][16 + fm] = f2bf(v1);
    Ps[nrow][32 + fm] = f2bf(v2);
    Ps[nrow][48 + fm] = f2bf(v3);
  }
  f32x4 o[2] = {};
  #pragma unroll
  for(int ks = 0; ks < 2; ks++){
    bf16x8 ap = ld_frag8(&Ps[w * 16 + fm][ks * 32 + fq * 8]);
    #pragma unroll
    for(int jt = 0; jt < 2; jt++){
      bf16x8 bv = ld_frag8(&Vs[jt * 16 + fm][ks * 32 + fq * 8]);
      o[jt] = __builtin_amdgcn_mfma_f32_16x16x32_bf16(ap, bv, o[jt], 0, 0, 0);
    }
  }
  #pragma unroll
  for(int jt = 0; jt < 2; jt++)
    #pragma unroll
    for(int r = 0; r < 4; r++)
      Cs[jt * 16 + fm][w * 16 + fq * 4 + r] = f2bf(o[jt][r] * sinv[r]);
  __syncthreads();
  {
    const int jv = t >> 3, ns = (t & 7) * 8;
    u16 e[8];
    #pragma unroll
    for(int i = 0; i < 8; i++) e[i] = Cs[jv][ns + i];
    *(uint4*)(xsa + ((size_t)(b * 8 + h) * 32 + jv) * 4096 + n0 + ns) = *(uint4*)e;
  }
}

// ---------------------------------------------------------------------------
// K7: MFMA out-writer (unchanged).
// ---------------------------------------------------------------------------
__global__ __launch_bounds__(256) void k_out_mfma(const u16* __restrict__ Y,
                                                  const float* __restrict__ attn,
                                                  const u16* __restrict__ xsa,
                                                  float* __restrict__ out){
  __shared__ u16 Vt[32][516];
  __shared__ u16 xs[32][16][34];
  __shared__ u16 Ah[32][40];
  __shared__ u16 Al[32][40];
  const int t = threadIdx.x;
  const int jg = blockIdx.x, hc = blockIdx.y, b = blockIdx.z;
  const int nn0 = jg * 512;
  const int w = t >> 6, lane = t & 63;
  const int fm = lane & 15, fq = lane >> 4;
  {
    const float4 v = *(const float4*)(attn + (size_t)(b * 8 + hc) * 1024 + t * 4);
    const int j = t >> 3, e0 = (t & 7) * 4;
    float vv[4] = {v.x, v.y, v.z, v.w};
    #pragma unroll
    for(int i = 0; i < 4; i++){
      u16 hi = f2bf(vv[i]);
      Ah[j][e0 + i] = hi;
      Al[j][e0 + i] = f2bf(vv[i] - bf2f(hi));
    }
  }
  {
    const int e = t >> 3, ch = (t & 7) * 64;
    const u16* src = Y + (size_t)(b * 1024 + 768 + hc * 32 + e) * 4096 + nn0 + ch;
    #pragma unroll
    for(int i = 0; i < 8; i++){
      uint4 v = *(const uint4*)(src + i * 8);
      uint2 lo; lo.x = v.x; lo.y = v.y;
      uint2 hi; hi.x = v.z; hi.y = v.w;
      *(uint2*)&Vt[e][ch + i * 8]     = lo;
      *(uint2*)&Vt[e][ch + i * 8 + 4] = hi;
    }
  }
  #pragma unroll
  for(int rep = 0; rep < 2; rep++){
    const int s = rep * 256 + t;
    const int hj = s >> 4, nh = s & 15;
    const int h = hj & 7, jj = hj >> 3;
    const u16* src = xsa + ((size_t)(b * 8 + h) * 32 + jg * 4 + jj) * 4096 + nh * 256 + hc * 32;
    uint4 v0 = *(const uint4*)src;
    uint4 v1 = *(const uint4*)(src + 8);
    u32* d32 = (u32*)&xs[hj][nh][0];
    d32[0] = v0.x; d32[1] = v0.y; d32[2] = v0.z; d32[3] = v0.w;
    d32[4] = v1.x; d32[5] = v1.y; d32[6] = v1.z; d32[7] = v1.w;
    uint4 v2 = *(const uint4*)(src + 16);
    uint4 v3 = *(const uint4*)(src + 24);
    d32[8]  = v2.x; d32[9]  = v2.y; d32[10] = v2.z; d32[11] = v2.w;
    d32[12] = v3.x; d32[13] = v3.y; d32[14] = v3.z; d32[15] = v3.w;
  }
  __syncthreads();
  bf16x8 ah[2], al[2];
  #pragma unroll
  for(int mt = 0; mt < 2; mt++){
    ah[mt] = *(const bf16x8*)&Ah[mt * 16 + fm][fq * 8];
    al[mt] = *(const bf16x8*)&Al[mt * 16 + fm][fq * 8];
  }
  f32x4 acc[2][8] = {};
  #pragma unroll
  for(int nt = 0; nt < 8; nt++){
    const int colb = w * 128 + nt * 16 + fm;
    bf16x8 bv;
    #pragma unroll
    for(int i = 0; i < 8; i++) bv[i] = (short)Vt[fq * 8 + i][colb];
    #pragma unroll
    for(int mt = 0; mt < 2; mt++){
      acc[mt][nt] = __builtin_amdgcn_mfma_f32_16x16x32_bf16(ah[mt], bv, acc[mt][nt], 0, 0, 0);
      acc[mt][nt] = __builtin_amdgcn_mfma_f32_16x16x32_bf16(al[mt], bv, acc[mt][nt], 0, 0, 0);
    }
  }
  #pragma unroll
  for(int mt = 0; mt < 2; mt++)
    #pragma unroll
    for(int nt = 0; nt < 8; nt++){
      const int col = w * 128 + nt * 16 + fm;
      float* op = out + (size_t)(b * 256 + hc * 32 + mt * 16 + fq * 4) * 4096 + nn0 + col;
      #pragma unroll
      for(int r = 0; r < 4; r++){
        const float sa = bf2f(xs[w * 8 + nt][fm][mt * 16 + fq * 4 + r]);
        op[(size_t)r * 4096] = acc[mt][nt][r] + sa;
      }
    }
}

// ---------------------------------------------------------------------------
// Workspace layout (bytes). ws >= 256 MB (fill counter shows 268 MB poison).
//   xsa overlays xb (xb dead after k_qkv_xef). xefp now has its OWN region
//   (no longer overlays xT — xef co-runs with qkv which reads xT).
// ---------------------------------------------------------------------------
#define OFF_XB    ((size_t)0)            // u16 [8][256][4096]  16,777,216 (reused as xsa)
#define OFF_XT    ((size_t)16777216)     // u16 [8][4096][256]  16,777,216
#define OFF_Y     ((size_t)33554432)     // u16 [8][1024][4096] 67,108,864
#define OFF_WSAF  ((size_t)100663296)    // f32 [1024][256]      1,048,576
#define OFF_WCAT  ((size_t)101711872)    // u16 [1024][256]        524,288
#define OFF_EFT   ((size_t)102236160)    // u16 [64][4096]         524,288
#define OFF_XEF   ((size_t)103284736)    // f32 [8][256][64]       524,288
#define OFF_KPT   ((size_t)103809024)    // u16 [8][8][64][32]     262,144
#define OFF_VPB   ((size_t)104071168)    // u16 [8][8][32][64]     262,144
#define OFF_ISA   ((size_t)104333312)    // f32 [3][8][256]         24,576 (isa|iqc|ikc)
#define OFF_IQC   ((size_t)104341504)
#define OFF_IKC   ((size_t)104349696)
#define OFF_GP    ((size_t)104357888)    // f32 [8][8][8][32][32] 2,097,152
#define OFF_ATT   ((size_t)106455040)    // f32 [8][8][32][32]      262,144
#define OFF_TF    ((size_t)106717184)    // f32 [16]
#define OFF_FLAG  ((size_t)106717248)    // u32
#define OFF_NRM   ((size_t)106717312)    // f32 [32][8][768]        786,432
#define OFF_XEFP  ((size_t)107503744)    // f32 [16][8][256][64]  8,388,608

extern "C" void kernel_launch(void* const* d_in, const int* in_sizes, int n_in,
                              void* d_out, int out_size, void* d_ws, size_t ws_size,
                              hipStream_t stream){
  (void)in_sizes; (void)n_in; (void)out_size; (void)ws_size;
  char* ws = (char*)d_ws;
  u16*   xb    = (u16*)  (ws + OFF_XB);
  u16*   xsa   = (u16*)  (ws + OFF_XB);    // overlay
  u16*   xT    = (u16*)  (ws + OFF_XT);
  u16*   Y     = (u16*)  (ws + OFF_Y);
  float* Wsaf  = (float*)(ws + OFF_WSAF);
  u16*   Wcat  = (u16*)  (ws + OFF_WCAT);
  u16*   EFT   = (u16*)  (ws + OFF_EFT);
  float* xef   = (float*)(ws + OFF_XEF);
  u16*   kpT   = (u16*)  (ws + OFF_KPT);
  u16*   vpb   = (u16*)  (ws + OFF_VPB);
  float* invsa = (float*)(ws + OFF_ISA);
  float* invqc = (float*)(ws + OFF_IQC);
  float* invkc = (float*)(ws + OFF_IKC);
  float* Gp    = (float*)(ws + OFF_GP);
  float* attn  = (float*)(ws + OFF_ATT);
  float* tf    = (float*)(ws + OFF_TF);
  u32*   flag  = (u32*)  (ws + OFF_FLAG);
  float* nrmp  = (float*)(ws + OFF_NRM);
  float* xefp  = (float*)(ws + OFF_XEFP);
  float* out = (float*)d_out;

  // 1) dtype detect  2) all canonicalization in one launch
  k_detect<<<1, 256, 0, stream>>>((const u16*)d_in[0], flag);
  k_conv_all<<<dim3(64, 5, 8), 256, 0, stream>>>(d_in[0], d_in[1], d_in[2],
                                                 d_in[4], d_in[3], d_in[5],
                                                 xb, xT, Wsaf, Wcat, EFT, tf, flag);
  // 3) fused QKV GEMM (2-phase dbuf) + xef partials (co-resident)
  k_qkv_xef<<<dim3(32, 9, 8), 256, 0, stream>>>(Wcat, xT, xb, EFT, Y, nrmp, xefp);
  // 4) xef reduce + norm finalize
  k_xred_nfin<<<152, 256, 0, stream>>>(xefp, xef, nrmp, invsa);
  // 5) kpT/vpb + channel gram (co-resident)
  k_kv_gram<<<dim3(192, 8), 256, 0, stream>>>(Y, Wsaf, xef, invsa, kpT, vpb, Gp);
  // 6) spatial attention + channel softmax (co-resident)
  k_sa_sm<<<dim3(65, 8, 8), 256, 0, stream>>>(Y, kpT, vpb, tf, Gp, invsa + 2048,
                                              invsa + 4096, xsa, attn);
  // 7) MFMA out-writer
  k_out_mfma<<<dim3(8, 8, 8), 256, 0, stream>>>(Y, attn, xsa, out);
}